// Round 5
// baseline (10973.042 us; speedup 1.0000x reference)
//
#include <hip/hip_runtime.h>
#include <math.h>

#define BATCH 8
#define LTOT 2048
#define DM 512
#define NHEADS 8
#define DH 64
#define NBH 64
#define NHASH 4
#define SEQ 1536
#define DECL 768
#define DFF 2048
#define NCH 2048   // total chunks (4 rounds * 512)

static __device__ __forceinline__ double gelu_d(double x) {
    return 0.5 * x * (1.0 + erf(x * 0.70710678118654752440));
}

// ---------------------------------------------------------------------------
// h = TokenConv(x) + TimeLinear(xm) + PE   -> H [B, L, 512]
// PE mimics numpy-fp32 rounding points: e, div, ang rounded to fp32.
// ---------------------------------------------------------------------------
__global__ __launch_bounds__(512) void build_h_kernel(
    const float* __restrict__ x_enc, const float* __restrict__ x_mark_enc,
    const float* __restrict__ x_dec, const float* __restrict__ x_mark_dec,
    const float* __restrict__ token_w, const float* __restrict__ temp_w,
    float* __restrict__ H)
{
    int bl = blockIdx.x;
    int b = bl >> 11, l = bl & 2047;
    __shared__ float xr[3][7];
    __shared__ float xmr[4];
    int tid = threadIdx.x;
    if (tid < 21) {
        int k = tid / 7, c = tid % 7;
        int t = (l + k - 1 + LTOT) & 2047;
        float v;
        if (t < SEQ) v = x_enc[(b * SEQ + t) * 7 + c];
        else         v = x_dec[(b * DECL + (t - 1280)) * 7 + c];
        xr[k][c] = v;
    } else if (tid < 25) {
        int m = tid - 21;
        float v;
        if (l < SEQ) v = x_mark_enc[(b * SEQ + l) * 4 + m];
        else         v = x_mark_dec[(b * DECL + (l - 1280)) * 4 + m];
        xmr[m] = v;
    }
    __syncthreads();
    int d = tid;  // 0..511
    double val = 0.0;
    #pragma unroll
    for (int k = 0; k < 3; ++k)
        #pragma unroll
        for (int c = 0; c < 7; ++c)
            val += (double)xr[k][c] * (double)token_w[(d * 7 + c) * 3 + k];
    double tmp = 0.0;
    #pragma unroll
    for (int m = 0; m < 4; ++m) tmp += (double)xmr[m] * (double)temp_w[d * 4 + m];
    // PE with fp32 rounding points as in the numpy reference:
    //   e   = fp32( fp32(2i) * fp32(-ln(10000)/512) )
    //   div = fp32( exp(e) )            (correctly-rounded via fp64 exp)
    //   ang = fp32( fp32(l) * div )
    //   pe  = sin/cos(ang)              (fp64 trig on the fp32 ang)
    const float cf = (float)(-9.210340371976184 / 512.0);
    float ef  = (float)(2 * (d >> 1)) * cf;
    float dvf = (float)exp((double)ef);
    float angf = (float)l * dvf;
    double pe = (d & 1) ? cos((double)angf) : sin((double)angf);
    H[((size_t)b * LTOT + l) * DM + d] = (float)(val + tmp + pe);
}

// ---------------------------------------------------------------------------
// C[M,N] = act( A[M,K] @ W[N,K]^T + bias + res )
// fp32 storage / LDS tiles, fp64 FMA + accumulation.
// ---------------------------------------------------------------------------
__global__ __launch_bounds__(256) void gemm_d(
    const float* __restrict__ A, const float* __restrict__ W,
    const float* __restrict__ bias, const float* __restrict__ res,
    float* __restrict__ C, int M, int N, int K, int act)
{
    __shared__ float As[16][64];
    __shared__ float Ws[16][64];
    const int tid = threadIdx.x;
    const int tx = tid & 15, ty = tid >> 4;
    const int n0 = blockIdx.x * 64, m0 = blockIdx.y * 64;
    const int lr = tid >> 2;           // 0..63
    const int lk = (tid & 3) << 2;     // 0,4,8,12
    const float* Ap = A + (size_t)(m0 + lr) * K + lk;
    const float* Wp = W + (size_t)(n0 + lr) * K + lk;
    double acc[4][4];
    #pragma unroll
    for (int i = 0; i < 4; ++i)
        #pragma unroll
        for (int j = 0; j < 4; ++j) acc[i][j] = 0.0;
    for (int kt = 0; kt < K; kt += 16) {
        float4 a4 = *(const float4*)(Ap + kt);
        float4 w4 = *(const float4*)(Wp + kt);
        __syncthreads();
        As[lk + 0][lr] = a4.x; As[lk + 1][lr] = a4.y;
        As[lk + 2][lr] = a4.z; As[lk + 3][lr] = a4.w;
        Ws[lk + 0][lr] = w4.x; Ws[lk + 1][lr] = w4.y;
        Ws[lk + 2][lr] = w4.z; Ws[lk + 3][lr] = w4.w;
        __syncthreads();
        #pragma unroll
        for (int kk = 0; kk < 16; ++kk) {
            float4 av = *(const float4*)&As[kk][ty << 2];
            float4 wv = *(const float4*)&Ws[kk][tx << 2];
            double ai[4] = {(double)av.x, (double)av.y, (double)av.z, (double)av.w};
            double wj[4] = {(double)wv.x, (double)wv.y, (double)wv.z, (double)wv.w};
            #pragma unroll
            for (int i = 0; i < 4; ++i)
                #pragma unroll
                for (int j = 0; j < 4; ++j)
                    acc[i][j] += ai[i] * wj[j];
        }
    }
    const int nb = n0 + (tx << 2);
    #pragma unroll
    for (int i = 0; i < 4; ++i) {
        int m = m0 + (ty << 2) + i;
        double v[4] = {acc[i][0], acc[i][1], acc[i][2], acc[i][3]};
        if (bias) {
            #pragma unroll
            for (int j = 0; j < 4; ++j) v[j] += (double)bias[nb + j];
        }
        if (res) {
            const float4 rv = *(const float4*)(res + (size_t)m * N + nb);
            v[0] += (double)rv.x; v[1] += (double)rv.y;
            v[2] += (double)rv.z; v[3] += (double)rv.w;
        }
        if (act == 1) {
            #pragma unroll
            for (int j = 0; j < 4; ++j) v[j] = gelu_d(v[j]);
        }
        *(float4*)(C + (size_t)m * N + nb) =
            make_float4((float)v[0], (float)v[1], (float)v[2], (float)v[3]);
    }
}

// ---------------------------------------------------------------------------
// LSH hashing: bucket = argmax over [R^T q, -R^T q]  (fp64 dots on fp32 data)
// grid: NBH * NHASH * 8 blocks of 256 (one thread per t)
// ---------------------------------------------------------------------------
__global__ __launch_bounds__(256) void lsh_hash_kernel(
    const float* __restrict__ QK, const float* __restrict__ rot,
    int* __restrict__ BKT)
{
    __shared__ float RT[128][65];   // [r][d], padded
    int bid = blockIdx.x;
    int tt = bid & 7;
    int h = (bid >> 3) & 3;
    int bh = bid >> 5;
    int tid = threadIdx.x;
    int t = tt * 256 + tid;
    int b = bh >> 3, hd = bh & 7;
    const float* qbase = QK + ((size_t)(b * LTOT + t)) * DM + hd * DH;
    float qf[64];
    #pragma unroll
    for (int d4 = 0; d4 < 16; ++d4) {
        float4 q4 = *(const float4*)(qbase + d4 * 4);
        qf[d4 * 4 + 0] = q4.x; qf[d4 * 4 + 1] = q4.y;
        qf[d4 * 4 + 2] = q4.z; qf[d4 * 4 + 3] = q4.w;
    }
    double bestP = -1e300, bestN = -1e300;
    int bp = 0, bn = 0;
    for (int half = 0; half < 2; ++half) {
        __syncthreads();
        for (int idx = tid; idx < 128 * 64; idx += 256) {
            int d = idx >> 7, r = idx & 127;
            RT[r][d] = rot[(d * 4 + h) * 256 + half * 128 + r];
        }
        __syncthreads();
        for (int r = 0; r < 128; ++r) {
            double acc = 0.0;
            #pragma unroll
            for (int d = 0; d < 64; ++d)
                acc += (double)qf[d] * (double)RT[r][d];
            int gr = half * 128 + r;
            if (acc > bestP)  { bestP = acc;  bp = gr; }
            if (-acc > bestN) { bestN = -acc; bn = gr; }
        }
    }
    int bucket = (bestN > bestP) ? (256 + bn) : bp;  // tie -> positive half
    BKT[((size_t)bh * NHASH + h) * LTOT + t] = bucket;
}

// ---------------------------------------------------------------------------
// Stable counting sort per (bh, hash): sorted-by-(bucket, t).
// ---------------------------------------------------------------------------
__global__ __launch_bounds__(256) void lsh_sort_kernel(
    const int* __restrict__ BKT, int* __restrict__ STS)
{
    __shared__ unsigned short bkt[2048];
    __shared__ unsigned int hist2[16][512];
    __shared__ unsigned int bstart[512];
    int bid = blockIdx.x;
    int h = bid & 3, bh = bid >> 2;
    int tid = threadIdx.x;
    const int* src = BKT + ((size_t)bh * NHASH + h) * LTOT;
    for (int t = tid; t < 2048; t += 256) bkt[t] = (unsigned short)src[t];
    for (int i = tid; i < 16 * 512; i += 256) (&hist2[0][0])[i] = 0u;
    __syncthreads();
    for (int t = tid; t < 2048; t += 256)
        atomicAdd(&hist2[t >> 7][bkt[t]], 1u);
    __syncthreads();
    for (int bb = tid; bb < 512; bb += 256) {
        unsigned int run = 0;
        #pragma unroll
        for (int g = 0; g < 16; ++g) {
            unsigned int c = hist2[g][bb];
            hist2[g][bb] = run;
            run += c;
        }
        bstart[bb] = run;
    }
    __syncthreads();
    if (tid == 0) {
        unsigned int run = 0;
        for (int bb = 0; bb < 512; ++bb) {
            unsigned int c = bstart[bb];
            bstart[bb] = run;
            run += c;
        }
    }
    __syncthreads();
    int* dst = STS + (size_t)bh * (NHASH * LTOT) + h * LTOT;
    for (int t = tid; t < 2048; t += 256) {
        int bb = bkt[t];
        unsigned int rank = hist2[t >> 7][bb];
        int g0 = t & ~127;
        for (int u = g0; u < t; ++u) rank += (bkt[u] == (unsigned short)bb);
        dst[bstart[bb] + rank] = t;
    }
}

// ---------------------------------------------------------------------------
// Pass A: per sorted position, logsumexp of the 4x8 chunk dots (fp64 math).
// ---------------------------------------------------------------------------
__global__ __launch_bounds__(256) void attn_lse_kernel(
    const float* __restrict__ QK, const int* __restrict__ STS,
    float* __restrict__ LSE)
{
    int gid = blockIdx.x * 256 + threadIdx.x;
    int bh = gid >> 13;
    int rem = gid & 8191;
    int c = rem >> 2, i = rem & 3;
    int cp = (c + NCH - 1) & (NCH - 1);
    const int* sts = STS + (size_t)bh * 8192;
    int tq = sts[4 * c + i];
    int b = bh >> 3, hd = bh & 7;
    const float* base = QK + ((size_t)b * LTOT) * DM + hd * DH;
    const float* qrow = base + (size_t)tq * DM;
    float qv[64];
    #pragma unroll
    for (int d4 = 0; d4 < 16; ++d4) {
        float4 q4 = *(const float4*)(qrow + d4 * 4);
        qv[d4 * 4 + 0] = q4.x; qv[d4 * 4 + 1] = q4.y;
        qv[d4 * 4 + 2] = q4.z; qv[d4 * 4 + 3] = q4.w;
    }
    double dots[8];
    #pragma unroll
    for (int j = 0; j < 8; ++j) {
        int kp = (j < 4) ? (4 * c + j) : (4 * cp + j - 4);
        int tk = sts[kp];
        const float* krow = base + (size_t)tk * DM;
        double dot = 0.0, nsq = 0.0;
        #pragma unroll
        for (int d = 0; d < 64; ++d) {
            double kv = (double)krow[d];
            dot += (double)qv[d] * kv;
            nsq += kv * kv;
        }
        double nrm = fmax(sqrt(nsq), 1e-12);
        dots[j] = (tk == tq) ? -5e4 : dot * 0.125 / nrm;
    }
    double m = dots[0];
    #pragma unroll
    for (int j = 1; j < 8; ++j) m = fmax(m, dots[j]);
    double s = 0.0;
    #pragma unroll
    for (int j = 0; j < 8; ++j) s += exp(dots[j] - m);
    double lse = m + log(s);
    int hr = c >> 9;
    LSE[((size_t)bh * NHASH + hr) * LTOT + tq] = (float)lse;
}

// ---------------------------------------------------------------------------
// Pass B: recompute probs (fp64), weight by hash-round softmax, fp32 atomics.
// ---------------------------------------------------------------------------
__global__ __launch_bounds__(256) void attn_out_kernel(
    const float* __restrict__ QK, const float* __restrict__ V,
    const int* __restrict__ STS, const float* __restrict__ LSE,
    float* __restrict__ C)
{
    int gid = blockIdx.x * 256 + threadIdx.x;
    int bh = gid >> 13;
    int rem = gid & 8191;
    int c = rem >> 2, i = rem & 3;
    int cp = (c + NCH - 1) & (NCH - 1);
    const int* sts = STS + (size_t)bh * 8192;
    int tq = sts[4 * c + i];
    int b = bh >> 3, hd = bh & 7;
    const float* base = QK + ((size_t)b * LTOT) * DM + hd * DH;
    const float* qrow = base + (size_t)tq * DM;
    float qv[64];
    #pragma unroll
    for (int d4 = 0; d4 < 16; ++d4) {
        float4 q4 = *(const float4*)(qrow + d4 * 4);
        qv[d4 * 4 + 0] = q4.x; qv[d4 * 4 + 1] = q4.y;
        qv[d4 * 4 + 2] = q4.z; qv[d4 * 4 + 3] = q4.w;
    }
    int tks[8];
    double p[8];
    {
        double dots[8];
        #pragma unroll
        for (int j = 0; j < 8; ++j) {
            int kp = (j < 4) ? (4 * c + j) : (4 * cp + j - 4);
            int tk = sts[kp];
            tks[j] = tk;
            const float* krow = base + (size_t)tk * DM;
            double dot = 0.0, nsq = 0.0;
            #pragma unroll
            for (int d = 0; d < 64; ++d) {
                double kv = (double)krow[d];
                dot += (double)qv[d] * kv;
                nsq += kv * kv;
            }
            double nrm = fmax(sqrt(nsq), 1e-12);
            dots[j] = (tk == tq) ? -5e4 : dot * 0.125 / nrm;
        }
        int hr = c >> 9;
        double Lh[4];
        #pragma unroll
        for (int hh = 0; hh < 4; ++hh)
            Lh[hh] = (double)LSE[((size_t)bh * NHASH + hh) * LTOT + tq];
        double my = Lh[hr];
        double wm = fmax(fmax(Lh[0], Lh[1]), fmax(Lh[2], Lh[3]));
        double wsum = 0.0;
        #pragma unroll
        for (int hh = 0; hh < 4; ++hh) wsum += exp(Lh[hh] - wm);
        double w = exp(my - wm) / wsum;
        #pragma unroll
        for (int j = 0; j < 8; ++j) p[j] = exp(dots[j] - my) * w;
    }
    const float* vbase = V + ((size_t)b * LTOT) * DM + hd * DH;
    float* crow = C + ((size_t)(b * LTOT + tq)) * DM + hd * DH;
    #pragma unroll
    for (int half = 0; half < 2; ++half) {
        double acc[32];
        #pragma unroll
        for (int d = 0; d < 32; ++d) acc[d] = 0.0;
        #pragma unroll
        for (int j = 0; j < 8; ++j) {
            const float* vrow = vbase + (size_t)tks[j] * DM + half * 32;
            #pragma unroll
            for (int d = 0; d < 32; ++d) acc[d] += p[j] * (double)vrow[d];
        }
        #pragma unroll
        for (int d = 0; d < 32; ++d)
            atomicAdd(crow + half * 32 + d, (float)acc[d]);
    }
}

// ---------------------------------------------------------------------------
// LayerNorm over last dim (512). fp64 stats + transform, fp32 out.
// ---------------------------------------------------------------------------
__global__ __launch_bounds__(256) void ln_kernel(
    const float* __restrict__ X, float* __restrict__ Y,
    const float* __restrict__ g, const float* __restrict__ bta)
{
    int row = blockIdx.x;
    int tid = threadIdx.x;
    const float* x = X + (size_t)row * DM;
    double v0 = (double)x[tid], v1 = (double)x[tid + 256];
    double s = v0 + v1;
    double q = v0 * v0 + v1 * v1;
    #pragma unroll
    for (int off = 32; off; off >>= 1) {
        s += __shfl_down(s, off, 64);
        q += __shfl_down(q, off, 64);
    }
    __shared__ double ss[4], qq[4];
    int wid = tid >> 6, lane = tid & 63;
    if (lane == 0) { ss[wid] = s; qq[wid] = q; }
    __syncthreads();
    if (tid == 0) {
        double S = ss[0] + ss[1] + ss[2] + ss[3];
        double Q = qq[0] + qq[1] + qq[2] + qq[3];
        double mu = S * (1.0 / 512.0);
        double var = Q * (1.0 / 512.0) - mu * mu;
        ss[0] = mu;
        qq[0] = 1.0 / sqrt(var + 1e-5);
    }
    __syncthreads();
    double mu = ss[0], rs = qq[0];
    Y[(size_t)row * DM + tid] =
        (float)((v0 - mu) * rs * (double)g[tid] + (double)bta[tid]);
    Y[(size_t)row * DM + tid + 256] =
        (float)((v1 - mu) * rs * (double)g[tid + 256] + (double)bta[tid + 256]);
}

// ---------------------------------------------------------------------------
// Final projection + slice (fp64 acc, fp32 out).
// ---------------------------------------------------------------------------
__global__ __launch_bounds__(64) void proj_kernel(
    const float* __restrict__ Hf, const float* __restrict__ pw,
    const float* __restrict__ pb, float* __restrict__ out)
{
    int idx = blockIdx.x;               // 0..4095
    int b = idx >> 9, i = idx & 511;
    const float* row = Hf + ((size_t)(b * LTOT + SEQ + i)) * DM;
    int lane = threadIdx.x;
    double s = 0.0;
    #pragma unroll
    for (int k = 0; k < 8; ++k)
        s += (double)row[lane + 64 * k] * (double)pw[lane + 64 * k];
    #pragma unroll
    for (int off = 32; off; off >>= 1) s += __shfl_down(s, off, 64);
    if (lane == 0) out[idx] = (float)(s + (double)pb[0]);
}

// ---------------------------------------------------------------------------
extern "C" void kernel_launch(void* const* d_in, const int* in_sizes, int n_in,
                              void* d_out, int out_size, void* d_ws, size_t ws_size,
                              hipStream_t stream)
{
    const float* x_enc      = (const float*)d_in[0];
    const float* x_mark_enc = (const float*)d_in[1];
    const float* x_dec      = (const float*)d_in[2];
    const float* x_mark_dec = (const float*)d_in[3];
    const float* token_w    = (const float*)d_in[4];
    const float* temp_w     = (const float*)d_in[5];
    const float* qk_w       = (const float*)d_in[6];
    const float* v_w        = (const float*)d_in[7];
    const float* out_w      = (const float*)d_in[8];
    const float* out_b      = (const float*)d_in[9];
    const float* ln1_g      = (const float*)d_in[10];
    const float* ln1_b      = (const float*)d_in[11];
    const float* ff1_w      = (const float*)d_in[12];
    const float* ff1_b      = (const float*)d_in[13];
    const float* ff2_w      = (const float*)d_in[14];
    const float* ff2_b      = (const float*)d_in[15];
    const float* ln2_g      = (const float*)d_in[16];
    const float* ln2_b      = (const float*)d_in[17];
    const float* norm_g     = (const float*)d_in[18];
    const float* norm_b     = (const float*)d_in[19];
    const float* proj_w     = (const float*)d_in[20];
    const float* proj_b     = (const float*)d_in[21];
    const float* rotations  = (const float*)d_in[22];

    float* ws = (float*)d_ws;
    const size_t S = (size_t)BATCH * LTOT * DM;   // 8,388,608 floats
    float* Hb  = ws;
    float* QKb = ws + S;
    float* Vb  = ws + 2 * S;
    float* Cb  = ws + 3 * S;
    float* Yb  = QKb;                    // FFN intermediate aliases QK
    int*   BKTb = (int*)(ws + 4 * S);              // 2 MB
    float* LSEb = ws + 4 * S + 524288;             // 2 MB
    int*   STSb = (int*)(ws + 4 * S + 2 * 524288); // 2 MB

    build_h_kernel<<<BATCH * LTOT, 512, 0, stream>>>(
        x_enc, x_mark_enc, x_dec, x_mark_dec, token_w, temp_w, Hb);

    const int M = BATCH * LTOT;  // 16384
    for (int l = 0; l < 2; ++l) {
        const float* qkw = qk_w + (size_t)l * DM * DM;
        const float* vw  = v_w  + (size_t)l * DM * DM;
        const float* ow  = out_w + (size_t)l * DM * DM;
        const float* ob  = out_b + (size_t)l * DM;
        const float* l1g = ln1_g + (size_t)l * DM;
        const float* l1b = ln1_b + (size_t)l * DM;
        const float* f1w = ff1_w + (size_t)l * DFF * DM;
        const float* f1b = ff1_b + (size_t)l * DFF;
        const float* f2w = ff2_w + (size_t)l * DM * DFF;
        const float* f2b = ff2_b + (size_t)l * DM;
        const float* l2g = ln2_g + (size_t)l * DM;
        const float* l2b = ln2_b + (size_t)l * DM;
        const float* rot = rotations + (size_t)l * DH * NHASH * 256;

        dim3 g1(DM / 64, M / 64);  // (8, 256)
        gemm_d<<<g1, 256, 0, stream>>>(Hb, qkw, nullptr, nullptr, QKb, M, DM, DM, 0);
        gemm_d<<<g1, 256, 0, stream>>>(Hb, vw,  nullptr, nullptr, Vb,  M, DM, DM, 0);

        lsh_hash_kernel<<<NBH * NHASH * 8, 256, 0, stream>>>(QKb, rot, BKTb);
        lsh_sort_kernel<<<NBH * NHASH, 256, 0, stream>>>(BKTb, STSb);

        hipMemsetAsync(Cb, 0, S * sizeof(float), stream);
        attn_lse_kernel<<<2048, 256, 0, stream>>>(QKb, STSb, LSEb);
        attn_out_kernel<<<2048, 256, 0, stream>>>(QKb, Vb, STSb, LSEb, Cb);

        // h = h + attn @ out_w^T + out_b   (in-place residual)
        gemm_d<<<g1, 256, 0, stream>>>(Cb, ow, ob, Hb, Hb, M, DM, DM, 0);
        ln_kernel<<<M, 256, 0, stream>>>(Hb, Hb, l1g, l1b);

        // FFN, tiled over 4 row-blocks of 4096 (intermediate aliases QKb)
        for (int mb = 0; mb < 4; ++mb) {
            const float* hpart = Hb + (size_t)mb * 4096 * DM;
            float* cpart = Cb + (size_t)mb * 4096 * DM;
            dim3 g2(DFF / 64, 4096 / 64);  // (32, 64)
            gemm_d<<<g2, 256, 0, stream>>>(hpart, f1w, f1b, nullptr, Yb, 4096, DFF, DM, 1);
            dim3 g3(DM / 64, 4096 / 64);   // (8, 64)
            gemm_d<<<g3, 256, 0, stream>>>(Yb, f2w, f2b, hpart, cpart, 4096, DM, DFF, 0);
        }
        ln_kernel<<<M, 256, 0, stream>>>(Cb, Hb, l2g, l2b);
    }

    ln_kernel<<<M, 256, 0, stream>>>(Hb, Cb, norm_g, norm_b);
    proj_kernel<<<4096, 64, 0, stream>>>(Cb, proj_w, proj_b, (float*)d_out);
}

// Round 6
// 8172.041 us; speedup vs baseline: 1.3428x; 1.3428x over previous
//
#include <hip/hip_runtime.h>
#include <math.h>

#define BATCH 8
#define LTOT 2048
#define DM 512
#define NHEADS 8
#define DH 64
#define NBH 64
#define NHASH 4
#define SEQ 1536
#define DECL 768
#define DFF 2048
#define NCH 2048   // total chunks (4 rounds * 512)

static __device__ __forceinline__ double gelu_d(double x) {
    return 0.5 * x * (1.0 + erf(x * 0.70710678118654752440));
}

// ---------------------------------------------------------------------------
// h = TokenConv(x) + TimeLinear(xm) + PE   -> H [B, L, 512]
// PE mimics numpy-fp32 rounding points: e, div, ang rounded to fp32.
// ---------------------------------------------------------------------------
__global__ __launch_bounds__(512) void build_h_kernel(
    const float* __restrict__ x_enc, const float* __restrict__ x_mark_enc,
    const float* __restrict__ x_dec, const float* __restrict__ x_mark_dec,
    const float* __restrict__ token_w, const float* __restrict__ temp_w,
    float* __restrict__ H)
{
    int bl = blockIdx.x;
    int b = bl >> 11, l = bl & 2047;
    __shared__ float xr[3][7];
    __shared__ float xmr[4];
    int tid = threadIdx.x;
    if (tid < 21) {
        int k = tid / 7, c = tid % 7;
        int t = (l + k - 1 + LTOT) & 2047;
        float v;
        if (t < SEQ) v = x_enc[(b * SEQ + t) * 7 + c];
        else         v = x_dec[(b * DECL + (t - 1280)) * 7 + c];
        xr[k][c] = v;
    } else if (tid < 25) {
        int m = tid - 21;
        float v;
        if (l < SEQ) v = x_mark_enc[(b * SEQ + l) * 4 + m];
        else         v = x_mark_dec[(b * DECL + (l - 1280)) * 4 + m];
        xmr[m] = v;
    }
    __syncthreads();
    int d = tid;  // 0..511
    double val = 0.0;
    #pragma unroll
    for (int k = 0; k < 3; ++k)
        #pragma unroll
        for (int c = 0; c < 7; ++c)
            val += (double)xr[k][c] * (double)token_w[(d * 7 + c) * 3 + k];
    double tmp = 0.0;
    #pragma unroll
    for (int m = 0; m < 4; ++m) tmp += (double)xmr[m] * (double)temp_w[d * 4 + m];
    const float cf = (float)(-9.210340371976184 / 512.0);
    float ef  = (float)(2 * (d >> 1)) * cf;
    float dvf = (float)exp((double)ef);
    float angf = (float)l * dvf;
    double pe = (d & 1) ? cos((double)angf) : sin((double)angf);
    H[((size_t)b * LTOT + l) * DM + d] = (float)(val + tmp + pe);
}

// ---------------------------------------------------------------------------
// C[M,N] = act( A[M,K] @ W[N,K]^T + bias + res )
// fp32 FMA inner tiles, fp64 accumulator flush per K=16 (noise ~2.4e-7).
// ---------------------------------------------------------------------------
__global__ __launch_bounds__(256) void gemm_d(
    const float* __restrict__ A, const float* __restrict__ W,
    const float* __restrict__ bias, const float* __restrict__ res,
    float* __restrict__ C, int M, int N, int K, int act)
{
    __shared__ float As[16][64];
    __shared__ float Ws[16][64];
    const int tid = threadIdx.x;
    const int tx = tid & 15, ty = tid >> 4;
    const int n0 = blockIdx.x * 64, m0 = blockIdx.y * 64;
    const int lr = tid >> 2;           // 0..63
    const int lk = (tid & 3) << 2;     // 0,4,8,12
    const float* Ap = A + (size_t)(m0 + lr) * K + lk;
    const float* Wp = W + (size_t)(n0 + lr) * K + lk;
    double acc2[4][4];
    #pragma unroll
    for (int i = 0; i < 4; ++i)
        #pragma unroll
        for (int j = 0; j < 4; ++j) acc2[i][j] = 0.0;
    for (int kt = 0; kt < K; kt += 16) {
        float4 a4 = *(const float4*)(Ap + kt);
        float4 w4 = *(const float4*)(Wp + kt);
        __syncthreads();
        As[lk + 0][lr] = a4.x; As[lk + 1][lr] = a4.y;
        As[lk + 2][lr] = a4.z; As[lk + 3][lr] = a4.w;
        Ws[lk + 0][lr] = w4.x; Ws[lk + 1][lr] = w4.y;
        Ws[lk + 2][lr] = w4.z; Ws[lk + 3][lr] = w4.w;
        __syncthreads();
        float acc[4][4];
        #pragma unroll
        for (int i = 0; i < 4; ++i)
            #pragma unroll
            for (int j = 0; j < 4; ++j) acc[i][j] = 0.f;
        #pragma unroll
        for (int kk = 0; kk < 16; ++kk) {
            float4 av = *(const float4*)&As[kk][ty << 2];
            float4 wv = *(const float4*)&Ws[kk][tx << 2];
            float ai[4] = {av.x, av.y, av.z, av.w};
            float wj[4] = {wv.x, wv.y, wv.z, wv.w};
            #pragma unroll
            for (int i = 0; i < 4; ++i)
                #pragma unroll
                for (int j = 0; j < 4; ++j)
                    acc[i][j] += ai[i] * wj[j];
        }
        #pragma unroll
        for (int i = 0; i < 4; ++i)
            #pragma unroll
            for (int j = 0; j < 4; ++j) acc2[i][j] += (double)acc[i][j];
    }
    const int nb = n0 + (tx << 2);
    #pragma unroll
    for (int i = 0; i < 4; ++i) {
        int m = m0 + (ty << 2) + i;
        double v[4] = {acc2[i][0], acc2[i][1], acc2[i][2], acc2[i][3]};
        if (bias) {
            #pragma unroll
            for (int j = 0; j < 4; ++j) v[j] += (double)bias[nb + j];
        }
        if (res) {
            const float4 rv = *(const float4*)(res + (size_t)m * N + nb);
            v[0] += (double)rv.x; v[1] += (double)rv.y;
            v[2] += (double)rv.z; v[3] += (double)rv.w;
        }
        if (act == 1) {
            #pragma unroll
            for (int j = 0; j < 4; ++j) v[j] = gelu_d(v[j]);
        }
        *(float4*)(C + (size_t)m * N + nb) =
            make_float4((float)v[0], (float)v[1], (float)v[2], (float)v[3]);
    }
}

// ---------------------------------------------------------------------------
// LSH hashing: bucket = argmax over [R^T q, -R^T q]  (fp64 dots on fp32 data)
// ---------------------------------------------------------------------------
__global__ __launch_bounds__(256) void lsh_hash_kernel(
    const float* __restrict__ QK, const float* __restrict__ rot,
    int* __restrict__ BKT)
{
    __shared__ float RT[128][65];   // [r][d], padded
    int bid = blockIdx.x;
    int tt = bid & 7;
    int h = (bid >> 3) & 3;
    int bh = bid >> 5;
    int tid = threadIdx.x;
    int t = tt * 256 + tid;
    int b = bh >> 3, hd = bh & 7;
    const float* qbase = QK + ((size_t)(b * LTOT + t)) * DM + hd * DH;
    float qf[64];
    #pragma unroll
    for (int d4 = 0; d4 < 16; ++d4) {
        float4 q4 = *(const float4*)(qbase + d4 * 4);
        qf[d4 * 4 + 0] = q4.x; qf[d4 * 4 + 1] = q4.y;
        qf[d4 * 4 + 2] = q4.z; qf[d4 * 4 + 3] = q4.w;
    }
    double bestP = -1e300, bestN = -1e300;
    int bp = 0, bn = 0;
    for (int half = 0; half < 2; ++half) {
        __syncthreads();
        for (int idx = tid; idx < 128 * 64; idx += 256) {
            int d = idx >> 7, r = idx & 127;
            RT[r][d] = rot[(d * 4 + h) * 256 + half * 128 + r];
        }
        __syncthreads();
        for (int r = 0; r < 128; ++r) {
            double acc = 0.0;
            #pragma unroll
            for (int d = 0; d < 64; ++d)
                acc += (double)qf[d] * (double)RT[r][d];
            int gr = half * 128 + r;
            if (acc > bestP)  { bestP = acc;  bp = gr; }
            if (-acc > bestN) { bestN = -acc; bn = gr; }
        }
    }
    int bucket = (bestN > bestP) ? (256 + bn) : bp;  // tie -> positive half
    BKT[((size_t)bh * NHASH + h) * LTOT + t] = bucket;
}

// ---------------------------------------------------------------------------
// Stable counting sort per (bh, hash): sorted-by-(bucket, t).
// ---------------------------------------------------------------------------
__global__ __launch_bounds__(256) void lsh_sort_kernel(
    const int* __restrict__ BKT, int* __restrict__ STS)
{
    __shared__ unsigned short bkt[2048];
    __shared__ unsigned int hist2[16][512];
    __shared__ unsigned int bstart[512];
    int bid = blockIdx.x;
    int h = bid & 3, bh = bid >> 2;
    int tid = threadIdx.x;
    const int* src = BKT + ((size_t)bh * NHASH + h) * LTOT;
    for (int t = tid; t < 2048; t += 256) bkt[t] = (unsigned short)src[t];
    for (int i = tid; i < 16 * 512; i += 256) (&hist2[0][0])[i] = 0u;
    __syncthreads();
    for (int t = tid; t < 2048; t += 256)
        atomicAdd(&hist2[t >> 7][bkt[t]], 1u);
    __syncthreads();
    for (int bb = tid; bb < 512; bb += 256) {
        unsigned int run = 0;
        #pragma unroll
        for (int g = 0; g < 16; ++g) {
            unsigned int c = hist2[g][bb];
            hist2[g][bb] = run;
            run += c;
        }
        bstart[bb] = run;
    }
    __syncthreads();
    if (tid == 0) {
        unsigned int run = 0;
        for (int bb = 0; bb < 512; ++bb) {
            unsigned int c = bstart[bb];
            bstart[bb] = run;
            run += c;
        }
    }
    __syncthreads();
    int* dst = STS + (size_t)bh * (NHASH * LTOT) + h * LTOT;
    for (int t = tid; t < 2048; t += 256) {
        int bb = bkt[t];
        unsigned int rank = hist2[t >> 7][bb];
        int g0 = t & ~127;
        for (int u = g0; u < t; ++u) rank += (bkt[u] == (unsigned short)bb);
        dst[bstart[bb] + rank] = t;
    }
}

// ---------------------------------------------------------------------------
// Attention pass A: one wave per (bh, chunk); lane = dim. Coalesced row loads,
// fp64 butterfly reductions. Writes LSE[bh][hr][t].
// ---------------------------------------------------------------------------
__global__ __launch_bounds__(256) void attn_lse_kernel(
    const float* __restrict__ QK, const int* __restrict__ STS,
    float* __restrict__ LSE)
{
    int wid = (blockIdx.x * 256 + threadIdx.x) >> 6;   // global wave id
    int lane = threadIdx.x & 63;
    int bh = wid >> 11;          // 0..63
    int c  = wid & 2047;
    int cp = (c + NCH - 1) & (NCH - 1);
    const int* sts = STS + (size_t)bh * 8192;
    int tok[8];
    #pragma unroll
    for (int j = 0; j < 4; ++j) tok[j] = sts[4 * c + j];
    #pragma unroll
    for (int j = 0; j < 4; ++j) tok[4 + j] = sts[4 * cp + j];
    int b = bh >> 3, hd = bh & 7;
    const float* base = QK + ((size_t)b * LTOT) * DM + hd * DH + lane;
    double kd[8];
    #pragma unroll
    for (int j = 0; j < 8; ++j) kd[j] = (double)base[(size_t)tok[j] * DM];
    double rnrm[8];
    #pragma unroll
    for (int j = 0; j < 8; ++j) {
        double v = kd[j] * kd[j];
        #pragma unroll
        for (int m = 32; m; m >>= 1) v += __shfl_xor(v, m, 64);
        rnrm[j] = 0.125 / fmax(sqrt(v), 1e-12);
    }
    int hr = c >> 9;
    #pragma unroll
    for (int i = 0; i < 4; ++i) {
        double dots[8];
        #pragma unroll
        for (int j = 0; j < 8; ++j) {
            double v = kd[i] * kd[j];
            #pragma unroll
            for (int m = 32; m; m >>= 1) v += __shfl_xor(v, m, 64);
            dots[j] = (tok[j] == tok[i]) ? -5e4 : v * rnrm[j];
        }
        double mx = dots[0];
        #pragma unroll
        for (int j = 1; j < 8; ++j) mx = fmax(mx, dots[j]);
        double s = 0.0;
        #pragma unroll
        for (int j = 0; j < 8; ++j) s += exp(dots[j] - mx);
        if (lane == 0)
            LSE[((size_t)bh * NHASH + hr) * LTOT + tok[i]] = (float)(mx + log(s));
    }
}

// ---------------------------------------------------------------------------
// Attention pass B: recompute dots, hash-round softmax weights, fp32 atomics.
// One wave per (bh, chunk); lane = dim.
// ---------------------------------------------------------------------------
__global__ __launch_bounds__(256) void attn_out_kernel(
    const float* __restrict__ QK, const float* __restrict__ V,
    const int* __restrict__ STS, const float* __restrict__ LSE,
    float* __restrict__ C)
{
    int wid = (blockIdx.x * 256 + threadIdx.x) >> 6;
    int lane = threadIdx.x & 63;
    int bh = wid >> 11;
    int c  = wid & 2047;
    int cp = (c + NCH - 1) & (NCH - 1);
    const int* sts = STS + (size_t)bh * 8192;
    int tok[8];
    #pragma unroll
    for (int j = 0; j < 4; ++j) tok[j] = sts[4 * c + j];
    #pragma unroll
    for (int j = 0; j < 4; ++j) tok[4 + j] = sts[4 * cp + j];
    int b = bh >> 3, hd = bh & 7;
    const float* base = QK + ((size_t)b * LTOT) * DM + hd * DH + lane;
    const float* vbase = V + ((size_t)b * LTOT) * DM + hd * DH + lane;
    double kd[8], vd[8];
    #pragma unroll
    for (int j = 0; j < 8; ++j) kd[j] = (double)base[(size_t)tok[j] * DM];
    #pragma unroll
    for (int j = 0; j < 8; ++j) vd[j] = (double)vbase[(size_t)tok[j] * DM];
    double rnrm[8];
    #pragma unroll
    for (int j = 0; j < 8; ++j) {
        double v = kd[j] * kd[j];
        #pragma unroll
        for (int m = 32; m; m >>= 1) v += __shfl_xor(v, m, 64);
        rnrm[j] = 0.125 / fmax(sqrt(v), 1e-12);
    }
    int hr = c >> 9;
    float* crow0 = C + ((size_t)b * LTOT) * DM + hd * DH + lane;
    #pragma unroll
    for (int i = 0; i < 4; ++i) {
        double dots[8];
        #pragma unroll
        for (int j = 0; j < 8; ++j) {
            double v = kd[i] * kd[j];
            #pragma unroll
            for (int m = 32; m; m >>= 1) v += __shfl_xor(v, m, 64);
            dots[j] = (tok[j] == tok[i]) ? -5e4 : v * rnrm[j];
        }
        double Lh[4];
        #pragma unroll
        for (int hh = 0; hh < 4; ++hh)
            Lh[hh] = (double)LSE[((size_t)bh * NHASH + hh) * LTOT + tok[i]];
        double my = Lh[hr];
        double wm = fmax(fmax(Lh[0], Lh[1]), fmax(Lh[2], Lh[3]));
        double wsum = 0.0;
        #pragma unroll
        for (int hh = 0; hh < 4; ++hh) wsum += exp(Lh[hh] - wm);
        double w = exp(my - wm) / wsum;
        double acc = 0.0;
        #pragma unroll
        for (int j = 0; j < 8; ++j) acc += exp(dots[j] - my) * vd[j];
        atomicAdd(crow0 + (size_t)tok[i] * DM, (float)(acc * w));
    }
}

// ---------------------------------------------------------------------------
// LayerNorm over last dim (512). fp64 stats + transform, fp32 out.
// ---------------------------------------------------------------------------
__global__ __launch_bounds__(256) void ln_kernel(
    const float* __restrict__ X, float* __restrict__ Y,
    const float* __restrict__ g, const float* __restrict__ bta)
{
    int row = blockIdx.x;
    int tid = threadIdx.x;
    const float* x = X + (size_t)row * DM;
    double v0 = (double)x[tid], v1 = (double)x[tid + 256];
    double s = v0 + v1;
    double q = v0 * v0 + v1 * v1;
    #pragma unroll
    for (int off = 32; off; off >>= 1) {
        s += __shfl_down(s, off, 64);
        q += __shfl_down(q, off, 64);
    }
    __shared__ double ss[4], qq[4];
    int wid = tid >> 6, lane = tid & 63;
    if (lane == 0) { ss[wid] = s; qq[wid] = q; }
    __syncthreads();
    if (tid == 0) {
        double S = ss[0] + ss[1] + ss[2] + ss[3];
        double Q = qq[0] + qq[1] + qq[2] + qq[3];
        double mu = S * (1.0 / 512.0);
        double var = Q * (1.0 / 512.0) - mu * mu;
        ss[0] = mu;
        qq[0] = 1.0 / sqrt(var + 1e-5);
    }
    __syncthreads();
    double mu = ss[0], rs = qq[0];
    Y[(size_t)row * DM + tid] =
        (float)((v0 - mu) * rs * (double)g[tid] + (double)bta[tid]);
    Y[(size_t)row * DM + tid + 256] =
        (float)((v1 - mu) * rs * (double)g[tid + 256] + (double)bta[tid + 256]);
}

// ---------------------------------------------------------------------------
// Final projection + slice (fp64 acc, fp32 out).
// ---------------------------------------------------------------------------
__global__ __launch_bounds__(64) void proj_kernel(
    const float* __restrict__ Hf, const float* __restrict__ pw,
    const float* __restrict__ pb, float* __restrict__ out)
{
    int idx = blockIdx.x;               // 0..4095
    int b = idx >> 9, i = idx & 511;
    const float* row = Hf + ((size_t)(b * LTOT + SEQ + i)) * DM;
    int lane = threadIdx.x;
    double s = 0.0;
    #pragma unroll
    for (int k = 0; k < 8; ++k)
        s += (double)row[lane + 64 * k] * (double)pw[lane + 64 * k];
    #pragma unroll
    for (int off = 32; off; off >>= 1) s += __shfl_down(s, off, 64);
    if (lane == 0) out[idx] = (float)(s + (double)pb[0]);
}

// ---------------------------------------------------------------------------
extern "C" void kernel_launch(void* const* d_in, const int* in_sizes, int n_in,
                              void* d_out, int out_size, void* d_ws, size_t ws_size,
                              hipStream_t stream)
{
    const float* x_enc      = (const float*)d_in[0];
    const float* x_mark_enc = (const float*)d_in[1];
    const float* x_dec      = (const float*)d_in[2];
    const float* x_mark_dec = (const float*)d_in[3];
    const float* token_w    = (const float*)d_in[4];
    const float* temp_w     = (const float*)d_in[5];
    const float* qk_w       = (const float*)d_in[6];
    const float* v_w        = (const float*)d_in[7];
    const float* out_w      = (const float*)d_in[8];
    const float* out_b      = (const float*)d_in[9];
    const float* ln1_g      = (const float*)d_in[10];
    const float* ln1_b      = (const float*)d_in[11];
    const float* ff1_w      = (const float*)d_in[12];
    const float* ff1_b      = (const float*)d_in[13];
    const float* ff2_w      = (const float*)d_in[14];
    const float* ff2_b      = (const float*)d_in[15];
    const float* ln2_g      = (const float*)d_in[16];
    const float* ln2_b      = (const float*)d_in[17];
    const float* norm_g     = (const float*)d_in[18];
    const float* norm_b     = (const float*)d_in[19];
    const float* proj_w     = (const float*)d_in[20];
    const float* proj_b     = (const float*)d_in[21];
    const float* rotations  = (const float*)d_in[22];

    float* ws = (float*)d_ws;
    const size_t S = (size_t)BATCH * LTOT * DM;   // 8,388,608 floats
    float* Hb  = ws;
    float* QKb = ws + S;
    float* Vb  = ws + 2 * S;
    float* Cb  = ws + 3 * S;
    float* Yb  = QKb;                    // FFN intermediate aliases QK
    int*   BKTb = (int*)(ws + 4 * S);              // 2 MB
    float* LSEb = ws + 4 * S + 524288;             // 2 MB
    int*   STSb = (int*)(ws + 4 * S + 2 * 524288); // 2 MB

    build_h_kernel<<<BATCH * LTOT, 512, 0, stream>>>(
        x_enc, x_mark_enc, x_dec, x_mark_dec, token_w, temp_w, Hb);

    const int M = BATCH * LTOT;  // 16384
    const int ATT_BLOCKS = NBH * NCH / 4;  // 32768 blocks of 4 waves
    for (int l = 0; l < 2; ++l) {
        const float* qkw = qk_w + (size_t)l * DM * DM;
        const float* vw  = v_w  + (size_t)l * DM * DM;
        const float* ow  = out_w + (size_t)l * DM * DM;
        const float* ob  = out_b + (size_t)l * DM;
        const float* l1g = ln1_g + (size_t)l * DM;
        const float* l1b = ln1_b + (size_t)l * DM;
        const float* f1w = ff1_w + (size_t)l * DFF * DM;
        const float* f1b = ff1_b + (size_t)l * DFF;
        const float* f2w = ff2_w + (size_t)l * DM * DFF;
        const float* f2b = ff2_b + (size_t)l * DM;
        const float* l2g = ln2_g + (size_t)l * DM;
        const float* l2b = ln2_b + (size_t)l * DM;
        const float* rot = rotations + (size_t)l * DH * NHASH * 256;

        dim3 g1(DM / 64, M / 64);  // (8, 256)
        gemm_d<<<g1, 256, 0, stream>>>(Hb, qkw, nullptr, nullptr, QKb, M, DM, DM, 0);
        gemm_d<<<g1, 256, 0, stream>>>(Hb, vw,  nullptr, nullptr, Vb,  M, DM, DM, 0);

        lsh_hash_kernel<<<NBH * NHASH * 8, 256, 0, stream>>>(QKb, rot, BKTb);
        lsh_sort_kernel<<<NBH * NHASH, 256, 0, stream>>>(BKTb, STSb);

        hipMemsetAsync(Cb, 0, S * sizeof(float), stream);
        attn_lse_kernel<<<ATT_BLOCKS, 256, 0, stream>>>(QKb, STSb, LSEb);
        attn_out_kernel<<<ATT_BLOCKS, 256, 0, stream>>>(QKb, Vb, STSb, LSEb, Cb);

        // h = h + attn @ out_w^T + out_b   (in-place residual)
        gemm_d<<<g1, 256, 0, stream>>>(Cb, ow, ob, Hb, Hb, M, DM, DM, 0);
        ln_kernel<<<M, 256, 0, stream>>>(Hb, Hb, l1g, l1b);

        // FFN, tiled over 4 row-blocks of 4096 (intermediate aliases QKb)
        for (int mb = 0; mb < 4; ++mb) {
            const float* hpart = Hb + (size_t)mb * 4096 * DM;
            float* cpart = Cb + (size_t)mb * 4096 * DM;
            dim3 g2(DFF / 64, 4096 / 64);  // (32, 64)
            gemm_d<<<g2, 256, 0, stream>>>(hpart, f1w, f1b, nullptr, Yb, 4096, DFF, DM, 1);
            dim3 g3(DM / 64, 4096 / 64);   // (8, 64)
            gemm_d<<<g3, 256, 0, stream>>>(Yb, f2w, f2b, hpart, cpart, 4096, DM, DFF, 0);
        }
        ln_kernel<<<M, 256, 0, stream>>>(Cb, Hb, l2g, l2b);
    }

    ln_kernel<<<M, 256, 0, stream>>>(Hb, Cb, norm_g, norm_b);
    proj_kernel<<<4096, 64, 0, stream>>>(Cb, proj_w, proj_b, (float*)d_out);
}

// Round 7
// 6776.884 us; speedup vs baseline: 1.6192x; 1.2059x over previous
//
#include <hip/hip_runtime.h>
#include <math.h>

#define BATCH 8
#define LTOT 2048
#define DM 512
#define NHEADS 8
#define DH 64
#define NBH 64
#define NHASH 4
#define SEQ 1536
#define DECL 768
#define DFF 2048
#define NCH 2048   // total chunks (4 rounds * 512)

static __device__ __forceinline__ double gelu_d(double x) {
    return 0.5 * x * (1.0 + erf(x * 0.70710678118654752440));
}

// ---------------------------------------------------------------------------
// h = TokenConv(x) + TimeLinear(xm) + PE   -> H [B, L, 512]
// PE mimics numpy-fp32 rounding points: e, div, ang rounded to fp32.
// ---------------------------------------------------------------------------
__global__ __launch_bounds__(512) void build_h_kernel(
    const float* __restrict__ x_enc, const float* __restrict__ x_mark_enc,
    const float* __restrict__ x_dec, const float* __restrict__ x_mark_dec,
    const float* __restrict__ token_w, const float* __restrict__ temp_w,
    float* __restrict__ H)
{
    int bl = blockIdx.x;
    int b = bl >> 11, l = bl & 2047;
    __shared__ float xr[3][7];
    __shared__ float xmr[4];
    int tid = threadIdx.x;
    if (tid < 21) {
        int k = tid / 7, c = tid % 7;
        int t = (l + k - 1 + LTOT) & 2047;
        float v;
        if (t < SEQ) v = x_enc[(b * SEQ + t) * 7 + c];
        else         v = x_dec[(b * DECL + (t - 1280)) * 7 + c];
        xr[k][c] = v;
    } else if (tid < 25) {
        int m = tid - 21;
        float v;
        if (l < SEQ) v = x_mark_enc[(b * SEQ + l) * 4 + m];
        else         v = x_mark_dec[(b * DECL + (l - 1280)) * 4 + m];
        xmr[m] = v;
    }
    __syncthreads();
    int d = tid;  // 0..511
    double val = 0.0;
    #pragma unroll
    for (int k = 0; k < 3; ++k)
        #pragma unroll
        for (int c = 0; c < 7; ++c)
            val += (double)xr[k][c] * (double)token_w[(d * 7 + c) * 3 + k];
    double tmp = 0.0;
    #pragma unroll
    for (int m = 0; m < 4; ++m) tmp += (double)xmr[m] * (double)temp_w[d * 4 + m];
    const float cf = (float)(-9.210340371976184 / 512.0);
    float ef  = (float)(2 * (d >> 1)) * cf;
    float dvf = (float)exp((double)ef);
    float angf = (float)l * dvf;
    double pe = (d & 1) ? cos((double)angf) : sin((double)angf);
    H[((size_t)b * LTOT + l) * DM + d] = (float)(val + tmp + pe);
}

// ---------------------------------------------------------------------------
// C[M,N] = act( A[M,K] @ W[N,K]^T + bias + res )
// 128x128 block, 8x8 per thread (two 4-row/4-col groups at stride 64).
// fp32 FMA + serial-k fp32 accumulate (flip-set proven stable to this noise);
// fp64 epilogue (bias/res/gelu) as before.
// ---------------------------------------------------------------------------
__global__ __launch_bounds__(256) void gemm_f32(
    const float* __restrict__ A, const float* __restrict__ W,
    const float* __restrict__ bias, const float* __restrict__ res,
    float* __restrict__ C, int M, int N, int K, int act)
{
    __shared__ float As[16][128];
    __shared__ float Ws[16][128];
    const int tid = threadIdx.x;
    const int tx = tid & 15, ty = tid >> 4;
    const int n0 = blockIdx.x * 128, m0 = blockIdx.y * 128;
    const int srow = tid >> 1;          // 0..127
    const int skoff = (tid & 1) * 8;    // 0 or 8
    const float* Ap = A + (size_t)(m0 + srow) * K + skoff;
    const float* Wp = W + (size_t)(n0 + srow) * K + skoff;
    float acc[8][8];
    #pragma unroll
    for (int i = 0; i < 8; ++i)
        #pragma unroll
        for (int j = 0; j < 8; ++j) acc[i][j] = 0.f;
    for (int kt = 0; kt < K; kt += 16) {
        float4 a0 = *(const float4*)(Ap + kt);
        float4 a1 = *(const float4*)(Ap + kt + 4);
        float4 w0 = *(const float4*)(Wp + kt);
        float4 w1 = *(const float4*)(Wp + kt + 4);
        __syncthreads();
        As[skoff + 0][srow] = a0.x; As[skoff + 1][srow] = a0.y;
        As[skoff + 2][srow] = a0.z; As[skoff + 3][srow] = a0.w;
        As[skoff + 4][srow] = a1.x; As[skoff + 5][srow] = a1.y;
        As[skoff + 6][srow] = a1.z; As[skoff + 7][srow] = a1.w;
        Ws[skoff + 0][srow] = w0.x; Ws[skoff + 1][srow] = w0.y;
        Ws[skoff + 2][srow] = w0.z; Ws[skoff + 3][srow] = w0.w;
        Ws[skoff + 4][srow] = w1.x; Ws[skoff + 5][srow] = w1.y;
        Ws[skoff + 6][srow] = w1.z; Ws[skoff + 7][srow] = w1.w;
        __syncthreads();
        #pragma unroll
        for (int kk = 0; kk < 16; ++kk) {
            float4 A0 = *(const float4*)&As[kk][ty * 4];
            float4 A1 = *(const float4*)&As[kk][ty * 4 + 64];
            float4 W0 = *(const float4*)&Ws[kk][tx * 4];
            float4 W1 = *(const float4*)&Ws[kk][tx * 4 + 64];
            float av[8] = {A0.x, A0.y, A0.z, A0.w, A1.x, A1.y, A1.z, A1.w};
            float wv[8] = {W0.x, W0.y, W0.z, W0.w, W1.x, W1.y, W1.z, W1.w};
            #pragma unroll
            for (int i = 0; i < 8; ++i)
                #pragma unroll
                for (int j = 0; j < 8; ++j)
                    acc[i][j] += av[i] * wv[j];
        }
    }
    #pragma unroll
    for (int ih = 0; ih < 2; ++ih) {
        #pragma unroll
        for (int i2 = 0; i2 < 4; ++i2) {
            const int i = ih * 4 + i2;
            const int m = m0 + ty * 4 + ih * 64 + i2;
            #pragma unroll
            for (int jh = 0; jh < 2; ++jh) {
                const int n = n0 + tx * 4 + jh * 64;
                double v[4];
                #pragma unroll
                for (int j2 = 0; j2 < 4; ++j2) v[j2] = (double)acc[i][jh * 4 + j2];
                if (bias) {
                    #pragma unroll
                    for (int j2 = 0; j2 < 4; ++j2) v[j2] += (double)bias[n + j2];
                }
                if (res) {
                    const float4 rv = *(const float4*)(res + (size_t)m * N + n);
                    v[0] += (double)rv.x; v[1] += (double)rv.y;
                    v[2] += (double)rv.z; v[3] += (double)rv.w;
                }
                if (act == 1) {
                    #pragma unroll
                    for (int j2 = 0; j2 < 4; ++j2) v[j2] = gelu_d(v[j2]);
                }
                *(float4*)(C + (size_t)m * N + n) =
                    make_float4((float)v[0], (float)v[1], (float)v[2], (float)v[3]);
            }
        }
    }
}

// ---------------------------------------------------------------------------
// LSH hashing: bucket = argmax over [R^T q, -R^T q]  (fp64 dots on fp32 data)
// float4 LDS reads (4 FMA per b128 broadcast), 4 independent fp64 chains.
// ---------------------------------------------------------------------------
__global__ __launch_bounds__(256) void lsh_hash_kernel(
    const float* __restrict__ QK, const float* __restrict__ rot,
    int* __restrict__ BKT)
{
    __shared__ float RT[128][68];   // [r][d], 16B-aligned rows
    int bid = blockIdx.x;
    int tt = bid & 7;
    int h = (bid >> 3) & 3;
    int bh = bid >> 5;
    int tid = threadIdx.x;
    int t = tt * 256 + tid;
    int b = bh >> 3, hd = bh & 7;
    const float* qbase = QK + ((size_t)(b * LTOT + t)) * DM + hd * DH;
    float qf[64];
    #pragma unroll
    for (int d4 = 0; d4 < 16; ++d4) {
        float4 q4 = *(const float4*)(qbase + d4 * 4);
        qf[d4 * 4 + 0] = q4.x; qf[d4 * 4 + 1] = q4.y;
        qf[d4 * 4 + 2] = q4.z; qf[d4 * 4 + 3] = q4.w;
    }
    double bestP = -1e300, bestN = -1e300;
    int bp = 0, bn = 0;
    for (int half = 0; half < 2; ++half) {
        __syncthreads();
        for (int idx = tid; idx < 128 * 64; idx += 256) {
            int d = idx >> 7, r = idx & 127;
            RT[r][d] = rot[(d * 4 + h) * 256 + half * 128 + r];
        }
        __syncthreads();
        for (int r = 0; r < 128; ++r) {
            double a0 = 0.0, a1 = 0.0, a2 = 0.0, a3 = 0.0;
            #pragma unroll
            for (int d4 = 0; d4 < 16; d4 += 4) {
                float4 r0 = *(const float4*)&RT[r][(d4 + 0) * 4];
                float4 r1 = *(const float4*)&RT[r][(d4 + 1) * 4];
                float4 r2 = *(const float4*)&RT[r][(d4 + 2) * 4];
                float4 r3 = *(const float4*)&RT[r][(d4 + 3) * 4];
                a0 += (double)qf[(d4+0)*4+0]*(double)r0.x + (double)qf[(d4+0)*4+1]*(double)r0.y
                    + (double)qf[(d4+0)*4+2]*(double)r0.z + (double)qf[(d4+0)*4+3]*(double)r0.w;
                a1 += (double)qf[(d4+1)*4+0]*(double)r1.x + (double)qf[(d4+1)*4+1]*(double)r1.y
                    + (double)qf[(d4+1)*4+2]*(double)r1.z + (double)qf[(d4+1)*4+3]*(double)r1.w;
                a2 += (double)qf[(d4+2)*4+0]*(double)r2.x + (double)qf[(d4+2)*4+1]*(double)r2.y
                    + (double)qf[(d4+2)*4+2]*(double)r2.z + (double)qf[(d4+2)*4+3]*(double)r2.w;
                a3 += (double)qf[(d4+3)*4+0]*(double)r3.x + (double)qf[(d4+3)*4+1]*(double)r3.y
                    + (double)qf[(d4+3)*4+2]*(double)r3.z + (double)qf[(d4+3)*4+3]*(double)r3.w;
            }
            double acc = (a0 + a1) + (a2 + a3);
            int gr = half * 128 + r;
            if (acc > bestP)  { bestP = acc;  bp = gr; }
            if (-acc > bestN) { bestN = -acc; bn = gr; }
        }
    }
    int bucket = (bestN > bestP) ? (256 + bn) : bp;  // tie -> positive half
    BKT[((size_t)bh * NHASH + h) * LTOT + t] = bucket;
}

// ---------------------------------------------------------------------------
// Stable counting sort per (bh, hash): sorted-by-(bucket, t).
// ---------------------------------------------------------------------------
__global__ __launch_bounds__(256) void lsh_sort_kernel(
    const int* __restrict__ BKT, int* __restrict__ STS)
{
    __shared__ unsigned short bkt[2048];
    __shared__ unsigned int hist2[16][512];
    __shared__ unsigned int bstart[512];
    int bid = blockIdx.x;
    int h = bid & 3, bh = bid >> 2;
    int tid = threadIdx.x;
    const int* src = BKT + ((size_t)bh * NHASH + h) * LTOT;
    for (int t = tid; t < 2048; t += 256) bkt[t] = (unsigned short)src[t];
    for (int i = tid; i < 16 * 512; i += 256) (&hist2[0][0])[i] = 0u;
    __syncthreads();
    for (int t = tid; t < 2048; t += 256)
        atomicAdd(&hist2[t >> 7][bkt[t]], 1u);
    __syncthreads();
    for (int bb = tid; bb < 512; bb += 256) {
        unsigned int run = 0;
        #pragma unroll
        for (int g = 0; g < 16; ++g) {
            unsigned int c = hist2[g][bb];
            hist2[g][bb] = run;
            run += c;
        }
        bstart[bb] = run;
    }
    __syncthreads();
    if (tid == 0) {
        unsigned int run = 0;
        for (int bb = 0; bb < 512; ++bb) {
            unsigned int c = bstart[bb];
            bstart[bb] = run;
            run += c;
        }
    }
    __syncthreads();
    int* dst = STS + (size_t)bh * (NHASH * LTOT) + h * LTOT;
    for (int t = tid; t < 2048; t += 256) {
        int bb = bkt[t];
        unsigned int rank = hist2[t >> 7][bb];
        int g0 = t & ~127;
        for (int u = g0; u < t; ++u) rank += (bkt[u] == (unsigned short)bb);
        dst[bstart[bb] + rank] = t;
    }
}

// ---------------------------------------------------------------------------
// Attention pass A: one wave per (bh, chunk); lane = dim.
// ---------------------------------------------------------------------------
__global__ __launch_bounds__(256) void attn_lse_kernel(
    const float* __restrict__ QK, const int* __restrict__ STS,
    float* __restrict__ LSE)
{
    int wid = (blockIdx.x * 256 + threadIdx.x) >> 6;   // global wave id
    int lane = threadIdx.x & 63;
    int bh = wid >> 11;          // 0..63
    int c  = wid & 2047;
    int cp = (c + NCH - 1) & (NCH - 1);
    const int* sts = STS + (size_t)bh * 8192;
    int tok[8];
    #pragma unroll
    for (int j = 0; j < 4; ++j) tok[j] = sts[4 * c + j];
    #pragma unroll
    for (int j = 0; j < 4; ++j) tok[4 + j] = sts[4 * cp + j];
    int b = bh >> 3, hd = bh & 7;
    const float* base = QK + ((size_t)b * LTOT) * DM + hd * DH + lane;
    double kd[8];
    #pragma unroll
    for (int j = 0; j < 8; ++j) kd[j] = (double)base[(size_t)tok[j] * DM];
    double rnrm[8];
    #pragma unroll
    for (int j = 0; j < 8; ++j) {
        double v = kd[j] * kd[j];
        #pragma unroll
        for (int m = 32; m; m >>= 1) v += __shfl_xor(v, m, 64);
        rnrm[j] = 0.125 / fmax(sqrt(v), 1e-12);
    }
    int hr = c >> 9;
    #pragma unroll
    for (int i = 0; i < 4; ++i) {
        double dots[8];
        #pragma unroll
        for (int j = 0; j < 8; ++j) {
            double v = kd[i] * kd[j];
            #pragma unroll
            for (int m = 32; m; m >>= 1) v += __shfl_xor(v, m, 64);
            dots[j] = (tok[j] == tok[i]) ? -5e4 : v * rnrm[j];
        }
        double mx = dots[0];
        #pragma unroll
        for (int j = 1; j < 8; ++j) mx = fmax(mx, dots[j]);
        double s = 0.0;
        #pragma unroll
        for (int j = 0; j < 8; ++j) s += exp(dots[j] - mx);
        if (lane == 0)
            LSE[((size_t)bh * NHASH + hr) * LTOT + tok[i]] = (float)(mx + log(s));
    }
}

// ---------------------------------------------------------------------------
// Attention pass B: recompute dots, hash-round softmax weights, fp32 atomics.
// ---------------------------------------------------------------------------
__global__ __launch_bounds__(256) void attn_out_kernel(
    const float* __restrict__ QK, const float* __restrict__ V,
    const int* __restrict__ STS, const float* __restrict__ LSE,
    float* __restrict__ C)
{
    int wid = (blockIdx.x * 256 + threadIdx.x) >> 6;
    int lane = threadIdx.x & 63;
    int bh = wid >> 11;
    int c  = wid & 2047;
    int cp = (c + NCH - 1) & (NCH - 1);
    const int* sts = STS + (size_t)bh * 8192;
    int tok[8];
    #pragma unroll
    for (int j = 0; j < 4; ++j) tok[j] = sts[4 * c + j];
    #pragma unroll
    for (int j = 0; j < 4; ++j) tok[4 + j] = sts[4 * cp + j];
    int b = bh >> 3, hd = bh & 7;
    const float* base = QK + ((size_t)b * LTOT) * DM + hd * DH + lane;
    const float* vbase = V + ((size_t)b * LTOT) * DM + hd * DH + lane;
    double kd[8], vd[8];
    #pragma unroll
    for (int j = 0; j < 8; ++j) kd[j] = (double)base[(size_t)tok[j] * DM];
    #pragma unroll
    for (int j = 0; j < 8; ++j) vd[j] = (double)vbase[(size_t)tok[j] * DM];
    double rnrm[8];
    #pragma unroll
    for (int j = 0; j < 8; ++j) {
        double v = kd[j] * kd[j];
        #pragma unroll
        for (int m = 32; m; m >>= 1) v += __shfl_xor(v, m, 64);
        rnrm[j] = 0.125 / fmax(sqrt(v), 1e-12);
    }
    int hr = c >> 9;
    float* crow0 = C + ((size_t)b * LTOT) * DM + hd * DH + lane;
    #pragma unroll
    for (int i = 0; i < 4; ++i) {
        double dots[8];
        #pragma unroll
        for (int j = 0; j < 8; ++j) {
            double v = kd[i] * kd[j];
            #pragma unroll
            for (int m = 32; m; m >>= 1) v += __shfl_xor(v, m, 64);
            dots[j] = (tok[j] == tok[i]) ? -5e4 : v * rnrm[j];
        }
        double Lh[4];
        #pragma unroll
        for (int hh = 0; hh < 4; ++hh)
            Lh[hh] = (double)LSE[((size_t)bh * NHASH + hh) * LTOT + tok[i]];
        double my = Lh[hr];
        double wm = fmax(fmax(Lh[0], Lh[1]), fmax(Lh[2], Lh[3]));
        double wsum = 0.0;
        #pragma unroll
        for (int hh = 0; hh < 4; ++hh) wsum += exp(Lh[hh] - wm);
        double w = exp(my - wm) / wsum;
        double acc = 0.0;
        #pragma unroll
        for (int j = 0; j < 8; ++j) acc += exp(dots[j] - my) * vd[j];
        atomicAdd(crow0 + (size_t)tok[i] * DM, (float)(acc * w));
    }
}

// ---------------------------------------------------------------------------
// LayerNorm over last dim (512). fp64 stats + transform, fp32 out.
// ---------------------------------------------------------------------------
__global__ __launch_bounds__(256) void ln_kernel(
    const float* __restrict__ X, float* __restrict__ Y,
    const float* __restrict__ g, const float* __restrict__ bta)
{
    int row = blockIdx.x;
    int tid = threadIdx.x;
    const float* x = X + (size_t)row * DM;
    double v0 = (double)x[tid], v1 = (double)x[tid + 256];
    double s = v0 + v1;
    double q = v0 * v0 + v1 * v1;
    #pragma unroll
    for (int off = 32; off; off >>= 1) {
        s += __shfl_down(s, off, 64);
        q += __shfl_down(q, off, 64);
    }
    __shared__ double ss[4], qq[4];
    int wid = tid >> 6, lane = tid & 63;
    if (lane == 0) { ss[wid] = s; qq[wid] = q; }
    __syncthreads();
    if (tid == 0) {
        double S = ss[0] + ss[1] + ss[2] + ss[3];
        double Q = qq[0] + qq[1] + qq[2] + qq[3];
        double mu = S * (1.0 / 512.0);
        double var = Q * (1.0 / 512.0) - mu * mu;
        ss[0] = mu;
        qq[0] = 1.0 / sqrt(var + 1e-5);
    }
    __syncthreads();
    double mu = ss[0], rs = qq[0];
    Y[(size_t)row * DM + tid] =
        (float)((v0 - mu) * rs * (double)g[tid] + (double)bta[tid]);
    Y[(size_t)row * DM + tid + 256] =
        (float)((v1 - mu) * rs * (double)g[tid + 256] + (double)bta[tid + 256]);
}

// ---------------------------------------------------------------------------
// Final projection + slice (fp64 acc, fp32 out).
// ---------------------------------------------------------------------------
__global__ __launch_bounds__(64) void proj_kernel(
    const float* __restrict__ Hf, const float* __restrict__ pw,
    const float* __restrict__ pb, float* __restrict__ out)
{
    int idx = blockIdx.x;               // 0..4095
    int b = idx >> 9, i = idx & 511;
    const float* row = Hf + ((size_t)(b * LTOT + SEQ + i)) * DM;
    int lane = threadIdx.x;
    double s = 0.0;
    #pragma unroll
    for (int k = 0; k < 8; ++k)
        s += (double)row[lane + 64 * k] * (double)pw[lane + 64 * k];
    #pragma unroll
    for (int off = 32; off; off >>= 1) s += __shfl_down(s, off, 64);
    if (lane == 0) out[idx] = (float)(s + (double)pb[0]);
}

// ---------------------------------------------------------------------------
extern "C" void kernel_launch(void* const* d_in, const int* in_sizes, int n_in,
                              void* d_out, int out_size, void* d_ws, size_t ws_size,
                              hipStream_t stream)
{
    const float* x_enc      = (const float*)d_in[0];
    const float* x_mark_enc = (const float*)d_in[1];
    const float* x_dec      = (const float*)d_in[2];
    const float* x_mark_dec = (const float*)d_in[3];
    const float* token_w    = (const float*)d_in[4];
    const float* temp_w     = (const float*)d_in[5];
    const float* qk_w       = (const float*)d_in[6];
    const float* v_w        = (const float*)d_in[7];
    const float* out_w      = (const float*)d_in[8];
    const float* out_b      = (const float*)d_in[9];
    const float* ln1_g      = (const float*)d_in[10];
    const float* ln1_b      = (const float*)d_in[11];
    const float* ff1_w      = (const float*)d_in[12];
    const float* ff1_b      = (const float*)d_in[13];
    const float* ff2_w      = (const float*)d_in[14];
    const float* ff2_b      = (const float*)d_in[15];
    const float* ln2_g      = (const float*)d_in[16];
    const float* ln2_b      = (const float*)d_in[17];
    const float* norm_g     = (const float*)d_in[18];
    const float* norm_b     = (const float*)d_in[19];
    const float* proj_w     = (const float*)d_in[20];
    const float* proj_b     = (const float*)d_in[21];
    const float* rotations  = (const float*)d_in[22];

    float* ws = (float*)d_ws;
    const size_t S = (size_t)BATCH * LTOT * DM;   // 8,388,608 floats
    float* Hb  = ws;
    float* QKb = ws + S;
    float* Vb  = ws + 2 * S;
    float* Cb  = ws + 3 * S;
    float* Yb  = QKb;                    // FFN intermediate: spans QKb+Vb (2S)
    int*   BKTb = (int*)(ws + 4 * S);              // 2 MB
    float* LSEb = ws + 4 * S + 524288;             // 2 MB
    int*   STSb = (int*)(ws + 4 * S + 2 * 524288); // 2 MB

    build_h_kernel<<<BATCH * LTOT, 512, 0, stream>>>(
        x_enc, x_mark_enc, x_dec, x_mark_dec, token_w, temp_w, Hb);

    const int M = BATCH * LTOT;  // 16384
    const int ATT_BLOCKS = NBH * NCH / 4;  // 32768 waves / 4 per block
    for (int l = 0; l < 2; ++l) {
        const float* qkw = qk_w + (size_t)l * DM * DM;
        const float* vw  = v_w  + (size_t)l * DM * DM;
        const float* ow  = out_w + (size_t)l * DM * DM;
        const float* ob  = out_b + (size_t)l * DM;
        const float* l1g = ln1_g + (size_t)l * DM;
        const float* l1b = ln1_b + (size_t)l * DM;
        const float* f1w = ff1_w + (size_t)l * DFF * DM;
        const float* f1b = ff1_b + (size_t)l * DFF;
        const float* f2w = ff2_w + (size_t)l * DM * DFF;
        const float* f2b = ff2_b + (size_t)l * DM;
        const float* l2g = ln2_g + (size_t)l * DM;
        const float* l2b = ln2_b + (size_t)l * DM;
        const float* rot = rotations + (size_t)l * DH * NHASH * 256;

        dim3 gQ(DM / 128, M / 128);  // (4, 128)
        gemm_f32<<<gQ, 256, 0, stream>>>(Hb, qkw, nullptr, nullptr, QKb, M, DM, DM, 0);
        gemm_f32<<<gQ, 256, 0, stream>>>(Hb, vw,  nullptr, nullptr, Vb,  M, DM, DM, 0);

        lsh_hash_kernel<<<NBH * NHASH * 8, 256, 0, stream>>>(QKb, rot, BKTb);
        lsh_sort_kernel<<<NBH * NHASH, 256, 0, stream>>>(BKTb, STSb);

        hipMemsetAsync(Cb, 0, S * sizeof(float), stream);
        attn_lse_kernel<<<ATT_BLOCKS, 256, 0, stream>>>(QKb, STSb, LSEb);
        attn_out_kernel<<<ATT_BLOCKS, 256, 0, stream>>>(QKb, Vb, STSb, LSEb, Cb);

        // h = h + attn @ out_w^T + out_b   (in-place residual)
        gemm_f32<<<gQ, 256, 0, stream>>>(Cb, ow, ob, Hb, Hb, M, DM, DM, 0);
        ln_kernel<<<M, 256, 0, stream>>>(Hb, Hb, l1g, l1b);

        // FFN in 2 row-halves of 8192; Y spans QKb+Vb; ff2 in-place into Hb.
        for (int hb2 = 0; hb2 < 2; ++hb2) {
            float* hpart = Hb + (size_t)hb2 * 8192 * DM;
            dim3 gF1(DFF / 128, 8192 / 128);  // (16, 64) = 1024 blocks
            gemm_f32<<<gF1, 256, 0, stream>>>(hpart, f1w, f1b, nullptr, Yb, 8192, DFF, DM, 1);
            dim3 gF2(DM / 128, 8192 / 128);   // (4, 64) = 256 blocks
            gemm_f32<<<gF2, 256, 0, stream>>>(Yb, f2w, f2b, hpart, hpart, 8192, DM, DFF, 0);
        }
        ln_kernel<<<M, 256, 0, stream>>>(Hb, Hb, l2g, l2b);
    }

    ln_kernel<<<M, 256, 0, stream>>>(Hb, Cb, norm_g, norm_b);
    proj_kernel<<<4096, 64, 0, stream>>>(Cb, proj_w, proj_b, (float*)d_out);
}

// Round 8
// 5743.367 us; speedup vs baseline: 1.9106x; 1.1799x over previous
//
#include <hip/hip_runtime.h>
#include <math.h>

#define BATCH 8
#define LTOT 2048
#define DM 512
#define NHEADS 8
#define DH 64
#define NBH 64
#define NHASH 4
#define SEQ 1536
#define DECL 768
#define DFF 2048
#define NCH 2048   // total chunks (4 rounds * 512)

typedef unsigned short u16;
typedef unsigned int u32;
typedef __attribute__((ext_vector_type(8))) short short8;   // 8 bf16 = 4 VGPR
typedef __attribute__((ext_vector_type(4))) float floatx4;  // MFMA C/D

static __device__ __forceinline__ double gelu_d(double x) {
    return 0.5 * x * (1.0 + erf(x * 0.70710678118654752440));
}

static __device__ __forceinline__ u16 f2bf(float x) {   // RNE float->bf16 bits
    u32 u = __float_as_uint(x);
    return (u16)((u + 0x7fffu + ((u >> 16) & 1u)) >> 16);
}
static __device__ __forceinline__ float bf2f(u16 h) {
    return __uint_as_float(((u32)h) << 16);
}
static __device__ __forceinline__ void split3(float x, u16& h, u16& m, u16& l) {
    h = f2bf(x);
    float r1 = x - bf2f(h);
    m = f2bf(r1);
    l = f2bf(r1 - bf2f(m));
}

// ---------------------------------------------------------------------------
// h = TokenConv(x) + TimeLinear(xm) + PE   -> H [B, L, 512]
// PE mimics numpy-fp32 rounding points: e, div, ang rounded to fp32.
// ---------------------------------------------------------------------------
__global__ __launch_bounds__(512) void build_h_kernel(
    const float* __restrict__ x_enc, const float* __restrict__ x_mark_enc,
    const float* __restrict__ x_dec, const float* __restrict__ x_mark_dec,
    const float* __restrict__ token_w, const float* __restrict__ temp_w,
    float* __restrict__ H)
{
    int bl = blockIdx.x;
    int b = bl >> 11, l = bl & 2047;
    __shared__ float xr[3][7];
    __shared__ float xmr[4];
    int tid = threadIdx.x;
    if (tid < 21) {
        int k = tid / 7, c = tid % 7;
        int t = (l + k - 1 + LTOT) & 2047;
        float v;
        if (t < SEQ) v = x_enc[(b * SEQ + t) * 7 + c];
        else         v = x_dec[(b * DECL + (t - 1280)) * 7 + c];
        xr[k][c] = v;
    } else if (tid < 25) {
        int m = tid - 21;
        float v;
        if (l < SEQ) v = x_mark_enc[(b * SEQ + l) * 4 + m];
        else         v = x_mark_dec[(b * DECL + (l - 1280)) * 4 + m];
        xmr[m] = v;
    }
    __syncthreads();
    int d = tid;  // 0..511
    double val = 0.0;
    #pragma unroll
    for (int k = 0; k < 3; ++k)
        #pragma unroll
        for (int c = 0; c < 7; ++c)
            val += (double)xr[k][c] * (double)token_w[(d * 7 + c) * 3 + k];
    double tmp = 0.0;
    #pragma unroll
    for (int m = 0; m < 4; ++m) tmp += (double)xmr[m] * (double)temp_w[d * 4 + m];
    const float cf = (float)(-9.210340371976184 / 512.0);
    float ef  = (float)(2 * (d >> 1)) * cf;
    float dvf = (float)exp((double)ef);
    float angf = (float)l * dvf;
    double pe = (d & 1) ? cos((double)angf) : sin((double)angf);
    H[((size_t)b * LTOT + l) * DM + d] = (float)(val + tmp + pe);
}

// ---------------------------------------------------------------------------
// MFMA split-bf16 GEMM: C[M,N] = act( A[M,K] @ W[N,K]^T + bias + res )
// 128x128 workgroup tile, 4 waves x (4x4 tiles of 16x16), K-step 32.
// NSPLIT=3: x = h+m+l bf16; 6 MFMAs/tile (noise ~1.2e-7 rel, inside the
//           measured flip-invariance band r1==r2==r4).
// NSPLIT=2: h+m only, 3 MFMAs (only for GEMMs that cannot reach a hash).
// fp64 epilogue (bias/res/gelu) identical to previous rounds.
// ---------------------------------------------------------------------------
template<int NSPLIT>
__global__ __launch_bounds__(256) void gemm_mfma(
    const float* __restrict__ A, const float* __restrict__ W,
    const float* __restrict__ bias, const float* __restrict__ res,
    float* __restrict__ C, int M, int N, int K, int act)
{
    __shared__ u16 Ah[128][32], Am[128][32], Al[128][32];
    __shared__ u16 Wh[128][32], Wm[128][32], Wl[128][32];
    const int tid = threadIdx.x;
    const int n0 = blockIdx.x * 128, m0 = blockIdx.y * 128;
    const int row = tid >> 1;           // 0..127
    const int koff = (tid & 1) * 16;    // 0 or 16
    const float* Ag = A + (size_t)(m0 + row) * K + koff;
    const float* Wg = W + (size_t)(n0 + row) * K + koff;

    const int wv = tid >> 6, lane = tid & 63;
    const int m0w = (wv >> 1) * 64, n0w = (wv & 1) * 64;
    const int fr = lane & 15, quad = lane >> 4;

    floatx4 acc[4][4];
    #pragma unroll
    for (int i = 0; i < 4; ++i)
        #pragma unroll
        for (int j = 0; j < 4; ++j) acc[i][j] = (floatx4)0.0f;

    for (int kt = 0; kt < K; kt += 32) {
        float fa[16], fw[16];
        #pragma unroll
        for (int g = 0; g < 4; ++g) {
            float4 a4 = *(const float4*)(Ag + kt + g * 4);
            float4 w4 = *(const float4*)(Wg + kt + g * 4);
            fa[g*4+0] = a4.x; fa[g*4+1] = a4.y; fa[g*4+2] = a4.z; fa[g*4+3] = a4.w;
            fw[g*4+0] = w4.x; fw[g*4+1] = w4.y; fw[g*4+2] = w4.z; fw[g*4+3] = w4.w;
        }
        u32 pah[8], pam[8], pal[8], pwh[8], pwm[8], pwl[8];
        #pragma unroll
        for (int i = 0; i < 8; ++i) {
            u16 h0, m0_, l0, h1, m1_, l1;
            split3(fa[2*i], h0, m0_, l0);
            split3(fa[2*i+1], h1, m1_, l1);
            pah[i] = (u32)h0 | ((u32)h1 << 16);
            pam[i] = (u32)m0_ | ((u32)m1_ << 16);
            pal[i] = (u32)l0 | ((u32)l1 << 16);
            split3(fw[2*i], h0, m0_, l0);
            split3(fw[2*i+1], h1, m1_, l1);
            pwh[i] = (u32)h0 | ((u32)h1 << 16);
            pwm[i] = (u32)m0_ | ((u32)m1_ << 16);
            pwl[i] = (u32)l0 | ((u32)l1 << 16);
        }
        __syncthreads();
        {
            u32* dh = (u32*)&Ah[row][koff];
            u32* dm = (u32*)&Am[row][koff];
            ((uint4*)dh)[0] = make_uint4(pah[0], pah[1], pah[2], pah[3]);
            ((uint4*)dh)[1] = make_uint4(pah[4], pah[5], pah[6], pah[7]);
            ((uint4*)dm)[0] = make_uint4(pam[0], pam[1], pam[2], pam[3]);
            ((uint4*)dm)[1] = make_uint4(pam[4], pam[5], pam[6], pam[7]);
            u32* eh = (u32*)&Wh[row][koff];
            u32* em = (u32*)&Wm[row][koff];
            ((uint4*)eh)[0] = make_uint4(pwh[0], pwh[1], pwh[2], pwh[3]);
            ((uint4*)eh)[1] = make_uint4(pwh[4], pwh[5], pwh[6], pwh[7]);
            ((uint4*)em)[0] = make_uint4(pwm[0], pwm[1], pwm[2], pwm[3]);
            ((uint4*)em)[1] = make_uint4(pwm[4], pwm[5], pwm[6], pwm[7]);
            if (NSPLIT == 3) {
                u32* dl = (u32*)&Al[row][koff];
                u32* el = (u32*)&Wl[row][koff];
                ((uint4*)dl)[0] = make_uint4(pal[0], pal[1], pal[2], pal[3]);
                ((uint4*)dl)[1] = make_uint4(pal[4], pal[5], pal[6], pal[7]);
                ((uint4*)el)[0] = make_uint4(pwl[0], pwl[1], pwl[2], pwl[3]);
                ((uint4*)el)[1] = make_uint4(pwl[4], pwl[5], pwl[6], pwl[7]);
            }
        }
        __syncthreads();
        short8 ah4[4], am4[4], al4[4];
        #pragma unroll
        for (int rt = 0; rt < 4; ++rt) {
            int r = m0w + rt * 16 + fr;
            ah4[rt] = *(const short8*)&Ah[r][quad * 8];
            am4[rt] = *(const short8*)&Am[r][quad * 8];
            if (NSPLIT == 3) al4[rt] = *(const short8*)&Al[r][quad * 8];
        }
        #pragma unroll
        for (int ct = 0; ct < 4; ++ct) {
            int nrw = n0w + ct * 16 + fr;
            short8 bh4 = *(const short8*)&Wh[nrw][quad * 8];
            short8 bm4 = *(const short8*)&Wm[nrw][quad * 8];
            short8 bl4;
            if (NSPLIT == 3) bl4 = *(const short8*)&Wl[nrw][quad * 8];
            #pragma unroll
            for (int rt = 0; rt < 4; ++rt) {
                floatx4 c = acc[rt][ct];
                c = __builtin_amdgcn_mfma_f32_16x16x32_bf16(ah4[rt], bh4, c, 0, 0, 0);
                c = __builtin_amdgcn_mfma_f32_16x16x32_bf16(ah4[rt], bm4, c, 0, 0, 0);
                c = __builtin_amdgcn_mfma_f32_16x16x32_bf16(am4[rt], bh4, c, 0, 0, 0);
                if (NSPLIT == 3) {
                    c = __builtin_amdgcn_mfma_f32_16x16x32_bf16(ah4[rt], bl4, c, 0, 0, 0);
                    c = __builtin_amdgcn_mfma_f32_16x16x32_bf16(am4[rt], bm4, c, 0, 0, 0);
                    c = __builtin_amdgcn_mfma_f32_16x16x32_bf16(al4[rt], bh4, c, 0, 0, 0);
                }
                acc[rt][ct] = c;
            }
        }
    }
    // Epilogue: C/D layout col=lane&15, row=quad*4+reg (m89-verified).
    #pragma unroll
    for (int rt = 0; rt < 4; ++rt) {
        #pragma unroll
        for (int ct = 0; ct < 4; ++ct) {
            int n = n0 + n0w + ct * 16 + fr;
            #pragma unroll
            for (int reg = 0; reg < 4; ++reg) {
                int m = m0 + m0w + rt * 16 + quad * 4 + reg;
                double v = (double)acc[rt][ct][reg];
                if (bias) v += (double)bias[n];
                if (res)  v += (double)res[(size_t)m * N + n];
                if (act == 1) v = gelu_d(v);
                C[(size_t)m * N + n] = (float)v;
            }
        }
    }
}

// ---------------------------------------------------------------------------
// LSH hashing: bucket = argmax over [R^T q, -R^T q]  (fp64 dots on fp32 data)
// ---------------------------------------------------------------------------
__global__ __launch_bounds__(256) void lsh_hash_kernel(
    const float* __restrict__ QK, const float* __restrict__ rot,
    int* __restrict__ BKT)
{
    __shared__ float RT[128][68];   // [r][d], 16B-aligned rows
    int bid = blockIdx.x;
    int tt = bid & 7;
    int h = (bid >> 3) & 3;
    int bh = bid >> 5;
    int tid = threadIdx.x;
    int t = tt * 256 + tid;
    int b = bh >> 3, hd = bh & 7;
    const float* qbase = QK + ((size_t)(b * LTOT + t)) * DM + hd * DH;
    float qf[64];
    #pragma unroll
    for (int d4 = 0; d4 < 16; ++d4) {
        float4 q4 = *(const float4*)(qbase + d4 * 4);
        qf[d4 * 4 + 0] = q4.x; qf[d4 * 4 + 1] = q4.y;
        qf[d4 * 4 + 2] = q4.z; qf[d4 * 4 + 3] = q4.w;
    }
    double bestP = -1e300, bestN = -1e300;
    int bp = 0, bn = 0;
    for (int half = 0; half < 2; ++half) {
        __syncthreads();
        for (int idx = tid; idx < 128 * 64; idx += 256) {
            int d = idx >> 7, r = idx & 127;
            RT[r][d] = rot[(d * 4 + h) * 256 + half * 128 + r];
        }
        __syncthreads();
        for (int r = 0; r < 128; ++r) {
            double a0 = 0.0, a1 = 0.0, a2 = 0.0, a3 = 0.0;
            #pragma unroll
            for (int d4 = 0; d4 < 16; d4 += 4) {
                float4 r0 = *(const float4*)&RT[r][(d4 + 0) * 4];
                float4 r1 = *(const float4*)&RT[r][(d4 + 1) * 4];
                float4 r2 = *(const float4*)&RT[r][(d4 + 2) * 4];
                float4 r3 = *(const float4*)&RT[r][(d4 + 3) * 4];
                a0 += (double)qf[(d4+0)*4+0]*(double)r0.x + (double)qf[(d4+0)*4+1]*(double)r0.y
                    + (double)qf[(d4+0)*4+2]*(double)r0.z + (double)qf[(d4+0)*4+3]*(double)r0.w;
                a1 += (double)qf[(d4+1)*4+0]*(double)r1.x + (double)qf[(d4+1)*4+1]*(double)r1.y
                    + (double)qf[(d4+1)*4+2]*(double)r1.z + (double)qf[(d4+1)*4+3]*(double)r1.w;
                a2 += (double)qf[(d4+2)*4+0]*(double)r2.x + (double)qf[(d4+2)*4+1]*(double)r2.y
                    + (double)qf[(d4+2)*4+2]*(double)r2.z + (double)qf[(d4+2)*4+3]*(double)r2.w;
                a3 += (double)qf[(d4+3)*4+0]*(double)r3.x + (double)qf[(d4+3)*4+1]*(double)r3.y
                    + (double)qf[(d4+3)*4+2]*(double)r3.z + (double)qf[(d4+3)*4+3]*(double)r3.w;
            }
            double acc = (a0 + a1) + (a2 + a3);
            int gr = half * 128 + r;
            if (acc > bestP)  { bestP = acc;  bp = gr; }
            if (-acc > bestN) { bestN = -acc; bn = gr; }
        }
    }
    int bucket = (bestN > bestP) ? (256 + bn) : bp;  // tie -> positive half
    BKT[((size_t)bh * NHASH + h) * LTOT + t] = bucket;
}

// ---------------------------------------------------------------------------
// Stable counting sort per (bh, hash): sorted-by-(bucket, t).
// ---------------------------------------------------------------------------
__global__ __launch_bounds__(256) void lsh_sort_kernel(
    const int* __restrict__ BKT, int* __restrict__ STS)
{
    __shared__ unsigned short bkt[2048];
    __shared__ unsigned int hist2[16][512];
    __shared__ unsigned int bstart[512];
    int bid = blockIdx.x;
    int h = bid & 3, bh = bid >> 2;
    int tid = threadIdx.x;
    const int* src = BKT + ((size_t)bh * NHASH + h) * LTOT;
    for (int t = tid; t < 2048; t += 256) bkt[t] = (unsigned short)src[t];
    for (int i = tid; i < 16 * 512; i += 256) (&hist2[0][0])[i] = 0u;
    __syncthreads();
    for (int t = tid; t < 2048; t += 256)
        atomicAdd(&hist2[t >> 7][bkt[t]], 1u);
    __syncthreads();
    for (int bb = tid; bb < 512; bb += 256) {
        unsigned int run = 0;
        #pragma unroll
        for (int g = 0; g < 16; ++g) {
            unsigned int c = hist2[g][bb];
            hist2[g][bb] = run;
            run += c;
        }
        bstart[bb] = run;
    }
    __syncthreads();
    if (tid == 0) {
        unsigned int run = 0;
        for (int bb = 0; bb < 512; ++bb) {
            unsigned int c = bstart[bb];
            bstart[bb] = run;
            run += c;
        }
    }
    __syncthreads();
    int* dst = STS + (size_t)bh * (NHASH * LTOT) + h * LTOT;
    for (int t = tid; t < 2048; t += 256) {
        int bb = bkt[t];
        unsigned int rank = hist2[t >> 7][bb];
        int g0 = t & ~127;
        for (int u = g0; u < t; ++u) rank += (bkt[u] == (unsigned short)bb);
        dst[bstart[bb] + rank] = t;
    }
}

// ---------------------------------------------------------------------------
// Attention pass A: one wave per (bh, chunk); lane = dim.
// ---------------------------------------------------------------------------
__global__ __launch_bounds__(256) void attn_lse_kernel(
    const float* __restrict__ QK, const int* __restrict__ STS,
    float* __restrict__ LSE)
{
    int wid = (blockIdx.x * 256 + threadIdx.x) >> 6;   // global wave id
    int lane = threadIdx.x & 63;
    int bh = wid >> 11;          // 0..63
    int c  = wid & 2047;
    int cp = (c + NCH - 1) & (NCH - 1);
    const int* sts = STS + (size_t)bh * 8192;
    int tok[8];
    #pragma unroll
    for (int j = 0; j < 4; ++j) tok[j] = sts[4 * c + j];
    #pragma unroll
    for (int j = 0; j < 4; ++j) tok[4 + j] = sts[4 * cp + j];
    int b = bh >> 3, hd = bh & 7;
    const float* base = QK + ((size_t)b * LTOT) * DM + hd * DH + lane;
    double kd[8];
    #pragma unroll
    for (int j = 0; j < 8; ++j) kd[j] = (double)base[(size_t)tok[j] * DM];
    double rnrm[8];
    #pragma unroll
    for (int j = 0; j < 8; ++j) {
        double v = kd[j] * kd[j];
        #pragma unroll
        for (int m = 32; m; m >>= 1) v += __shfl_xor(v, m, 64);
        rnrm[j] = 0.125 / fmax(sqrt(v), 1e-12);
    }
    int hr = c >> 9;
    #pragma unroll
    for (int i = 0; i < 4; ++i) {
        double dots[8];
        #pragma unroll
        for (int j = 0; j < 8; ++j) {
            double v = kd[i] * kd[j];
            #pragma unroll
            for (int m = 32; m; m >>= 1) v += __shfl_xor(v, m, 64);
            dots[j] = (tok[j] == tok[i]) ? -5e4 : v * rnrm[j];
        }
        double mx = dots[0];
        #pragma unroll
        for (int j = 1; j < 8; ++j) mx = fmax(mx, dots[j]);
        double s = 0.0;
        #pragma unroll
        for (int j = 0; j < 8; ++j) s += exp(dots[j] - mx);
        if (lane == 0)
            LSE[((size_t)bh * NHASH + hr) * LTOT + tok[i]] = (float)(mx + log(s));
    }
}

// ---------------------------------------------------------------------------
// Attention pass B: recompute dots, hash-round softmax weights, fp32 atomics.
// ---------------------------------------------------------------------------
__global__ __launch_bounds__(256) void attn_out_kernel(
    const float* __restrict__ QK, const float* __restrict__ V,
    const int* __restrict__ STS, const float* __restrict__ LSE,
    float* __restrict__ C)
{
    int wid = (blockIdx.x * 256 + threadIdx.x) >> 6;
    int lane = threadIdx.x & 63;
    int bh = wid >> 11;
    int c  = wid & 2047;
    int cp = (c + NCH - 1) & (NCH - 1);
    const int* sts = STS + (size_t)bh * 8192;
    int tok[8];
    #pragma unroll
    for (int j = 0; j < 4; ++j) tok[j] = sts[4 * c + j];
    #pragma unroll
    for (int j = 0; j < 4; ++j) tok[4 + j] = sts[4 * cp + j];
    int b = bh >> 3, hd = bh & 7;
    const float* base = QK + ((size_t)b * LTOT) * DM + hd * DH + lane;
    const float* vbase = V + ((size_t)b * LTOT) * DM + hd * DH + lane;
    double kd[8], vd[8];
    #pragma unroll
    for (int j = 0; j < 8; ++j) kd[j] = (double)base[(size_t)tok[j] * DM];
    #pragma unroll
    for (int j = 0; j < 8; ++j) vd[j] = (double)vbase[(size_t)tok[j] * DM];
    double rnrm[8];
    #pragma unroll
    for (int j = 0; j < 8; ++j) {
        double v = kd[j] * kd[j];
        #pragma unroll
        for (int m = 32; m; m >>= 1) v += __shfl_xor(v, m, 64);
        rnrm[j] = 0.125 / fmax(sqrt(v), 1e-12);
    }
    int hr = c >> 9;
    float* crow0 = C + ((size_t)b * LTOT) * DM + hd * DH + lane;
    #pragma unroll
    for (int i = 0; i < 4; ++i) {
        double dots[8];
        #pragma unroll
        for (int j = 0; j < 8; ++j) {
            double v = kd[i] * kd[j];
            #pragma unroll
            for (int m = 32; m; m >>= 1) v += __shfl_xor(v, m, 64);
            dots[j] = (tok[j] == tok[i]) ? -5e4 : v * rnrm[j];
        }
        double Lh[4];
        #pragma unroll
        for (int hh = 0; hh < 4; ++hh)
            Lh[hh] = (double)LSE[((size_t)bh * NHASH + hh) * LTOT + tok[i]];
        double my = Lh[hr];
        double wm = fmax(fmax(Lh[0], Lh[1]), fmax(Lh[2], Lh[3]));
        double wsum = 0.0;
        #pragma unroll
        for (int hh = 0; hh < 4; ++hh) wsum += exp(Lh[hh] - wm);
        double w = exp(my - wm) / wsum;
        double acc = 0.0;
        #pragma unroll
        for (int j = 0; j < 8; ++j) acc += exp(dots[j] - my) * vd[j];
        atomicAdd(crow0 + (size_t)tok[i] * DM, (float)(acc * w));
    }
}

// ---------------------------------------------------------------------------
// LayerNorm over last dim (512). fp64 stats + transform, fp32 out.
// ---------------------------------------------------------------------------
__global__ __launch_bounds__(256) void ln_kernel(
    const float* __restrict__ X, float* __restrict__ Y,
    const float* __restrict__ g, const float* __restrict__ bta)
{
    int row = blockIdx.x;
    int tid = threadIdx.x;
    const float* x = X + (size_t)row * DM;
    double v0 = (double)x[tid], v1 = (double)x[tid + 256];
    double s = v0 + v1;
    double q = v0 * v0 + v1 * v1;
    #pragma unroll
    for (int off = 32; off; off >>= 1) {
        s += __shfl_down(s, off, 64);
        q += __shfl_down(q, off, 64);
    }
    __shared__ double ss[4], qq[4];
    int wid = tid >> 6, lane = tid & 63;
    if (lane == 0) { ss[wid] = s; qq[wid] = q; }
    __syncthreads();
    if (tid == 0) {
        double S = ss[0] + ss[1] + ss[2] + ss[3];
        double Q = qq[0] + qq[1] + qq[2] + qq[3];
        double mu = S * (1.0 / 512.0);
        double var = Q * (1.0 / 512.0) - mu * mu;
        ss[0] = mu;
        qq[0] = 1.0 / sqrt(var + 1e-5);
    }
    __syncthreads();
    double mu = ss[0], rs = qq[0];
    Y[(size_t)row * DM + tid] =
        (float)((v0 - mu) * rs * (double)g[tid] + (double)bta[tid]);
    Y[(size_t)row * DM + tid + 256] =
        (float)((v1 - mu) * rs * (double)g[tid + 256] + (double)bta[tid + 256]);
}

// ---------------------------------------------------------------------------
// Final projection + slice (fp64 acc, fp32 out).
// ---------------------------------------------------------------------------
__global__ __launch_bounds__(64) void proj_kernel(
    const float* __restrict__ Hf, const float* __restrict__ pw,
    const float* __restrict__ pb, float* __restrict__ out)
{
    int idx = blockIdx.x;               // 0..4095
    int b = idx >> 9, i = idx & 511;
    const float* row = Hf + ((size_t)(b * LTOT + SEQ + i)) * DM;
    int lane = threadIdx.x;
    double s = 0.0;
    #pragma unroll
    for (int k = 0; k < 8; ++k)
        s += (double)row[lane + 64 * k] * (double)pw[lane + 64 * k];
    #pragma unroll
    for (int off = 32; off; off >>= 1) s += __shfl_down(s, off, 64);
    if (lane == 0) out[idx] = (float)(s + (double)pb[0]);
}

// ---------------------------------------------------------------------------
extern "C" void kernel_launch(void* const* d_in, const int* in_sizes, int n_in,
                              void* d_out, int out_size, void* d_ws, size_t ws_size,
                              hipStream_t stream)
{
    const float* x_enc      = (const float*)d_in[0];
    const float* x_mark_enc = (const float*)d_in[1];
    const float* x_dec      = (const float*)d_in[2];
    const float* x_mark_dec = (const float*)d_in[3];
    const float* token_w    = (const float*)d_in[4];
    const float* temp_w     = (const float*)d_in[5];
    const float* qk_w       = (const float*)d_in[6];
    const float* v_w        = (const float*)d_in[7];
    const float* out_w      = (const float*)d_in[8];
    const float* out_b      = (const float*)d_in[9];
    const float* ln1_g      = (const float*)d_in[10];
    const float* ln1_b      = (const float*)d_in[11];
    const float* ff1_w      = (const float*)d_in[12];
    const float* ff1_b      = (const float*)d_in[13];
    const float* ff2_w      = (const float*)d_in[14];
    const float* ff2_b      = (const float*)d_in[15];
    const float* ln2_g      = (const float*)d_in[16];
    const float* ln2_b      = (const float*)d_in[17];
    const float* norm_g     = (const float*)d_in[18];
    const float* norm_b     = (const float*)d_in[19];
    const float* proj_w     = (const float*)d_in[20];
    const float* proj_b     = (const float*)d_in[21];
    const float* rotations  = (const float*)d_in[22];

    float* ws = (float*)d_ws;
    const size_t S = (size_t)BATCH * LTOT * DM;   // 8,388,608 floats
    float* Hb  = ws;
    float* QKb = ws + S;
    float* Vb  = ws + 2 * S;
    float* Cb  = ws + 3 * S;
    float* Yb  = QKb;                    // FFN intermediate: spans QKb+Vb (2S)
    int*   BKTb = (int*)(ws + 4 * S);              // 2 MB
    float* LSEb = ws + 4 * S + 524288;             // 2 MB
    int*   STSb = (int*)(ws + 4 * S + 2 * 524288); // 2 MB

    build_h_kernel<<<BATCH * LTOT, 512, 0, stream>>>(
        x_enc, x_mark_enc, x_dec, x_mark_dec, token_w, temp_w, Hb);

    const int M = BATCH * LTOT;  // 16384
    const int ATT_BLOCKS = NBH * NCH / 4;  // 32768 waves / 4 per block
    for (int l = 0; l < 2; ++l) {
        const float* qkw = qk_w + (size_t)l * DM * DM;
        const float* vw  = v_w  + (size_t)l * DM * DM;
        const float* ow  = out_w + (size_t)l * DM * DM;
        const float* ob  = out_b + (size_t)l * DM;
        const float* l1g = ln1_g + (size_t)l * DM;
        const float* l1b = ln1_b + (size_t)l * DM;
        const float* f1w = ff1_w + (size_t)l * DFF * DM;
        const float* f1b = ff1_b + (size_t)l * DFF;
        const float* f2w = ff2_w + (size_t)l * DM * DFF;
        const float* f2b = ff2_b + (size_t)l * DM;
        const float* l2g = ln2_g + (size_t)l * DM;
        const float* l2b = ln2_b + (size_t)l * DM;
        const float* rot = rotations + (size_t)l * DH * NHASH * 256;

        dim3 gQ(DM / 128, M / 128);  // (4, 128)
        // QK feeds the hash in both layers -> split-3 always.
        gemm_mfma<3><<<gQ, 256, 0, stream>>>(Hb, qkw, nullptr, nullptr, QKb, M, DM, DM, 0);
        // Layer 0's V/out/FFN feed layer 1's hash through H -> split-3.
        // Layer 1's V/out/FFN only reach the output -> split-2 suffices.
        if (l == 0)
            gemm_mfma<3><<<gQ, 256, 0, stream>>>(Hb, vw, nullptr, nullptr, Vb, M, DM, DM, 0);
        else
            gemm_mfma<2><<<gQ, 256, 0, stream>>>(Hb, vw, nullptr, nullptr, Vb, M, DM, DM, 0);

        lsh_hash_kernel<<<NBH * NHASH * 8, 256, 0, stream>>>(QKb, rot, BKTb);
        lsh_sort_kernel<<<NBH * NHASH, 256, 0, stream>>>(BKTb, STSb);

        hipMemsetAsync(Cb, 0, S * sizeof(float), stream);
        attn_lse_kernel<<<ATT_BLOCKS, 256, 0, stream>>>(QKb, STSb, LSEb);
        attn_out_kernel<<<ATT_BLOCKS, 256, 0, stream>>>(QKb, Vb, STSb, LSEb, Cb);

        // h = h + attn @ out_w^T + out_b   (in-place residual)
        if (l == 0)
            gemm_mfma<3><<<gQ, 256, 0, stream>>>(Cb, ow, ob, Hb, Hb, M, DM, DM, 0);
        else
            gemm_mfma<2><<<gQ, 256, 0, stream>>>(Cb, ow, ob, Hb, Hb, M, DM, DM, 0);
        ln_kernel<<<M, 256, 0, stream>>>(Hb, Hb, l1g, l1b);

        // FFN in 2 row-halves of 8192; Y spans QKb+Vb; ff2 in-place into Hb.
        for (int hb2 = 0; hb2 < 2; ++hb2) {
            float* hpart = Hb + (size_t)hb2 * 8192 * DM;
            dim3 gF1(DFF / 128, 8192 / 128);  // (16, 64) = 1024 blocks
            dim3 gF2(DM / 128, 8192 / 128);   // (4, 64)  = 256 blocks
            if (l == 0) {
                gemm_mfma<3><<<gF1, 256, 0, stream>>>(hpart, f1w, f1b, nullptr, Yb, 8192, DFF, DM, 1);
                gemm_mfma<3><<<gF2, 256, 0, stream>>>(Yb, f2w, f2b, hpart, hpart, 8192, DM, DFF, 0);
            } else {
                gemm_mfma<2><<<gF1, 256, 0, stream>>>(hpart, f1w, f1b, nullptr, Yb, 8192, DFF, DM, 1);
                gemm_mfma<2><<<gF2, 256, 0, stream>>>(Yb, f2w, f2b, hpart, hpart, 8192, DM, DFF, 0);
            }
        }
        ln_kernel<<<M, 256, 0, stream>>>(Hb, Hb, l2g, l2b);
    }

    ln_kernel<<<M, 256, 0, stream>>>(Hb, Cb, norm_g, norm_b);
    proj_kernel<<<4096, 64, 0, stream>>>(Cb, proj_w, proj_b, (float*)d_out);
}

// Round 9
// 3638.977 us; speedup vs baseline: 3.0154x; 1.5783x over previous
//
#include <hip/hip_runtime.h>
#include <math.h>

#define BATCH 8
#define LTOT 2048
#define DM 512
#define NHEADS 8
#define DH 64
#define NBH 64
#define NHASH 4
#define SEQ 1536
#define DECL 768
#define DFF 2048
#define NCH 2048   // total chunks (4 rounds * 512)

typedef unsigned short u16;
typedef unsigned int u32;
typedef unsigned long long u64;
typedef __attribute__((ext_vector_type(8))) short short8;   // 8 bf16 = 4 VGPR
typedef __attribute__((ext_vector_type(4))) float floatx4;  // MFMA C/D

static __device__ __forceinline__ double gelu_d(double x) {
    return 0.5 * x * (1.0 + erf(x * 0.70710678118654752440));
}

static __device__ __forceinline__ u16 f2bf(float x) {   // RNE float->bf16 bits
    u32 u = __float_as_uint(x);
    return (u16)((u + 0x7fffu + ((u >> 16) & 1u)) >> 16);
}
static __device__ __forceinline__ float bf2f(u16 h) {
    return __uint_as_float(((u32)h) << 16);
}
static __device__ __forceinline__ void split3(float x, u16& h, u16& m, u16& l) {
    h = f2bf(x);
    float r1 = x - bf2f(h);
    m = f2bf(r1);
    l = f2bf(r1 - bf2f(m));
}
static __device__ __forceinline__ u32 ordf(float x) {   // monotone float->u32
    u32 b = __float_as_uint(x);
    return (b & 0x80000000u) ? ~b : (b | 0x80000000u);
}

// ---------------------------------------------------------------------------
// h = TokenConv(x) + TimeLinear(xm) + PE   -> H [B, L, 512]
// PE mimics numpy-fp32 rounding points: e, div, ang rounded to fp32.
// ---------------------------------------------------------------------------
__global__ __launch_bounds__(512) void build_h_kernel(
    const float* __restrict__ x_enc, const float* __restrict__ x_mark_enc,
    const float* __restrict__ x_dec, const float* __restrict__ x_mark_dec,
    const float* __restrict__ token_w, const float* __restrict__ temp_w,
    float* __restrict__ H)
{
    int bl = blockIdx.x;
    int b = bl >> 11, l = bl & 2047;
    __shared__ float xr[3][7];
    __shared__ float xmr[4];
    int tid = threadIdx.x;
    if (tid < 21) {
        int k = tid / 7, c = tid % 7;
        int t = (l + k - 1 + LTOT) & 2047;
        float v;
        if (t < SEQ) v = x_enc[(b * SEQ + t) * 7 + c];
        else         v = x_dec[(b * DECL + (t - 1280)) * 7 + c];
        xr[k][c] = v;
    } else if (tid < 25) {
        int m = tid - 21;
        float v;
        if (l < SEQ) v = x_mark_enc[(b * SEQ + l) * 4 + m];
        else         v = x_mark_dec[(b * DECL + (l - 1280)) * 4 + m];
        xmr[m] = v;
    }
    __syncthreads();
    int d = tid;  // 0..511
    double val = 0.0;
    #pragma unroll
    for (int k = 0; k < 3; ++k)
        #pragma unroll
        for (int c = 0; c < 7; ++c)
            val += (double)xr[k][c] * (double)token_w[(d * 7 + c) * 3 + k];
    double tmp = 0.0;
    #pragma unroll
    for (int m = 0; m < 4; ++m) tmp += (double)xmr[m] * (double)temp_w[d * 4 + m];
    const float cf = (float)(-9.210340371976184 / 512.0);
    float ef  = (float)(2 * (d >> 1)) * cf;
    float dvf = (float)exp((double)ef);
    float angf = (float)l * dvf;
    double pe = (d & 1) ? cos((double)angf) : sin((double)angf);
    H[((size_t)b * LTOT + l) * DM + d] = (float)(val + tmp + pe);
}

// ---------------------------------------------------------------------------
// MFMA split-bf16 GEMM: C[M,N] = act( A[M,K] @ W[N,K]^T + bias + res )
// ---------------------------------------------------------------------------
template<int NSPLIT>
__global__ __launch_bounds__(256) void gemm_mfma(
    const float* __restrict__ A, const float* __restrict__ W,
    const float* __restrict__ bias, const float* __restrict__ res,
    float* __restrict__ C, int M, int N, int K, int act)
{
    __shared__ u16 Ah[128][32], Am[128][32], Al[128][32];
    __shared__ u16 Wh[128][32], Wm[128][32], Wl[128][32];
    const int tid = threadIdx.x;
    const int n0 = blockIdx.x * 128, m0 = blockIdx.y * 128;
    const int row = tid >> 1;           // 0..127
    const int koff = (tid & 1) * 16;    // 0 or 16
    const float* Ag = A + (size_t)(m0 + row) * K + koff;
    const float* Wg = W + (size_t)(n0 + row) * K + koff;

    const int wv = tid >> 6, lane = tid & 63;
    const int m0w = (wv >> 1) * 64, n0w = (wv & 1) * 64;
    const int fr = lane & 15, quad = lane >> 4;

    floatx4 acc[4][4];
    #pragma unroll
    for (int i = 0; i < 4; ++i)
        #pragma unroll
        for (int j = 0; j < 4; ++j) acc[i][j] = (floatx4)0.0f;

    for (int kt = 0; kt < K; kt += 32) {
        float fa[16], fw[16];
        #pragma unroll
        for (int g = 0; g < 4; ++g) {
            float4 a4 = *(const float4*)(Ag + kt + g * 4);
            float4 w4 = *(const float4*)(Wg + kt + g * 4);
            fa[g*4+0] = a4.x; fa[g*4+1] = a4.y; fa[g*4+2] = a4.z; fa[g*4+3] = a4.w;
            fw[g*4+0] = w4.x; fw[g*4+1] = w4.y; fw[g*4+2] = w4.z; fw[g*4+3] = w4.w;
        }
        u32 pah[8], pam[8], pal[8], pwh[8], pwm[8], pwl[8];
        #pragma unroll
        for (int i = 0; i < 8; ++i) {
            u16 h0, m0_, l0, h1, m1_, l1;
            split3(fa[2*i], h0, m0_, l0);
            split3(fa[2*i+1], h1, m1_, l1);
            pah[i] = (u32)h0 | ((u32)h1 << 16);
            pam[i] = (u32)m0_ | ((u32)m1_ << 16);
            pal[i] = (u32)l0 | ((u32)l1 << 16);
            split3(fw[2*i], h0, m0_, l0);
            split3(fw[2*i+1], h1, m1_, l1);
            pwh[i] = (u32)h0 | ((u32)h1 << 16);
            pwm[i] = (u32)m0_ | ((u32)m1_ << 16);
            pwl[i] = (u32)l0 | ((u32)l1 << 16);
        }
        __syncthreads();
        {
            u32* dh = (u32*)&Ah[row][koff];
            u32* dm = (u32*)&Am[row][koff];
            ((uint4*)dh)[0] = make_uint4(pah[0], pah[1], pah[2], pah[3]);
            ((uint4*)dh)[1] = make_uint4(pah[4], pah[5], pah[6], pah[7]);
            ((uint4*)dm)[0] = make_uint4(pam[0], pam[1], pam[2], pam[3]);
            ((uint4*)dm)[1] = make_uint4(pam[4], pam[5], pam[6], pam[7]);
            u32* eh = (u32*)&Wh[row][koff];
            u32* em = (u32*)&Wm[row][koff];
            ((uint4*)eh)[0] = make_uint4(pwh[0], pwh[1], pwh[2], pwh[3]);
            ((uint4*)eh)[1] = make_uint4(pwh[4], pwh[5], pwh[6], pwh[7]);
            ((uint4*)em)[0] = make_uint4(pwm[0], pwm[1], pwm[2], pwm[3]);
            ((uint4*)em)[1] = make_uint4(pwm[4], pwm[5], pwm[6], pwm[7]);
            if (NSPLIT == 3) {
                u32* dl = (u32*)&Al[row][koff];
                u32* el = (u32*)&Wl[row][koff];
                ((uint4*)dl)[0] = make_uint4(pal[0], pal[1], pal[2], pal[3]);
                ((uint4*)dl)[1] = make_uint4(pal[4], pal[5], pal[6], pal[7]);
                ((uint4*)el)[0] = make_uint4(pwl[0], pwl[1], pwl[2], pwl[3]);
                ((uint4*)el)[1] = make_uint4(pwl[4], pwl[5], pwl[6], pwl[7]);
            }
        }
        __syncthreads();
        short8 ah4[4], am4[4], al4[4];
        #pragma unroll
        for (int rt = 0; rt < 4; ++rt) {
            int r = m0w + rt * 16 + fr;
            ah4[rt] = *(const short8*)&Ah[r][quad * 8];
            am4[rt] = *(const short8*)&Am[r][quad * 8];
            if (NSPLIT == 3) al4[rt] = *(const short8*)&Al[r][quad * 8];
        }
        #pragma unroll
        for (int ct = 0; ct < 4; ++ct) {
            int nrw = n0w + ct * 16 + fr;
            short8 bh4 = *(const short8*)&Wh[nrw][quad * 8];
            short8 bm4 = *(const short8*)&Wm[nrw][quad * 8];
            short8 bl4;
            if (NSPLIT == 3) bl4 = *(const short8*)&Wl[nrw][quad * 8];
            #pragma unroll
            for (int rt = 0; rt < 4; ++rt) {
                floatx4 c = acc[rt][ct];
                c = __builtin_amdgcn_mfma_f32_16x16x32_bf16(ah4[rt], bh4, c, 0, 0, 0);
                c = __builtin_amdgcn_mfma_f32_16x16x32_bf16(ah4[rt], bm4, c, 0, 0, 0);
                c = __builtin_amdgcn_mfma_f32_16x16x32_bf16(am4[rt], bh4, c, 0, 0, 0);
                if (NSPLIT == 3) {
                    c = __builtin_amdgcn_mfma_f32_16x16x32_bf16(ah4[rt], bl4, c, 0, 0, 0);
                    c = __builtin_amdgcn_mfma_f32_16x16x32_bf16(am4[rt], bm4, c, 0, 0, 0);
                    c = __builtin_amdgcn_mfma_f32_16x16x32_bf16(al4[rt], bh4, c, 0, 0, 0);
                }
                acc[rt][ct] = c;
            }
        }
    }
    // Epilogue: C/D layout col=lane&15, row=quad*4+reg (m89-verified).
    #pragma unroll
    for (int rt = 0; rt < 4; ++rt) {
        #pragma unroll
        for (int ct = 0; ct < 4; ++ct) {
            int n = n0 + n0w + ct * 16 + fr;
            #pragma unroll
            for (int reg = 0; reg < 4; ++reg) {
                int m = m0 + m0w + rt * 16 + quad * 4 + reg;
                double v = (double)acc[rt][ct][reg];
                if (bias) v += (double)bias[n];
                if (res)  v += (double)res[(size_t)m * N + n];
                if (act == 1) v = gelu_d(v);
                C[(size_t)m * N + n] = (float)v;
            }
        }
    }
}

// ---------------------------------------------------------------------------
// Precompute split-3 bf16 planes of rot, transposed to [h][r][d].
// ---------------------------------------------------------------------------
__global__ __launch_bounds__(256) void rot_split_kernel(
    const float* __restrict__ rot, u16* __restrict__ RSh,
    u16* __restrict__ RSm, u16* __restrict__ RSl)
{
    int h = blockIdx.x;      // 0..3
    int r = threadIdx.x;     // 0..255
    #pragma unroll 4
    for (int d = 0; d < 64; ++d) {
        float v = rot[(d * 4 + h) * 256 + r];
        u16 hh, mm, ll;
        split3(v, hh, mm, ll);
        size_t o = ((size_t)h * 256 + r) * 64 + d;
        RSh[o] = hh; RSm[o] = mm; RSl[o] = ll;
    }
}

// ---------------------------------------------------------------------------
// LSH hash via split-3 bf16 MFMA + fused argmax.
// Block: 128 tokens x one hash x all 256 rotations. 4 waves split N (64 each).
// Noise ~5e-7 rel — inside the measured flip-invariance band (r1: 1.3e-6).
// Argmax: packed (ordf(value), ~idx) u64, fr-butterfly + LDS atomicMax;
// first-index tie-break preserved.
// ---------------------------------------------------------------------------
__global__ __launch_bounds__(256) void lsh_hash_mfma(
    const float* __restrict__ QK, const u16* __restrict__ RSh,
    const u16* __restrict__ RSm, const u16* __restrict__ RSl,
    int* __restrict__ BKT)
{
    __shared__ u16 Ah[128][72], Am[128][72], Al[128][72];  // padded rows
    __shared__ u64 best[128];
    int bid = blockIdx.x;
    int tt = bid & 15;
    int h  = (bid >> 4) & 3;
    int bh = bid >> 6;
    int tid = threadIdx.x;
    int b = bh >> 3, hd = bh & 7;
    const int t0 = tt * 128;

    if (tid < 128) best[tid] = 0ull;

    // Stage A: 128 token rows x 64 dims, split-3.
    {
        int row = tid >> 1;
        int kbase = (tid & 1) * 32;
        const float* src = QK + ((size_t)(b * LTOT + t0 + row)) * DM + hd * DH + kbase;
        u32 ph[16], pm[16], pl[16];
        #pragma unroll
        for (int g = 0; g < 8; ++g) {
            float4 a4 = *(const float4*)(src + g * 4);
            u16 h0, m0_, l0, h1, m1_, l1;
            split3(a4.x, h0, m0_, l0); split3(a4.y, h1, m1_, l1);
            ph[g*2]   = (u32)h0 | ((u32)h1 << 16);
            pm[g*2]   = (u32)m0_ | ((u32)m1_ << 16);
            pl[g*2]   = (u32)l0 | ((u32)l1 << 16);
            split3(a4.z, h0, m0_, l0); split3(a4.w, h1, m1_, l1);
            ph[g*2+1] = (u32)h0 | ((u32)h1 << 16);
            pm[g*2+1] = (u32)m0_ | ((u32)m1_ << 16);
            pl[g*2+1] = (u32)l0 | ((u32)l1 << 16);
        }
        #pragma unroll
        for (int g = 0; g < 4; ++g) {
            ((uint4*)&Ah[row][kbase])[g] = make_uint4(ph[g*4], ph[g*4+1], ph[g*4+2], ph[g*4+3]);
            ((uint4*)&Am[row][kbase])[g] = make_uint4(pm[g*4], pm[g*4+1], pm[g*4+2], pm[g*4+3]);
            ((uint4*)&Al[row][kbase])[g] = make_uint4(pl[g*4], pl[g*4+1], pl[g*4+2], pl[g*4+3]);
        }
    }
    __syncthreads();

    const int wv = tid >> 6, lane = tid & 63;
    const int fr = lane & 15, quad = lane >> 4;
    const int nbase = wv * 64;

    floatx4 acc[8][4];
    #pragma unroll
    for (int i = 0; i < 8; ++i)
        #pragma unroll
        for (int j = 0; j < 4; ++j) acc[i][j] = (floatx4)0.0f;

    #pragma unroll
    for (int kt = 0; kt < 2; ++kt) {
        #pragma unroll
        for (int ct = 0; ct < 4; ++ct) {
            size_t bo = ((size_t)h * 256 + nbase + ct * 16 + fr) * 64 + kt * 32 + quad * 8;
            short8 bh4 = *(const short8*)(RSh + bo);
            short8 bm4 = *(const short8*)(RSm + bo);
            short8 bl4 = *(const short8*)(RSl + bo);
            #pragma unroll
            for (int rt = 0; rt < 8; ++rt) {
                const int ar = rt * 16 + fr, ak = kt * 32 + quad * 8;
                short8 ah4 = *(const short8*)&Ah[ar][ak];
                short8 am4 = *(const short8*)&Am[ar][ak];
                short8 al4 = *(const short8*)&Al[ar][ak];
                floatx4 c = acc[rt][ct];
                c = __builtin_amdgcn_mfma_f32_16x16x32_bf16(ah4, bh4, c, 0, 0, 0);
                c = __builtin_amdgcn_mfma_f32_16x16x32_bf16(ah4, bm4, c, 0, 0, 0);
                c = __builtin_amdgcn_mfma_f32_16x16x32_bf16(am4, bh4, c, 0, 0, 0);
                c = __builtin_amdgcn_mfma_f32_16x16x32_bf16(ah4, bl4, c, 0, 0, 0);
                c = __builtin_amdgcn_mfma_f32_16x16x32_bf16(am4, bm4, c, 0, 0, 0);
                c = __builtin_amdgcn_mfma_f32_16x16x32_bf16(al4, bh4, c, 0, 0, 0);
                acc[rt][ct] = c;
            }
        }
    }

    // Per-lane argmax over ct (+/- candidates), then fr-butterfly, then LDS.
    #pragma unroll
    for (int rt = 0; rt < 8; ++rt) {
        #pragma unroll
        for (int reg = 0; reg < 4; ++reg) {
            u64 key = 0ull;
            #pragma unroll
            for (int ct = 0; ct < 4; ++ct) {
                float v = acc[rt][ct][reg];
                u32 idxp = nbase + ct * 16 + fr;        // + candidate
                u32 idxn = idxp + 256;                   // - candidate
                u64 kp = ((u64)ordf(v) << 32) | (u32)(0xFFFFFFFFu - idxp);
                u64 kn = ((u64)ordf(-v) << 32) | (u32)(0xFFFFFFFFu - idxn);
                if (kp > key) key = kp;
                if (kn > key) key = kn;
            }
            #pragma unroll
            for (int m = 1; m <= 8; m <<= 1) {
                u64 o = __shfl_xor((unsigned long long)key, m, 64);
                if (o > key) key = o;
            }
            if (fr == 0) {
                int tok = rt * 16 + quad * 4 + reg;
                atomicMax(&best[tok], key);
            }
        }
    }
    __syncthreads();
    if (tid < 128) {
        u32 idx = 0xFFFFFFFFu - (u32)best[tid];
        BKT[((size_t)bh * NHASH + h) * LTOT + t0 + tid] = (int)idx;
    }
}

// ---------------------------------------------------------------------------
// Stable counting sort per (bh, hash): sorted-by-(bucket, t).
// ---------------------------------------------------------------------------
__global__ __launch_bounds__(256) void lsh_sort_kernel(
    const int* __restrict__ BKT, int* __restrict__ STS)
{
    __shared__ unsigned short bkt[2048];
    __shared__ unsigned int hist2[16][512];
    __shared__ unsigned int bstart[512];
    int bid = blockIdx.x;
    int h = bid & 3, bh = bid >> 2;
    int tid = threadIdx.x;
    const int* src = BKT + ((size_t)bh * NHASH + h) * LTOT;
    for (int t = tid; t < 2048; t += 256) bkt[t] = (unsigned short)src[t];
    for (int i = tid; i < 16 * 512; i += 256) (&hist2[0][0])[i] = 0u;
    __syncthreads();
    for (int t = tid; t < 2048; t += 256)
        atomicAdd(&hist2[t >> 7][bkt[t]], 1u);
    __syncthreads();
    for (int bb = tid; bb < 512; bb += 256) {
        unsigned int run = 0;
        #pragma unroll
        for (int g = 0; g < 16; ++g) {
            unsigned int c = hist2[g][bb];
            hist2[g][bb] = run;
            run += c;
        }
        bstart[bb] = run;
    }
    __syncthreads();
    if (tid == 0) {
        unsigned int run = 0;
        for (int bb = 0; bb < 512; ++bb) {
            unsigned int c = bstart[bb];
            bstart[bb] = run;
            run += c;
        }
    }
    __syncthreads();
    int* dst = STS + (size_t)bh * (NHASH * LTOT) + h * LTOT;
    for (int t = tid; t < 2048; t += 256) {
        int bb = bkt[t];
        unsigned int rank = hist2[t >> 7][bb];
        int g0 = t & ~127;
        for (int u = g0; u < t; ++u) rank += (bkt[u] == (unsigned short)bb);
        dst[bstart[bb] + rank] = t;
    }
}

// ---------------------------------------------------------------------------
// Attention pass A (fp32 — r1-proven band-safe): one wave per (bh, chunk).
// ---------------------------------------------------------------------------
__global__ __launch_bounds__(256) void attn_lse_kernel(
    const float* __restrict__ QK, const int* __restrict__ STS,
    float* __restrict__ LSE)
{
    int wid = (blockIdx.x * 256 + threadIdx.x) >> 6;   // global wave id
    int lane = threadIdx.x & 63;
    int bh = wid >> 11;          // 0..63
    int c  = wid & 2047;
    int cp = (c + NCH - 1) & (NCH - 1);
    const int* sts = STS + (size_t)bh * 8192;
    int tok[8];
    #pragma unroll
    for (int j = 0; j < 4; ++j) tok[j] = sts[4 * c + j];
    #pragma unroll
    for (int j = 0; j < 4; ++j) tok[4 + j] = sts[4 * cp + j];
    int b = bh >> 3, hd = bh & 7;
    const float* base = QK + ((size_t)b * LTOT) * DM + hd * DH + lane;
    float kd[8];
    #pragma unroll
    for (int j = 0; j < 8; ++j) kd[j] = base[(size_t)tok[j] * DM];
    float rnrm[8];
    #pragma unroll
    for (int j = 0; j < 8; ++j) {
        float v = kd[j] * kd[j];
        #pragma unroll
        for (int m = 32; m; m >>= 1) v += __shfl_xor(v, m, 64);
        rnrm[j] = 0.125f / fmaxf(sqrtf(v), 1e-12f);
    }
    int hr = c >> 9;
    #pragma unroll
    for (int i = 0; i < 4; ++i) {
        float dots[8];
        #pragma unroll
        for (int j = 0; j < 8; ++j) {
            float v = kd[i] * kd[j];
            #pragma unroll
            for (int m = 32; m; m >>= 1) v += __shfl_xor(v, m, 64);
            dots[j] = (tok[j] == tok[i]) ? -5e4f : v * rnrm[j];
        }
        float mx = dots[0];
        #pragma unroll
        for (int j = 1; j < 8; ++j) mx = fmaxf(mx, dots[j]);
        float s = 0.f;
        #pragma unroll
        for (int j = 0; j < 8; ++j) s += expf(dots[j] - mx);
        if (lane == 0)
            LSE[((size_t)bh * NHASH + hr) * LTOT + tok[i]] = mx + logf(s);
    }
}

// ---------------------------------------------------------------------------
// Attention pass B (fp32): recompute dots, hash-round weights, fp32 atomics.
// ---------------------------------------------------------------------------
__global__ __launch_bounds__(256) void attn_out_kernel(
    const float* __restrict__ QK, const float* __restrict__ V,
    const int* __restrict__ STS, const float* __restrict__ LSE,
    float* __restrict__ C)
{
    int wid = (blockIdx.x * 256 + threadIdx.x) >> 6;
    int lane = threadIdx.x & 63;
    int bh = wid >> 11;
    int c  = wid & 2047;
    int cp = (c + NCH - 1) & (NCH - 1);
    const int* sts = STS + (size_t)bh * 8192;
    int tok[8];
    #pragma unroll
    for (int j = 0; j < 4; ++j) tok[j] = sts[4 * c + j];
    #pragma unroll
    for (int j = 0; j < 4; ++j) tok[4 + j] = sts[4 * cp + j];
    int b = bh >> 3, hd = bh & 7;
    const float* base = QK + ((size_t)b * LTOT) * DM + hd * DH + lane;
    const float* vbase = V + ((size_t)b * LTOT) * DM + hd * DH + lane;
    float kd[8], vd[8];
    #pragma unroll
    for (int j = 0; j < 8; ++j) kd[j] = base[(size_t)tok[j] * DM];
    #pragma unroll
    for (int j = 0; j < 8; ++j) vd[j] = vbase[(size_t)tok[j] * DM];
    float rnrm[8];
    #pragma unroll
    for (int j = 0; j < 8; ++j) {
        float v = kd[j] * kd[j];
        #pragma unroll
        for (int m = 32; m; m >>= 1) v += __shfl_xor(v, m, 64);
        rnrm[j] = 0.125f / fmaxf(sqrtf(v), 1e-12f);
    }
    int hr = c >> 9;
    float* crow0 = C + ((size_t)b * LTOT) * DM + hd * DH + lane;
    #pragma unroll
    for (int i = 0; i < 4; ++i) {
        float dots[8];
        #pragma unroll
        for (int j = 0; j < 8; ++j) {
            float v = kd[i] * kd[j];
            #pragma unroll
            for (int m = 32; m; m >>= 1) v += __shfl_xor(v, m, 64);
            dots[j] = (tok[j] == tok[i]) ? -5e4f : v * rnrm[j];
        }
        float Lh[4];
        #pragma unroll
        for (int hh = 0; hh < 4; ++hh)
            Lh[hh] = LSE[((size_t)bh * NHASH + hh) * LTOT + tok[i]];
        float my = Lh[hr];
        float wm = fmaxf(fmaxf(Lh[0], Lh[1]), fmaxf(Lh[2], Lh[3]));
        float wsum = 0.f;
        #pragma unroll
        for (int hh = 0; hh < 4; ++hh) wsum += expf(Lh[hh] - wm);
        float w = expf(my - wm) / wsum;
        float acc = 0.f;
        #pragma unroll
        for (int j = 0; j < 8; ++j) acc += expf(dots[j] - my) * vd[j];
        atomicAdd(crow0 + (size_t)tok[i] * DM, acc * w);
    }
}

// ---------------------------------------------------------------------------
// LayerNorm over last dim (512). fp64 stats + transform, fp32 out.
// ---------------------------------------------------------------------------
__global__ __launch_bounds__(256) void ln_kernel(
    const float* __restrict__ X, float* __restrict__ Y,
    const float* __restrict__ g, const float* __restrict__ bta)
{
    int row = blockIdx.x;
    int tid = threadIdx.x;
    const float* x = X + (size_t)row * DM;
    double v0 = (double)x[tid], v1 = (double)x[tid + 256];
    double s = v0 + v1;
    double q = v0 * v0 + v1 * v1;
    #pragma unroll
    for (int off = 32; off; off >>= 1) {
        s += __shfl_down(s, off, 64);
        q += __shfl_down(q, off, 64);
    }
    __shared__ double ss[4], qq[4];
    int wid = tid >> 6, lane = tid & 63;
    if (lane == 0) { ss[wid] = s; qq[wid] = q; }
    __syncthreads();
    if (tid == 0) {
        double S = ss[0] + ss[1] + ss[2] + ss[3];
        double Q = qq[0] + qq[1] + qq[2] + qq[3];
        double mu = S * (1.0 / 512.0);
        double var = Q * (1.0 / 512.0) - mu * mu;
        ss[0] = mu;
        qq[0] = 1.0 / sqrt(var + 1e-5);
    }
    __syncthreads();
    double mu = ss[0], rs = qq[0];
    Y[(size_t)row * DM + tid] =
        (float)((v0 - mu) * rs * (double)g[tid] + (double)bta[tid]);
    Y[(size_t)row * DM + tid + 256] =
        (float)((v1 - mu) * rs * (double)g[tid + 256] + (double)bta[tid + 256]);
}

// ---------------------------------------------------------------------------
// Final projection + slice (fp64 acc, fp32 out).
// ---------------------------------------------------------------------------
__global__ __launch_bounds__(64) void proj_kernel(
    const float* __restrict__ Hf, const float* __restrict__ pw,
    const float* __restrict__ pb, float* __restrict__ out)
{
    int idx = blockIdx.x;               // 0..4095
    int b = idx >> 9, i = idx & 511;
    const float* row = Hf + ((size_t)(b * LTOT + SEQ + i)) * DM;
    int lane = threadIdx.x;
    double s = 0.0;
    #pragma unroll
    for (int k = 0; k < 8; ++k)
        s += (double)row[lane + 64 * k] * (double)pw[lane + 64 * k];
    #pragma unroll
    for (int off = 32; off; off >>= 1) s += __shfl_down(s, off, 64);
    if (lane == 0) out[idx] = (float)(s + (double)pb[0]);
}

// ---------------------------------------------------------------------------
extern "C" void kernel_launch(void* const* d_in, const int* in_sizes, int n_in,
                              void* d_out, int out_size, void* d_ws, size_t ws_size,
                              hipStream_t stream)
{
    const float* x_enc      = (const float*)d_in[0];
    const float* x_mark_enc = (const float*)d_in[1];
    const float* x_dec      = (const float*)d_in[2];
    const float* x_mark_dec = (const float*)d_in[3];
    const float* token_w    = (const float*)d_in[4];
    const float* temp_w     = (const float*)d_in[5];
    const float* qk_w       = (const float*)d_in[6];
    const float* v_w        = (const float*)d_in[7];
    const float* out_w      = (const float*)d_in[8];
    const float* out_b      = (const float*)d_in[9];
    const float* ln1_g      = (const float*)d_in[10];
    const float* ln1_b      = (const float*)d_in[11];
    const float* ff1_w      = (const float*)d_in[12];
    const float* ff1_b      = (const float*)d_in[13];
    const float* ff2_w      = (const float*)d_in[14];
    const float* ff2_b      = (const float*)d_in[15];
    const float* ln2_g      = (const float*)d_in[16];
    const float* ln2_b      = (const float*)d_in[17];
    const float* norm_g     = (const float*)d_in[18];
    const float* norm_b     = (const float*)d_in[19];
    const float* proj_w     = (const float*)d_in[20];
    const float* proj_b     = (const float*)d_in[21];
    const float* rotations  = (const float*)d_in[22];

    float* ws = (float*)d_ws;
    const size_t S = (size_t)BATCH * LTOT * DM;   // 8,388,608 floats
    float* Hb  = ws;
    float* QKb = ws + S;
    float* Vb  = ws + 2 * S;
    float* Cb  = ws + 3 * S;
    float* Yb  = QKb;                    // FFN intermediate: spans QKb+Vb (2S)
    int*   BKTb = (int*)(ws + 4 * S);              // 2 MB
    float* LSEb = ws + 4 * S + 524288;             // 2 MB
    int*   STSb = (int*)(ws + 4 * S + 2 * 524288); // 2 MB
    u16*   RShb = (u16*)(ws + 4 * S + 3 * 524288); // 128 KB x3 planes
    u16*   RSmb = RShb + 4 * 256 * 64;
    u16*   RSlb = RSmb + 4 * 256 * 64;

    build_h_kernel<<<BATCH * LTOT, 512, 0, stream>>>(
        x_enc, x_mark_enc, x_dec, x_mark_dec, token_w, temp_w, Hb);

    const int M = BATCH * LTOT;  // 16384
    const int ATT_BLOCKS = NBH * NCH / 4;  // 32768 waves / 4 per block
    for (int l = 0; l < 2; ++l) {
        const float* qkw = qk_w + (size_t)l * DM * DM;
        const float* vw  = v_w  + (size_t)l * DM * DM;
        const float* ow  = out_w + (size_t)l * DM * DM;
        const float* ob  = out_b + (size_t)l * DM;
        const float* l1g = ln1_g + (size_t)l * DM;
        const float* l1b = ln1_b + (size_t)l * DM;
        const float* f1w = ff1_w + (size_t)l * DFF * DM;
        const float* f1b = ff1_b + (size_t)l * DFF;
        const float* f2w = ff2_w + (size_t)l * DM * DFF;
        const float* f2b = ff2_b + (size_t)l * DM;
        const float* l2g = ln2_g + (size_t)l * DM;
        const float* l2b = ln2_b + (size_t)l * DM;
        const float* rot = rotations + (size_t)l * DH * NHASH * 256;

        dim3 gQ(DM / 128, M / 128);  // (4, 128)
        gemm_mfma<3><<<gQ, 256, 0, stream>>>(Hb, qkw, nullptr, nullptr, QKb, M, DM, DM, 0);
        if (l == 0)
            gemm_mfma<3><<<gQ, 256, 0, stream>>>(Hb, vw, nullptr, nullptr, Vb, M, DM, DM, 0);
        else
            gemm_mfma<2><<<gQ, 256, 0, stream>>>(Hb, vw, nullptr, nullptr, Vb, M, DM, DM, 0);

        rot_split_kernel<<<4, 256, 0, stream>>>(rot, RShb, RSmb, RSlb);
        lsh_hash_mfma<<<NBH * NHASH * 16, 256, 0, stream>>>(QKb, RShb, RSmb, RSlb, BKTb);
        lsh_sort_kernel<<<NBH * NHASH, 256, 0, stream>>>(BKTb, STSb);

        hipMemsetAsync(Cb, 0, S * sizeof(float), stream);
        attn_lse_kernel<<<ATT_BLOCKS, 256, 0, stream>>>(QKb, STSb, LSEb);
        attn_out_kernel<<<ATT_BLOCKS, 256, 0, stream>>>(QKb, Vb, STSb, LSEb, Cb);

        // h = h + attn @ out_w^T + out_b   (in-place residual)
        if (l == 0)
            gemm_mfma<3><<<gQ, 256, 0, stream>>>(Cb, ow, ob, Hb, Hb, M, DM, DM, 0);
        else
            gemm_mfma<2><<<gQ, 256, 0, stream>>>(Cb, ow, ob, Hb, Hb, M, DM, DM, 0);
        ln_kernel<<<M, 256, 0, stream>>>(Hb, Hb, l1g, l1b);

        // FFN in 2 row-halves of 8192; Y spans QKb+Vb; ff2 in-place into Hb.
        for (int hb2 = 0; hb2 < 2; ++hb2) {
            float* hpart = Hb + (size_t)hb2 * 8192 * DM;
            dim3 gF1(DFF / 128, 8192 / 128);  // (16, 64) = 1024 blocks
            dim3 gF2(DM / 128, 8192 / 128);   // (4, 64)  = 256 blocks
            if (l == 0) {
                gemm_mfma<3><<<gF1, 256, 0, stream>>>(hpart, f1w, f1b, nullptr, Yb, 8192, DFF, DM, 1);
                gemm_mfma<3><<<gF2, 256, 0, stream>>>(Yb, f2w, f2b, hpart, hpart, 8192, DM, DFF, 0);
            } else {
                gemm_mfma<2><<<gF1, 256, 0, stream>>>(hpart, f1w, f1b, nullptr, Yb, 8192, DFF, DM, 1);
                gemm_mfma<2><<<gF2, 256, 0, stream>>>(Yb, f2w, f2b, hpart, hpart, 8192, DM, DFF, 0);
            }
        }
        ln_kernel<<<M, 256, 0, stream>>>(Hb, Hb, l2g, l2b);
    }

    ln_kernel<<<M, 256, 0, stream>>>(Hb, Cb, norm_g, norm_b);
    proj_kernel<<<4096, 64, 0, stream>>>(Cb, proj_w, proj_b, (float*)d_out);
}

// Round 10
// 3504.242 us; speedup vs baseline: 3.1314x; 1.0384x over previous
//
#include <hip/hip_runtime.h>
#include <math.h>

#define BATCH 8
#define LTOT 2048
#define DM 512
#define NHEADS 8
#define DH 64
#define NBH 64
#define NHASH 4
#define SEQ 1536
#define DECL 768
#define DFF 2048
#define NCH 2048   // total chunks (4 rounds * 512)

typedef unsigned short u16;
typedef unsigned int u32;
typedef unsigned long long u64;
typedef __attribute__((ext_vector_type(8))) short short8;   // 8 bf16 = 4 VGPR
typedef __attribute__((ext_vector_type(4))) float floatx4;  // MFMA C/D

static __device__ __forceinline__ double gelu_d(double x) {
    return 0.5 * x * (1.0 + erf(x * 0.70710678118654752440));
}

static __device__ __forceinline__ u16 f2bf(float x) {   // RNE float->bf16 bits
    u32 u = __float_as_uint(x);
    return (u16)((u + 0x7fffu + ((u >> 16) & 1u)) >> 16);
}
static __device__ __forceinline__ float bf2f(u16 h) {
    return __uint_as_float(((u32)h) << 16);
}
static __device__ __forceinline__ void split3(float x, u16& h, u16& m, u16& l) {
    h = f2bf(x);
    float r1 = x - bf2f(h);
    m = f2bf(r1);
    l = f2bf(r1 - bf2f(m));
}
static __device__ __forceinline__ u32 ordf(float x) {   // monotone float->u32
    u32 b = __float_as_uint(x);
    return (b & 0x80000000u) ? ~b : (b | 0x80000000u);
}
// pack top-16 bits of two fp32: low u16 = a>>16, high u16 = b>>16 (1 v_perm)
static __device__ __forceinline__ u32 pack_hi16(u32 a, u32 b) {
    return __builtin_amdgcn_perm(b, a, 0x07060302u);
}
// truncation split-3: h,m,l = successive top-16 truncations (exact subs).
// h+m+l == x to ~2^-24 rel; dropped MFMA cross terms ~2^-25 — inside the
// measured flip-invariance band (r1 1.3e-6 == r4 1e-13 flip sets).
static __device__ __forceinline__ void tsplit3_pack(
    float x0, float x1, u32& ph, u32& pm, u32& pl)
{
    u32 b0 = __float_as_uint(x0), b1 = __float_as_uint(x1);
    ph = pack_hi16(b0, b1);
    float r0 = x0 - __uint_as_float(b0 & 0xFFFF0000u);
    float r1 = x1 - __uint_as_float(b1 & 0xFFFF0000u);
    u32 c0 = __float_as_uint(r0), c1 = __float_as_uint(r1);
    pm = pack_hi16(c0, c1);
    float s0 = r0 - __uint_as_float(c0 & 0xFFFF0000u);
    float s1 = r1 - __uint_as_float(c1 & 0xFFFF0000u);
    pl = pack_hi16(__float_as_uint(s0), __float_as_uint(s1));
}
static __device__ __forceinline__ void tsplit2_pack(
    float x0, float x1, u32& ph, u32& pm)
{
    u32 b0 = __float_as_uint(x0), b1 = __float_as_uint(x1);
    ph = pack_hi16(b0, b1);
    float r0 = x0 - __uint_as_float(b0 & 0xFFFF0000u);
    float r1 = x1 - __uint_as_float(b1 & 0xFFFF0000u);
    pm = pack_hi16(__float_as_uint(r0), __float_as_uint(r1));
}

// ---------------------------------------------------------------------------
// h = TokenConv(x) + TimeLinear(xm) + PE   -> H [B, L, 512]
// PE mimics numpy-fp32 rounding points: e, div, ang rounded to fp32.
// ---------------------------------------------------------------------------
__global__ __launch_bounds__(512) void build_h_kernel(
    const float* __restrict__ x_enc, const float* __restrict__ x_mark_enc,
    const float* __restrict__ x_dec, const float* __restrict__ x_mark_dec,
    const float* __restrict__ token_w, const float* __restrict__ temp_w,
    float* __restrict__ H)
{
    int bl = blockIdx.x;
    int b = bl >> 11, l = bl & 2047;
    __shared__ float xr[3][7];
    __shared__ float xmr[4];
    int tid = threadIdx.x;
    if (tid < 21) {
        int k = tid / 7, c = tid % 7;
        int t = (l + k - 1 + LTOT) & 2047;
        float v;
        if (t < SEQ) v = x_enc[(b * SEQ + t) * 7 + c];
        else         v = x_dec[(b * DECL + (t - 1280)) * 7 + c];
        xr[k][c] = v;
    } else if (tid < 25) {
        int m = tid - 21;
        float v;
        if (l < SEQ) v = x_mark_enc[(b * SEQ + l) * 4 + m];
        else         v = x_mark_dec[(b * DECL + (l - 1280)) * 4 + m];
        xmr[m] = v;
    }
    __syncthreads();
    int d = tid;  // 0..511
    double val = 0.0;
    #pragma unroll
    for (int k = 0; k < 3; ++k)
        #pragma unroll
        for (int c = 0; c < 7; ++c)
            val += (double)xr[k][c] * (double)token_w[(d * 7 + c) * 3 + k];
    double tmp = 0.0;
    #pragma unroll
    for (int m = 0; m < 4; ++m) tmp += (double)xmr[m] * (double)temp_w[d * 4 + m];
    const float cf = (float)(-9.210340371976184 / 512.0);
    float ef  = (float)(2 * (d >> 1)) * cf;
    float dvf = (float)exp((double)ef);
    float angf = (float)l * dvf;
    double pe = (d & 1) ? cos((double)angf) : sin((double)angf);
    H[((size_t)b * LTOT + l) * DM + d] = (float)(val + tmp + pe);
}

// ---------------------------------------------------------------------------
// Pre-split a layer's 5 weight matrices into trunc-bf16 h/m/l u16 planes.
// Element offsets: qk 0, v 262144, out 524288, ff1 786432, ff2 1835008.
// ---------------------------------------------------------------------------
__global__ __launch_bounds__(256) void wsplit_kernel(
    const float* __restrict__ qkw, const float* __restrict__ vw,
    const float* __restrict__ ow, const float* __restrict__ f1w,
    const float* __restrict__ f2w,
    u16* __restrict__ Ph, u16* __restrict__ Pm, u16* __restrict__ Pl)
{
    size_t i = ((size_t)blockIdx.x * 256 + threadIdx.x) * 4;
    const float* src; size_t off;
    if (i < 262144)       { src = qkw; off = i; }
    else if (i < 524288)  { src = vw;  off = i - 262144; }
    else if (i < 786432)  { src = ow;  off = i - 524288; }
    else if (i < 1835008) { src = f1w; off = i - 786432; }
    else                  { src = f2w; off = i - 1835008; }
    float4 x = *(const float4*)(src + off);
    u32 h01, m01, l01, h23, m23, l23;
    tsplit3_pack(x.x, x.y, h01, m01, l01);
    tsplit3_pack(x.z, x.w, h23, m23, l23);
    *(uint2*)(Ph + i) = make_uint2(h01, h23);
    *(uint2*)(Pm + i) = make_uint2(m01, m23);
    *(uint2*)(Pl + i) = make_uint2(l01, l23);
}

// ---------------------------------------------------------------------------
// MFMA split-bf16 GEMM: C[M,N] = act( A[M,K] @ W[N,K]^T + bias + res )
// A split in-kernel (trunc packs); W read from pre-split u16 planes.
// ---------------------------------------------------------------------------
template<int NSPLIT>
__global__ __launch_bounds__(256) void gemm_mfma(
    const float* __restrict__ A,
    const u16* __restrict__ RWh, const u16* __restrict__ RWm,
    const u16* __restrict__ RWl,
    const float* __restrict__ bias, const float* __restrict__ res,
    float* __restrict__ C, int M, int N, int K, int act)
{
    __shared__ u16 Ah[128][32], Am[128][32], Al[128][32];
    __shared__ u16 Wh[128][32], Wm[128][32], Wl[128][32];
    const int tid = threadIdx.x;
    const int n0 = blockIdx.x * 128, m0 = blockIdx.y * 128;
    const int row = tid >> 1;           // 0..127
    const int koff = (tid & 1) * 16;    // 0 or 16
    const float* Ag = A + (size_t)(m0 + row) * K + koff;
    const u16* Wgh = RWh + (size_t)(n0 + row) * K + koff;
    const u16* Wgm = RWm + (size_t)(n0 + row) * K + koff;
    const u16* Wgl = RWl + (size_t)(n0 + row) * K + koff;

    const int wv = tid >> 6, lane = tid & 63;
    const int m0w = (wv >> 1) * 64, n0w = (wv & 1) * 64;
    const int fr = lane & 15, quad = lane >> 4;

    floatx4 acc[4][4];
    #pragma unroll
    for (int i = 0; i < 4; ++i)
        #pragma unroll
        for (int j = 0; j < 4; ++j) acc[i][j] = (floatx4)0.0f;

    for (int kt = 0; kt < K; kt += 32) {
        // W planes: straight u16 loads.
        uint4 wh0 = *(const uint4*)(Wgh + kt);
        uint4 wh1 = *(const uint4*)(Wgh + kt + 8);
        uint4 wm0 = *(const uint4*)(Wgm + kt);
        uint4 wm1 = *(const uint4*)(Wgm + kt + 8);
        uint4 wl0, wl1;
        if (NSPLIT == 3) {
            wl0 = *(const uint4*)(Wgl + kt);
            wl1 = *(const uint4*)(Wgl + kt + 8);
        }
        // A: load fp32, trunc-split.
        u32 pah[8], pam[8], pal[8];
        #pragma unroll
        for (int g = 0; g < 4; ++g) {
            float4 a4 = *(const float4*)(Ag + kt + g * 4);
            if (NSPLIT == 3) {
                tsplit3_pack(a4.x, a4.y, pah[g*2], pam[g*2], pal[g*2]);
                tsplit3_pack(a4.z, a4.w, pah[g*2+1], pam[g*2+1], pal[g*2+1]);
            } else {
                tsplit2_pack(a4.x, a4.y, pah[g*2], pam[g*2]);
                tsplit2_pack(a4.z, a4.w, pah[g*2+1], pam[g*2+1]);
            }
        }
        __syncthreads();
        ((uint4*)&Ah[row][koff])[0] = make_uint4(pah[0], pah[1], pah[2], pah[3]);
        ((uint4*)&Ah[row][koff])[1] = make_uint4(pah[4], pah[5], pah[6], pah[7]);
        ((uint4*)&Am[row][koff])[0] = make_uint4(pam[0], pam[1], pam[2], pam[3]);
        ((uint4*)&Am[row][koff])[1] = make_uint4(pam[4], pam[5], pam[6], pam[7]);
        ((uint4*)&Wh[row][koff])[0] = wh0;
        ((uint4*)&Wh[row][koff])[1] = wh1;
        ((uint4*)&Wm[row][koff])[0] = wm0;
        ((uint4*)&Wm[row][koff])[1] = wm1;
        if (NSPLIT == 3) {
            ((uint4*)&Al[row][koff])[0] = make_uint4(pal[0], pal[1], pal[2], pal[3]);
            ((uint4*)&Al[row][koff])[1] = make_uint4(pal[4], pal[5], pal[6], pal[7]);
            ((uint4*)&Wl[row][koff])[0] = wl0;
            ((uint4*)&Wl[row][koff])[1] = wl1;
        }
        __syncthreads();
        short8 ah4[4], am4[4], al4[4];
        #pragma unroll
        for (int rt = 0; rt < 4; ++rt) {
            int r = m0w + rt * 16 + fr;
            ah4[rt] = *(const short8*)&Ah[r][quad * 8];
            am4[rt] = *(const short8*)&Am[r][quad * 8];
            if (NSPLIT == 3) al4[rt] = *(const short8*)&Al[r][quad * 8];
        }
        #pragma unroll
        for (int ct = 0; ct < 4; ++ct) {
            int nrw = n0w + ct * 16 + fr;
            short8 bh4 = *(const short8*)&Wh[nrw][quad * 8];
            short8 bm4 = *(const short8*)&Wm[nrw][quad * 8];
            short8 bl4;
            if (NSPLIT == 3) bl4 = *(const short8*)&Wl[nrw][quad * 8];
            #pragma unroll
            for (int rt = 0; rt < 4; ++rt) {
                floatx4 c = acc[rt][ct];
                c = __builtin_amdgcn_mfma_f32_16x16x32_bf16(ah4[rt], bh4, c, 0, 0, 0);
                c = __builtin_amdgcn_mfma_f32_16x16x32_bf16(ah4[rt], bm4, c, 0, 0, 0);
                c = __builtin_amdgcn_mfma_f32_16x16x32_bf16(am4[rt], bh4, c, 0, 0, 0);
                if (NSPLIT == 3) {
                    c = __builtin_amdgcn_mfma_f32_16x16x32_bf16(ah4[rt], bl4, c, 0, 0, 0);
                    c = __builtin_amdgcn_mfma_f32_16x16x32_bf16(am4[rt], bm4, c, 0, 0, 0);
                    c = __builtin_amdgcn_mfma_f32_16x16x32_bf16(al4[rt], bh4, c, 0, 0, 0);
                }
                acc[rt][ct] = c;
            }
        }
    }
    // Epilogue: C/D layout col=lane&15, row=quad*4+reg (m89-verified).
    #pragma unroll
    for (int rt = 0; rt < 4; ++rt) {
        #pragma unroll
        for (int ct = 0; ct < 4; ++ct) {
            int n = n0 + n0w + ct * 16 + fr;
            #pragma unroll
            for (int reg = 0; reg < 4; ++reg) {
                int m = m0 + m0w + rt * 16 + quad * 4 + reg;
                double v = (double)acc[rt][ct][reg];
                if (bias) v += (double)bias[n];
                if (res)  v += (double)res[(size_t)m * N + n];
                if (act == 1) v = gelu_d(v);
                C[(size_t)m * N + n] = (float)v;
            }
        }
    }
}

// ---------------------------------------------------------------------------
// Precompute split-3 bf16 planes of rot, transposed to [h][r][d].
// ---------------------------------------------------------------------------
__global__ __launch_bounds__(256) void rot_split_kernel(
    const float* __restrict__ rot, u16* __restrict__ RSh,
    u16* __restrict__ RSm, u16* __restrict__ RSl)
{
    int h = blockIdx.x;      // 0..3
    int r = threadIdx.x;     // 0..255
    #pragma unroll 4
    for (int d = 0; d < 64; ++d) {
        float v = rot[(d * 4 + h) * 256 + r];
        u16 hh, mm, ll;
        split3(v, hh, mm, ll);
        size_t o = ((size_t)h * 256 + r) * 64 + d;
        RSh[o] = hh; RSm[o] = mm; RSl[o] = ll;
    }
}

// ---------------------------------------------------------------------------
// LSH hash via split-3 bf16 MFMA + fused argmax (r9-verified).
// ---------------------------------------------------------------------------
__global__ __launch_bounds__(256) void lsh_hash_mfma(
    const float* __restrict__ QK, const u16* __restrict__ RSh,
    const u16* __restrict__ RSm, const u16* __restrict__ RSl,
    int* __restrict__ BKT)
{
    __shared__ u16 Ah[128][72], Am[128][72], Al[128][72];  // padded rows
    __shared__ u64 best[128];
    int bid = blockIdx.x;
    int tt = bid & 15;
    int h  = (bid >> 4) & 3;
    int bh = bid >> 6;
    int tid = threadIdx.x;
    int b = bh >> 3, hd = bh & 7;
    const int t0 = tt * 128;

    if (tid < 128) best[tid] = 0ull;

    {
        int row = tid >> 1;
        int kbase = (tid & 1) * 32;
        const float* src = QK + ((size_t)(b * LTOT + t0 + row)) * DM + hd * DH + kbase;
        u32 ph[16], pm[16], pl[16];
        #pragma unroll
        for (int g = 0; g < 8; ++g) {
            float4 a4 = *(const float4*)(src + g * 4);
            u16 h0, m0_, l0, h1, m1_, l1;
            split3(a4.x, h0, m0_, l0); split3(a4.y, h1, m1_, l1);
            ph[g*2]   = (u32)h0 | ((u32)h1 << 16);
            pm[g*2]   = (u32)m0_ | ((u32)m1_ << 16);
            pl[g*2]   = (u32)l0 | ((u32)l1 << 16);
            split3(a4.z, h0, m0_, l0); split3(a4.w, h1, m1_, l1);
            ph[g*2+1] = (u32)h0 | ((u32)h1 << 16);
            pm[g*2+1] = (u32)m0_ | ((u32)m1_ << 16);
            pl[g*2+1] = (u32)l0 | ((u32)l1 << 16);
        }
        #pragma unroll
        for (int g = 0; g < 4; ++g) {
            ((uint4*)&Ah[row][kbase])[g] = make_uint4(ph[g*4], ph[g*4+1], ph[g*4+2], ph[g*4+3]);
            ((uint4*)&Am[row][kbase])[g] = make_uint4(pm[g*4], pm[g*4+1], pm[g*4+2], pm[g*4+3]);
            ((uint4*)&Al[row][kbase])[g] = make_uint4(pl[g*4], pl[g*4+1], pl[g*4+2], pl[g*4+3]);
        }
    }
    __syncthreads();

    const int wv = tid >> 6, lane = tid & 63;
    const int fr = lane & 15, quad = lane >> 4;
    const int nbase = wv * 64;

    floatx4 acc[8][4];
    #pragma unroll
    for (int i = 0; i < 8; ++i)
        #pragma unroll
        for (int j = 0; j < 4; ++j) acc[i][j] = (floatx4)0.0f;

    #pragma unroll
    for (int kt = 0; kt < 2; ++kt) {
        #pragma unroll
        for (int ct = 0; ct < 4; ++ct) {
            size_t bo = ((size_t)h * 256 + nbase + ct * 16 + fr) * 64 + kt * 32 + quad * 8;
            short8 bh4 = *(const short8*)(RSh + bo);
            short8 bm4 = *(const short8*)(RSm + bo);
            short8 bl4 = *(const short8*)(RSl + bo);
            #pragma unroll
            for (int rt = 0; rt < 8; ++rt) {
                const int ar = rt * 16 + fr, ak = kt * 32 + quad * 8;
                short8 ah4 = *(const short8*)&Ah[ar][ak];
                short8 am4 = *(const short8*)&Am[ar][ak];
                short8 al4 = *(const short8*)&Al[ar][ak];
                floatx4 c = acc[rt][ct];
                c = __builtin_amdgcn_mfma_f32_16x16x32_bf16(ah4, bh4, c, 0, 0, 0);
                c = __builtin_amdgcn_mfma_f32_16x16x32_bf16(ah4, bm4, c, 0, 0, 0);
                c = __builtin_amdgcn_mfma_f32_16x16x32_bf16(am4, bh4, c, 0, 0, 0);
                c = __builtin_amdgcn_mfma_f32_16x16x32_bf16(ah4, bl4, c, 0, 0, 0);
                c = __builtin_amdgcn_mfma_f32_16x16x32_bf16(am4, bm4, c, 0, 0, 0);
                c = __builtin_amdgcn_mfma_f32_16x16x32_bf16(al4, bh4, c, 0, 0, 0);
                acc[rt][ct] = c;
            }
        }
    }

    #pragma unroll
    for (int rt = 0; rt < 8; ++rt) {
        #pragma unroll
        for (int reg = 0; reg < 4; ++reg) {
            u64 key = 0ull;
            #pragma unroll
            for (int ct = 0; ct < 4; ++ct) {
                float v = acc[rt][ct][reg];
                u32 idxp = nbase + ct * 16 + fr;        // + candidate
                u32 idxn = idxp + 256;                   // - candidate
                u64 kp = ((u64)ordf(v) << 32) | (u32)(0xFFFFFFFFu - idxp);
                u64 kn = ((u64)ordf(-v) << 32) | (u32)(0xFFFFFFFFu - idxn);
                if (kp > key) key = kp;
                if (kn > key) key = kn;
            }
            #pragma unroll
            for (int m = 1; m <= 8; m <<= 1) {
                u64 o = __shfl_xor((unsigned long long)key, m, 64);
                if (o > key) key = o;
            }
            if (fr == 0) {
                int tok = rt * 16 + quad * 4 + reg;
                atomicMax(&best[tok], key);
            }
        }
    }
    __syncthreads();
    if (tid < 128) {
        u32 idx = 0xFFFFFFFFu - (u32)best[tid];
        BKT[((size_t)bh * NHASH + h) * LTOT + t0 + tid] = (int)idx;
    }
}

// ---------------------------------------------------------------------------
// Stable counting sort per (bh, hash): sorted-by-(bucket, t).
// ---------------------------------------------------------------------------
__global__ __launch_bounds__(256) void lsh_sort_kernel(
    const int* __restrict__ BKT, int* __restrict__ STS)
{
    __shared__ unsigned short bkt[2048];
    __shared__ unsigned int hist2[16][512];
    __shared__ unsigned int bstart[512];
    int bid = blockIdx.x;
    int h = bid & 3, bh = bid >> 2;
    int tid = threadIdx.x;
    const int* src = BKT + ((size_t)bh * NHASH + h) * LTOT;
    for (int t = tid; t < 2048; t += 256) bkt[t] = (unsigned short)src[t];
    for (int i = tid; i < 16 * 512; i += 256) (&hist2[0][0])[i] = 0u;
    __syncthreads();
    for (int t = tid; t < 2048; t += 256)
        atomicAdd(&hist2[t >> 7][bkt[t]], 1u);
    __syncthreads();
    for (int bb = tid; bb < 512; bb += 256) {
        unsigned int run = 0;
        #pragma unroll
        for (int g = 0; g < 16; ++g) {
            unsigned int c = hist2[g][bb];
            hist2[g][bb] = run;
            run += c;
        }
        bstart[bb] = run;
    }
    __syncthreads();
    if (tid == 0) {
        unsigned int run = 0;
        for (int bb = 0; bb < 512; ++bb) {
            unsigned int c = bstart[bb];
            bstart[bb] = run;
            run += c;
        }
    }
    __syncthreads();
    int* dst = STS + (size_t)bh * (NHASH * LTOT) + h * LTOT;
    for (int t = tid; t < 2048; t += 256) {
        int bb = bkt[t];
        unsigned int rank = hist2[t >> 7][bb];
        int g0 = t & ~127;
        for (int u = g0; u < t; ++u) rank += (bkt[u] == (unsigned short)bb);
        dst[bstart[bb] + rank] = t;
    }
}

// ---------------------------------------------------------------------------
// Attention pass A (fp32 — r1-proven band-safe): one wave per (bh, chunk).
// ---------------------------------------------------------------------------
__global__ __launch_bounds__(256) void attn_lse_kernel(
    const float* __restrict__ QK, const int* __restrict__ STS,
    float* __restrict__ LSE)
{
    int wid = (blockIdx.x * 256 + threadIdx.x) >> 6;   // global wave id
    int lane = threadIdx.x & 63;
    int bh = wid >> 11;          // 0..63
    int c  = wid & 2047;
    int cp = (c + NCH - 1) & (NCH - 1);
    const int* sts = STS + (size_t)bh * 8192;
    int tok[8];
    #pragma unroll
    for (int j = 0; j < 4; ++j) tok[j] = sts[4 * c + j];
    #pragma unroll
    for (int j = 0; j < 4; ++j) tok[4 + j] = sts[4 * cp + j];
    int b = bh >> 3, hd = bh & 7;
    const float* base = QK + ((size_t)b * LTOT) * DM + hd * DH + lane;
    float kd[8];
    #pragma unroll
    for (int j = 0; j < 8; ++j) kd[j] = base[(size_t)tok[j] * DM];
    float rnrm[8];
    #pragma unroll
    for (int j = 0; j < 8; ++j) {
        float v = kd[j] * kd[j];
        #pragma unroll
        for (int m = 32; m; m >>= 1) v += __shfl_xor(v, m, 64);
        rnrm[j] = 0.125f / fmaxf(sqrtf(v), 1e-12f);
    }
    int hr = c >> 9;
    #pragma unroll
    for (int i = 0; i < 4; ++i) {
        float dots[8];
        #pragma unroll
        for (int j = 0; j < 8; ++j) {
            float v = kd[i] * kd[j];
            #pragma unroll
            for (int m = 32; m; m >>= 1) v += __shfl_xor(v, m, 64);
            dots[j] = (tok[j] == tok[i]) ? -5e4f : v * rnrm[j];
        }
        float mx = dots[0];
        #pragma unroll
        for (int j = 1; j < 8; ++j) mx = fmaxf(mx, dots[j]);
        float s = 0.f;
        #pragma unroll
        for (int j = 0; j < 8; ++j) s += expf(dots[j] - mx);
        if (lane == 0)
            LSE[((size_t)bh * NHASH + hr) * LTOT + tok[i]] = mx + logf(s);
    }
}

// ---------------------------------------------------------------------------
// Attention pass B (fp32): recompute dots, hash-round weights, fp32 atomics.
// ---------------------------------------------------------------------------
__global__ __launch_bounds__(256) void attn_out_kernel(
    const float* __restrict__ QK, const float* __restrict__ V,
    const int* __restrict__ STS, const float* __restrict__ LSE,
    float* __restrict__ C)
{
    int wid = (blockIdx.x * 256 + threadIdx.x) >> 6;
    int lane = threadIdx.x & 63;
    int bh = wid >> 11;
    int c  = wid & 2047;
    int cp = (c + NCH - 1) & (NCH - 1);
    const int* sts = STS + (size_t)bh * 8192;
    int tok[8];
    #pragma unroll
    for (int j = 0; j < 4; ++j) tok[j] = sts[4 * c + j];
    #pragma unroll
    for (int j = 0; j < 4; ++j) tok[4 + j] = sts[4 * cp + j];
    int b = bh >> 3, hd = bh & 7;
    const float* base = QK + ((size_t)b * LTOT) * DM + hd * DH + lane;
    const float* vbase = V + ((size_t)b * LTOT) * DM + hd * DH + lane;
    float kd[8], vd[8];
    #pragma unroll
    for (int j = 0; j < 8; ++j) kd[j] = base[(size_t)tok[j] * DM];
    #pragma unroll
    for (int j = 0; j < 8; ++j) vd[j] = vbase[(size_t)tok[j] * DM];
    float rnrm[8];
    #pragma unroll
    for (int j = 0; j < 8; ++j) {
        float v = kd[j] * kd[j];
        #pragma unroll
        for (int m = 32; m; m >>= 1) v += __shfl_xor(v, m, 64);
        rnrm[j] = 0.125f / fmaxf(sqrtf(v), 1e-12f);
    }
    int hr = c >> 9;
    float* crow0 = C + ((size_t)b * LTOT) * DM + hd * DH + lane;
    #pragma unroll
    for (int i = 0; i < 4; ++i) {
        float dots[8];
        #pragma unroll
        for (int j = 0; j < 8; ++j) {
            float v = kd[i] * kd[j];
            #pragma unroll
            for (int m = 32; m; m >>= 1) v += __shfl_xor(v, m, 64);
            dots[j] = (tok[j] == tok[i]) ? -5e4f : v * rnrm[j];
        }
        float Lh[4];
        #pragma unroll
        for (int hh = 0; hh < 4; ++hh)
            Lh[hh] = LSE[((size_t)bh * NHASH + hh) * LTOT + tok[i]];
        float my = Lh[hr];
        float wm = fmaxf(fmaxf(Lh[0], Lh[1]), fmaxf(Lh[2], Lh[3]));
        float wsum = 0.f;
        #pragma unroll
        for (int hh = 0; hh < 4; ++hh) wsum += expf(Lh[hh] - wm);
        float w = expf(my - wm) / wsum;
        float acc = 0.f;
        #pragma unroll
        for (int j = 0; j < 8; ++j) acc += expf(dots[j] - my) * vd[j];
        atomicAdd(crow0 + (size_t)tok[i] * DM, acc * w);
    }
}

// ---------------------------------------------------------------------------
// LayerNorm over last dim (512). fp64 stats + transform, fp32 out.
// ---------------------------------------------------------------------------
__global__ __launch_bounds__(256) void ln_kernel(
    const float* __restrict__ X, float* __restrict__ Y,
    const float* __restrict__ g, const float* __restrict__ bta)
{
    int row = blockIdx.x;
    int tid = threadIdx.x;
    const float* x = X + (size_t)row * DM;
    double v0 = (double)x[tid], v1 = (double)x[tid + 256];
    double s = v0 + v1;
    double q = v0 * v0 + v1 * v1;
    #pragma unroll
    for (int off = 32; off; off >>= 1) {
        s += __shfl_down(s, off, 64);
        q += __shfl_down(q, off, 64);
    }
    __shared__ double ss[4], qq[4];
    int wid = tid >> 6, lane = tid & 63;
    if (lane == 0) { ss[wid] = s; qq[wid] = q; }
    __syncthreads();
    if (tid == 0) {
        double S = ss[0] + ss[1] + ss[2] + ss[3];
        double Q = qq[0] + qq[1] + qq[2] + qq[3];
        double mu = S * (1.0 / 512.0);
        double var = Q * (1.0 / 512.0) - mu * mu;
        ss[0] = mu;
        qq[0] = 1.0 / sqrt(var + 1e-5);
    }
    __syncthreads();
    double mu = ss[0], rs = qq[0];
    Y[(size_t)row * DM + tid] =
        (float)((v0 - mu) * rs * (double)g[tid] + (double)bta[tid]);
    Y[(size_t)row * DM + tid + 256] =
        (float)((v1 - mu) * rs * (double)g[tid + 256] + (double)bta[tid + 256]);
}

// ---------------------------------------------------------------------------
// Final projection + slice (fp64 acc, fp32 out).
// ---------------------------------------------------------------------------
__global__ __launch_bounds__(64) void proj_kernel(
    const float* __restrict__ Hf, const float* __restrict__ pw,
    const float* __restrict__ pb, float* __restrict__ out)
{
    int idx = blockIdx.x;               // 0..4095
    int b = idx >> 9, i = idx & 511;
    const float* row = Hf + ((size_t)(b * LTOT + SEQ + i)) * DM;
    int lane = threadIdx.x;
    double s = 0.0;
    #pragma unroll
    for (int k = 0; k < 8; ++k)
        s += (double)row[lane + 64 * k] * (double)pw[lane + 64 * k];
    #pragma unroll
    for (int off = 32; off; off >>= 1) s += __shfl_down(s, off, 64);
    if (lane == 0) out[idx] = (float)(s + (double)pb[0]);
}

// ---------------------------------------------------------------------------
extern "C" void kernel_launch(void* const* d_in, const int* in_sizes, int n_in,
                              void* d_out, int out_size, void* d_ws, size_t ws_size,
                              hipStream_t stream)
{
    const float* x_enc      = (const float*)d_in[0];
    const float* x_mark_enc = (const float*)d_in[1];
    const float* x_dec      = (const float*)d_in[2];
    const float* x_mark_dec = (const float*)d_in[3];
    const float* token_w    = (const float*)d_in[4];
    const float* temp_w     = (const float*)d_in[5];
    const float* qk_w       = (const float*)d_in[6];
    const float* v_w        = (const float*)d_in[7];
    const float* out_w      = (const float*)d_in[8];
    const float* out_b      = (const float*)d_in[9];
    const float* ln1_g      = (const float*)d_in[10];
    const float* ln1_b      = (const float*)d_in[11];
    const float* ff1_w      = (const float*)d_in[12];
    const float* ff1_b      = (const float*)d_in[13];
    const float* ff2_w      = (const float*)d_in[14];
    const float* ff2_b      = (const float*)d_in[15];
    const float* ln2_g      = (const float*)d_in[16];
    const float* ln2_b      = (const float*)d_in[17];
    const float* norm_g     = (const float*)d_in[18];
    const float* norm_b     = (const float*)d_in[19];
    const float* proj_w     = (const float*)d_in[20];
    const float* proj_b     = (const float*)d_in[21];
    const float* rotations  = (const float*)d_in[22];

    float* ws = (float*)d_ws;
    const size_t S = (size_t)BATCH * LTOT * DM;   // 8,388,608 floats
    float* Hb  = ws;
    float* QKb = ws + S;
    float* Vb  = ws + 2 * S;
    float* Cb  = ws + 3 * S;
    float* Yb  = QKb;                    // FFN intermediate: spans QKb+Vb (2S)
    int*   BKTb = (int*)(ws + 4 * S);              // 2 MB
    float* LSEb = ws + 4 * S + 524288;             // 2 MB
    int*   STSb = (int*)(ws + 4 * S + 2 * 524288); // 2 MB
    u16*   RShb = (u16*)(ws + 4 * S + 3 * 524288); // rot planes 128 KB x3
    u16*   RSmb = RShb + 4 * 256 * 64;
    u16*   RSlb = RSmb + 4 * 256 * 64;
    // weight planes: 2,883,584 u16 per plane x3 = 17.3 MB (after rot planes)
    const size_t WTOT = 2883584;
    u16*   WPh = (u16*)(ws + 4 * S + 3 * 524288 + 98304);
    u16*   WPm = WPh + WTOT;
    u16*   WPl = WPm + WTOT;
    const size_t WO_QK = 0, WO_V = 262144, WO_O = 524288,
                 WO_F1 = 786432, WO_F2 = 1835008;

    build_h_kernel<<<BATCH * LTOT, 512, 0, stream>>>(
        x_enc, x_mark_enc, x_dec, x_mark_dec, token_w, temp_w, Hb);

    const int M = BATCH * LTOT;  // 16384
    const int ATT_BLOCKS = NBH * NCH / 4;  // 32768 waves / 4 per block
    for (int l = 0; l < 2; ++l) {
        const float* qkw = qk_w + (size_t)l * DM * DM;
        const float* vw  = v_w  + (size_t)l * DM * DM;
        const float* ow  = out_w + (size_t)l * DM * DM;
        const float* ob  = out_b + (size_t)l * DM;
        const float* l1g = ln1_g + (size_t)l * DM;
        const float* l1b = ln1_b + (size_t)l * DM;
        const float* f1w = ff1_w + (size_t)l * DFF * DM;
        const float* f1b = ff1_b + (size_t)l * DFF;
        const float* f2w = ff2_w + (size_t)l * DM * DFF;
        const float* f2b = ff2_b + (size_t)l * DM;
        const float* l2g = ln2_g + (size_t)l * DM;
        const float* l2b = ln2_b + (size_t)l * DM;
        const float* rot = rotations + (size_t)l * DH * NHASH * 256;

        wsplit_kernel<<<2816, 256, 0, stream>>>(qkw, vw, ow, f1w, f2w, WPh, WPm, WPl);

        dim3 gQ(DM / 128, M / 128);  // (4, 128)
        gemm_mfma<3><<<gQ, 256, 0, stream>>>(Hb, WPh + WO_QK, WPm + WO_QK, WPl + WO_QK,
                                             nullptr, nullptr, QKb, M, DM, DM, 0);
        if (l == 0)
            gemm_mfma<3><<<gQ, 256, 0, stream>>>(Hb, WPh + WO_V, WPm + WO_V, WPl + WO_V,
                                                 nullptr, nullptr, Vb, M, DM, DM, 0);
        else
            gemm_mfma<2><<<gQ, 256, 0, stream>>>(Hb, WPh + WO_V, WPm + WO_V, WPl + WO_V,
                                                 nullptr, nullptr, Vb, M, DM, DM, 0);

        rot_split_kernel<<<4, 256, 0, stream>>>(rot, RShb, RSmb, RSlb);
        lsh_hash_mfma<<<NBH * NHASH * 16, 256, 0, stream>>>(QKb, RShb, RSmb, RSlb, BKTb);
        lsh_sort_kernel<<<NBH * NHASH, 256, 0, stream>>>(BKTb, STSb);

        hipMemsetAsync(Cb, 0, S * sizeof(float), stream);
        attn_lse_kernel<<<ATT_BLOCKS, 256, 0, stream>>>(QKb, STSb, LSEb);
        attn_out_kernel<<<ATT_BLOCKS, 256, 0, stream>>>(QKb, Vb, STSb, LSEb, Cb);

        // h = h + attn @ out_w^T + out_b   (in-place residual)
        if (l == 0)
            gemm_mfma<3><<<gQ, 256, 0, stream>>>(Cb, WPh + WO_O, WPm + WO_O, WPl + WO_O,
                                                 ob, Hb, Hb, M, DM, DM, 0);
        else
            gemm_mfma<2><<<gQ, 256, 0, stream>>>(Cb, WPh + WO_O, WPm + WO_O, WPl + WO_O,
                                                 ob, Hb, Hb, M, DM, DM, 0);
        ln_kernel<<<M, 256, 0, stream>>>(Hb, Hb, l1g, l1b);

        // FFN in 2 row-halves of 8192; Y spans QKb+Vb; ff2 in-place into Hb.
        for (int hb2 = 0; hb2 < 2; ++hb2) {
            float* hpart = Hb + (size_t)hb2 * 8192 * DM;
            dim3 gF1(DFF / 128, 8192 / 128);  // (16, 64) = 1024 blocks
            dim3 gF2(DM / 128, 8192 / 128);   // (4, 64)  = 256 blocks
            if (l == 0) {
                gemm_mfma<3><<<gF1, 256, 0, stream>>>(hpart, WPh + WO_F1, WPm + WO_F1, WPl + WO_F1,
                                                      f1b, nullptr, Yb, 8192, DFF, DM, 1);
                gemm_mfma<3><<<gF2, 256, 0, stream>>>(Yb, WPh + WO_F2, WPm + WO_F2, WPl + WO_F2,
                                                      f2b, hpart, hpart, 8192, DM, DFF, 0);
            } else {
                gemm_mfma<2><<<gF1, 256, 0, stream>>>(hpart, WPh + WO_F1, WPm + WO_F1, WPl + WO_F1,
                                                      f1b, nullptr, Yb, 8192, DFF, DM, 1);
                gemm_mfma<2><<<gF2, 256, 0, stream>>>(Yb, WPh + WO_F2, WPm + WO_F2, WPl + WO_F2,
                                                      f2b, hpart, hpart, 8192, DM, DFF, 0);
            }
        }
        ln_kernel<<<M, 256, 0, stream>>>(Hb, Hb, l2g, l2b);
    }

    ln_kernel<<<M, 256, 0, stream>>>(Hb, Cb, norm_g, norm_b);
    proj_kernel<<<4096, 64, 0, stream>>>(Cb, proj_w, proj_b, (float*)d_out);
}

// Round 11
// 3335.089 us; speedup vs baseline: 3.2902x; 1.0507x over previous
//
#include <hip/hip_runtime.h>
#include <math.h>

#define BATCH 8
#define LTOT 2048
#define DM 512
#define NHEADS 8
#define DH 64
#define NBH 64
#define NHASH 4
#define SEQ 1536
#define DECL 768
#define DFF 2048
#define NCH 2048   // total chunks (4 rounds * 512)

typedef unsigned short u16;
typedef unsigned int u32;
typedef unsigned long long u64;
typedef __attribute__((ext_vector_type(8))) short short8;   // 8 bf16 = 4 VGPR
typedef __attribute__((ext_vector_type(4))) float floatx4;  // MFMA C/D

static __device__ __forceinline__ double gelu_d(double x) {
    return 0.5 * x * (1.0 + erf(x * 0.70710678118654752440));
}

static __device__ __forceinline__ u16 f2bf(float x) {   // RNE float->bf16 bits
    u32 u = __float_as_uint(x);
    return (u16)((u + 0x7fffu + ((u >> 16) & 1u)) >> 16);
}
static __device__ __forceinline__ float bf2f(u16 h) {
    return __uint_as_float(((u32)h) << 16);
}
static __device__ __forceinline__ void split3(float x, u16& h, u16& m, u16& l) {
    h = f2bf(x);
    float r1 = x - bf2f(h);
    m = f2bf(r1);
    l = f2bf(r1 - bf2f(m));
}
static __device__ __forceinline__ u32 ordf(float x) {   // monotone float->u32
    u32 b = __float_as_uint(x);
    return (b & 0x80000000u) ? ~b : (b | 0x80000000u);
}
// pack top-16 bits of two fp32 (1 v_perm)
static __device__ __forceinline__ u32 pack_hi16(u32 a, u32 b) {
    return __builtin_amdgcn_perm(b, a, 0x07060302u);
}
// truncation split-3: h,m,l = successive top-16 truncations (exact subs).
static __device__ __forceinline__ void tsplit3_pack(
    float x0, float x1, u32& ph, u32& pm, u32& pl)
{
    u32 b0 = __float_as_uint(x0), b1 = __float_as_uint(x1);
    ph = pack_hi16(b0, b1);
    float r0 = x0 - __uint_as_float(b0 & 0xFFFF0000u);
    float r1 = x1 - __uint_as_float(b1 & 0xFFFF0000u);
    u32 c0 = __float_as_uint(r0), c1 = __float_as_uint(r1);
    pm = pack_hi16(c0, c1);
    float s0 = r0 - __uint_as_float(c0 & 0xFFFF0000u);
    float s1 = r1 - __uint_as_float(c1 & 0xFFFF0000u);
    pl = pack_hi16(__float_as_uint(s0), __float_as_uint(s1));
}
static __device__ __forceinline__ void tsplit2_pack(
    float x0, float x1, u32& ph, u32& pm)
{
    u32 b0 = __float_as_uint(x0), b1 = __float_as_uint(x1);
    ph = pack_hi16(b0, b1);
    float r0 = x0 - __uint_as_float(b0 & 0xFFFF0000u);
    float r1 = x1 - __uint_as_float(b1 & 0xFFFF0000u);
    pm = pack_hi16(__float_as_uint(r0), __float_as_uint(r1));
}

// ---------------------------------------------------------------------------
// h = TokenConv(x) + TimeLinear(xm) + PE   -> H [B, L, 512]
// ---------------------------------------------------------------------------
__global__ __launch_bounds__(512) void build_h_kernel(
    const float* __restrict__ x_enc, const float* __restrict__ x_mark_enc,
    const float* __restrict__ x_dec, const float* __restrict__ x_mark_dec,
    const float* __restrict__ token_w, const float* __restrict__ temp_w,
    float* __restrict__ H)
{
    int bl = blockIdx.x;
    int b = bl >> 11, l = bl & 2047;
    __shared__ float xr[3][7];
    __shared__ float xmr[4];
    int tid = threadIdx.x;
    if (tid < 21) {
        int k = tid / 7, c = tid % 7;
        int t = (l + k - 1 + LTOT) & 2047;
        float v;
        if (t < SEQ) v = x_enc[(b * SEQ + t) * 7 + c];
        else         v = x_dec[(b * DECL + (t - 1280)) * 7 + c];
        xr[k][c] = v;
    } else if (tid < 25) {
        int m = tid - 21;
        float v;
        if (l < SEQ) v = x_mark_enc[(b * SEQ + l) * 4 + m];
        else         v = x_mark_dec[(b * DECL + (l - 1280)) * 4 + m];
        xmr[m] = v;
    }
    __syncthreads();
    int d = tid;  // 0..511
    double val = 0.0;
    #pragma unroll
    for (int k = 0; k < 3; ++k)
        #pragma unroll
        for (int c = 0; c < 7; ++c)
            val += (double)xr[k][c] * (double)token_w[(d * 7 + c) * 3 + k];
    double tmp = 0.0;
    #pragma unroll
    for (int m = 0; m < 4; ++m) tmp += (double)xmr[m] * (double)temp_w[d * 4 + m];
    const float cf = (float)(-9.210340371976184 / 512.0);
    float ef  = (float)(2 * (d >> 1)) * cf;
    float dvf = (float)exp((double)ef);
    float angf = (float)l * dvf;
    double pe = (d & 1) ? cos((double)angf) : sin((double)angf);
    H[((size_t)b * LTOT + l) * DM + d] = (float)(val + tmp + pe);
}

// ---------------------------------------------------------------------------
// Pre-split the layer's 5 weight matrices into trunc-bf16 h/m/l planes,
// TILED layout: per matrix, [nt][kt][128][32] (exact GEMM LDS image).
// ---------------------------------------------------------------------------
__global__ __launch_bounds__(256) void wsplit_kernel(
    const float* __restrict__ qkw, const float* __restrict__ vw,
    const float* __restrict__ ow, const float* __restrict__ f1w,
    const float* __restrict__ f2w,
    u16* __restrict__ Ph, u16* __restrict__ Pm, u16* __restrict__ Pl)
{
    size_t i = ((size_t)blockIdx.x * 256 + threadIdx.x) * 4;
    const float* src; size_t off, base; int kshift;
    if (i < 262144)       { src = qkw; off = i;           base = 0;       kshift = 9; }
    else if (i < 524288)  { src = vw;  off = i - 262144;  base = 262144;  kshift = 9; }
    else if (i < 786432)  { src = ow;  off = i - 524288;  base = 524288;  kshift = 9; }
    else if (i < 1835008) { src = f1w; off = i - 786432;  base = 786432;  kshift = 9; }
    else                  { src = f2w; off = i - 1835008; base = 1835008; kshift = 11; }
    int K = 1 << kshift;
    int n  = (int)(off >> kshift);
    int kg = (int)(off & (size_t)(K - 1));
    int nt = n >> 7, r = n & 127, kt = kg >> 5, kk = kg & 31;
    size_t o = base + ((((size_t)nt * (K >> 5) + kt) << 12) | ((size_t)r << 5) | kk);
    float4 x = *(const float4*)(src + off);
    u32 h01, m01, l01, h23, m23, l23;
    tsplit3_pack(x.x, x.y, h01, m01, l01);
    tsplit3_pack(x.z, x.w, h23, m23, l23);
    *(uint2*)(Ph + o) = make_uint2(h01, h23);
    *(uint2*)(Pm + o) = make_uint2(m01, m23);
    *(uint2*)(Pl + o) = make_uint2(l01, l23);
}

// ---------------------------------------------------------------------------
// MFMA split-bf16 GEMM: C[M,N] = act( A[M,K] @ W[N,K]^T + bias + res )
// W from tiled u16 planes (fully coalesced staging); A split in-kernel.
// ---------------------------------------------------------------------------
template<int NSPLIT>
__global__ __launch_bounds__(256) void gemm_mfma(
    const float* __restrict__ A,
    const u16* __restrict__ WTh, const u16* __restrict__ WTm,
    const u16* __restrict__ WTl,
    const float* __restrict__ bias, const float* __restrict__ res,
    float* __restrict__ C, int M, int N, int K, int act)
{
    __shared__ u16 Ah[128][32], Am[128][32], Al[128][32];
    __shared__ u16 Wh[128][32], Wm[128][32], Wl[128][32];
    const int tid = threadIdx.x;
    const int n0 = blockIdx.x * 128, m0 = blockIdx.y * 128;
    const int row = tid >> 1;           // 0..127
    const int koff = (tid & 1) * 16;    // 0 or 16
    const float* Ag = A + (size_t)(m0 + row) * K + koff;

    const int wv = tid >> 6, lane = tid & 63;
    const int m0w = (wv >> 1) * 64, n0w = (wv & 1) * 64;
    const int fr = lane & 15, quad = lane >> 4;
    u16* WhF = &Wh[0][0]; u16* WmF = &Wm[0][0]; u16* WlF = &Wl[0][0];

    floatx4 acc[4][4];
    #pragma unroll
    for (int i = 0; i < 4; ++i)
        #pragma unroll
        for (int j = 0; j < 4; ++j) acc[i][j] = (floatx4)0.0f;

    for (int kt = 0; kt < K; kt += 32) {
        const size_t tb = ((size_t)blockIdx.x * (K >> 5) + (kt >> 5)) * 4096;
        // W planes: tiled -> fully coalesced 16B/lane loads.
        uint4 wh0 = *(const uint4*)(WTh + tb + tid * 8);
        uint4 wh1 = *(const uint4*)(WTh + tb + 2048 + tid * 8);
        uint4 wm0 = *(const uint4*)(WTm + tb + tid * 8);
        uint4 wm1 = *(const uint4*)(WTm + tb + 2048 + tid * 8);
        uint4 wl0, wl1;
        if (NSPLIT == 3) {
            wl0 = *(const uint4*)(WTl + tb + tid * 8);
            wl1 = *(const uint4*)(WTl + tb + 2048 + tid * 8);
        }
        // A: load fp32, trunc-split.
        u32 pah[8], pam[8], pal[8];
        #pragma unroll
        for (int g = 0; g < 4; ++g) {
            float4 a4 = *(const float4*)(Ag + kt + g * 4);
            if (NSPLIT == 3) {
                tsplit3_pack(a4.x, a4.y, pah[g*2], pam[g*2], pal[g*2]);
                tsplit3_pack(a4.z, a4.w, pah[g*2+1], pam[g*2+1], pal[g*2+1]);
            } else {
                tsplit2_pack(a4.x, a4.y, pah[g*2], pam[g*2]);
                tsplit2_pack(a4.z, a4.w, pah[g*2+1], pam[g*2+1]);
            }
        }
        __syncthreads();
        ((uint4*)&Ah[row][koff])[0] = make_uint4(pah[0], pah[1], pah[2], pah[3]);
        ((uint4*)&Ah[row][koff])[1] = make_uint4(pah[4], pah[5], pah[6], pah[7]);
        ((uint4*)&Am[row][koff])[0] = make_uint4(pam[0], pam[1], pam[2], pam[3]);
        ((uint4*)&Am[row][koff])[1] = make_uint4(pam[4], pam[5], pam[6], pam[7]);
        *(uint4*)(WhF + tid * 8) = wh0;
        *(uint4*)(WhF + 2048 + tid * 8) = wh1;
        *(uint4*)(WmF + tid * 8) = wm0;
        *(uint4*)(WmF + 2048 + tid * 8) = wm1;
        if (NSPLIT == 3) {
            ((uint4*)&Al[row][koff])[0] = make_uint4(pal[0], pal[1], pal[2], pal[3]);
            ((uint4*)&Al[row][koff])[1] = make_uint4(pal[4], pal[5], pal[6], pal[7]);
            *(uint4*)(WlF + tid * 8) = wl0;
            *(uint4*)(WlF + 2048 + tid * 8) = wl1;
        }
        __syncthreads();
        short8 ah4[4], am4[4], al4[4];
        #pragma unroll
        for (int rt = 0; rt < 4; ++rt) {
            int r = m0w + rt * 16 + fr;
            ah4[rt] = *(const short8*)&Ah[r][quad * 8];
            am4[rt] = *(const short8*)&Am[r][quad * 8];
            if (NSPLIT == 3) al4[rt] = *(const short8*)&Al[r][quad * 8];
        }
        #pragma unroll
        for (int ct = 0; ct < 4; ++ct) {
            int nrw = n0w + ct * 16 + fr;
            short8 bh4 = *(const short8*)&Wh[nrw][quad * 8];
            short8 bm4 = *(const short8*)&Wm[nrw][quad * 8];
            short8 bl4;
            if (NSPLIT == 3) bl4 = *(const short8*)&Wl[nrw][quad * 8];
            #pragma unroll
            for (int rt = 0; rt < 4; ++rt) {
                floatx4 c = acc[rt][ct];
                c = __builtin_amdgcn_mfma_f32_16x16x32_bf16(ah4[rt], bh4, c, 0, 0, 0);
                c = __builtin_amdgcn_mfma_f32_16x16x32_bf16(ah4[rt], bm4, c, 0, 0, 0);
                c = __builtin_amdgcn_mfma_f32_16x16x32_bf16(am4[rt], bh4, c, 0, 0, 0);
                if (NSPLIT == 3) {
                    c = __builtin_amdgcn_mfma_f32_16x16x32_bf16(ah4[rt], bl4, c, 0, 0, 0);
                    c = __builtin_amdgcn_mfma_f32_16x16x32_bf16(am4[rt], bm4, c, 0, 0, 0);
                    c = __builtin_amdgcn_mfma_f32_16x16x32_bf16(al4[rt], bh4, c, 0, 0, 0);
                }
                acc[rt][ct] = c;
            }
        }
    }
    // Epilogue: C/D layout col=lane&15, row=quad*4+reg (m89-verified).
    #pragma unroll
    for (int rt = 0; rt < 4; ++rt) {
        #pragma unroll
        for (int ct = 0; ct < 4; ++ct) {
            int n = n0 + n0w + ct * 16 + fr;
            #pragma unroll
            for (int reg = 0; reg < 4; ++reg) {
                int m = m0 + m0w + rt * 16 + quad * 4 + reg;
                double v = (double)acc[rt][ct][reg];
                if (bias) v += (double)bias[n];
                if (res)  v += (double)res[(size_t)m * N + n];
                if (act == 1) v = gelu_d(v);
                C[(size_t)m * N + n] = (float)v;
            }
        }
    }
}

// ---------------------------------------------------------------------------
// Precompute split-3 bf16 planes of rot, transposed to [h][r][d].
// ---------------------------------------------------------------------------
__global__ __launch_bounds__(256) void rot_split_kernel(
    const float* __restrict__ rot, u16* __restrict__ RSh,
    u16* __restrict__ RSm, u16* __restrict__ RSl)
{
    int h = blockIdx.x;      // 0..3
    int r = threadIdx.x;     // 0..255
    #pragma unroll 4
    for (int d = 0; d < 64; ++d) {
        float v = rot[(d * 4 + h) * 256 + r];
        u16 hh, mm, ll;
        split3(v, hh, mm, ll);
        size_t o = ((size_t)h * 256 + r) * 64 + d;
        RSh[o] = hh; RSm[o] = mm; RSl[o] = ll;
    }
}

// ---------------------------------------------------------------------------
// LSH hash via split-3 bf16 MFMA + fused argmax (r9-verified).
// ---------------------------------------------------------------------------
__global__ __launch_bounds__(256) void lsh_hash_mfma(
    const float* __restrict__ QK, const u16* __restrict__ RSh,
    const u16* __restrict__ RSm, const u16* __restrict__ RSl,
    int* __restrict__ BKT)
{
    __shared__ u16 Ah[128][72], Am[128][72], Al[128][72];  // padded rows
    __shared__ u64 best[128];
    int bid = blockIdx.x;
    int tt = bid & 15;
    int h  = (bid >> 4) & 3;
    int bh = bid >> 6;
    int tid = threadIdx.x;
    int b = bh >> 3, hd = bh & 7;
    const int t0 = tt * 128;

    if (tid < 128) best[tid] = 0ull;

    {
        int row = tid >> 1;
        int kbase = (tid & 1) * 32;
        const float* src = QK + ((size_t)(b * LTOT + t0 + row)) * DM + hd * DH + kbase;
        u32 ph[16], pm[16], pl[16];
        #pragma unroll
        for (int g = 0; g < 8; ++g) {
            float4 a4 = *(const float4*)(src + g * 4);
            u16 h0, m0_, l0, h1, m1_, l1;
            split3(a4.x, h0, m0_, l0); split3(a4.y, h1, m1_, l1);
            ph[g*2]   = (u32)h0 | ((u32)h1 << 16);
            pm[g*2]   = (u32)m0_ | ((u32)m1_ << 16);
            pl[g*2]   = (u32)l0 | ((u32)l1 << 16);
            split3(a4.z, h0, m0_, l0); split3(a4.w, h1, m1_, l1);
            ph[g*2+1] = (u32)h0 | ((u32)h1 << 16);
            pm[g*2+1] = (u32)m0_ | ((u32)m1_ << 16);
            pl[g*2+1] = (u32)l0 | ((u32)l1 << 16);
        }
        #pragma unroll
        for (int g = 0; g < 4; ++g) {
            ((uint4*)&Ah[row][kbase])[g] = make_uint4(ph[g*4], ph[g*4+1], ph[g*4+2], ph[g*4+3]);
            ((uint4*)&Am[row][kbase])[g] = make_uint4(pm[g*4], pm[g*4+1], pm[g*4+2], pm[g*4+3]);
            ((uint4*)&Al[row][kbase])[g] = make_uint4(pl[g*4], pl[g*4+1], pl[g*4+2], pl[g*4+3]);
        }
    }
    __syncthreads();

    const int wv = tid >> 6, lane = tid & 63;
    const int fr = lane & 15, quad = lane >> 4;
    const int nbase = wv * 64;

    floatx4 acc[8][4];
    #pragma unroll
    for (int i = 0; i < 8; ++i)
        #pragma unroll
        for (int j = 0; j < 4; ++j) acc[i][j] = (floatx4)0.0f;

    #pragma unroll
    for (int kt = 0; kt < 2; ++kt) {
        #pragma unroll
        for (int ct = 0; ct < 4; ++ct) {
            size_t bo = ((size_t)h * 256 + nbase + ct * 16 + fr) * 64 + kt * 32 + quad * 8;
            short8 bh4 = *(const short8*)(RSh + bo);
            short8 bm4 = *(const short8*)(RSm + bo);
            short8 bl4 = *(const short8*)(RSl + bo);
            #pragma unroll
            for (int rt = 0; rt < 8; ++rt) {
                const int ar = rt * 16 + fr, ak = kt * 32 + quad * 8;
                short8 ah4 = *(const short8*)&Ah[ar][ak];
                short8 am4 = *(const short8*)&Am[ar][ak];
                short8 al4 = *(const short8*)&Al[ar][ak];
                floatx4 c = acc[rt][ct];
                c = __builtin_amdgcn_mfma_f32_16x16x32_bf16(ah4, bh4, c, 0, 0, 0);
                c = __builtin_amdgcn_mfma_f32_16x16x32_bf16(ah4, bm4, c, 0, 0, 0);
                c = __builtin_amdgcn_mfma_f32_16x16x32_bf16(am4, bh4, c, 0, 0, 0);
                c = __builtin_amdgcn_mfma_f32_16x16x32_bf16(ah4, bl4, c, 0, 0, 0);
                c = __builtin_amdgcn_mfma_f32_16x16x32_bf16(am4, bm4, c, 0, 0, 0);
                c = __builtin_amdgcn_mfma_f32_16x16x32_bf16(al4, bh4, c, 0, 0, 0);
                acc[rt][ct] = c;
            }
        }
    }

    #pragma unroll
    for (int rt = 0; rt < 8; ++rt) {
        #pragma unroll
        for (int reg = 0; reg < 4; ++reg) {
            u64 key = 0ull;
            #pragma unroll
            for (int ct = 0; ct < 4; ++ct) {
                float v = acc[rt][ct][reg];
                u32 idxp = nbase + ct * 16 + fr;        // + candidate
                u32 idxn = idxp + 256;                   // - candidate
                u64 kp = ((u64)ordf(v) << 32) | (u32)(0xFFFFFFFFu - idxp);
                u64 kn = ((u64)ordf(-v) << 32) | (u32)(0xFFFFFFFFu - idxn);
                if (kp > key) key = kp;
                if (kn > key) key = kn;
            }
            #pragma unroll
            for (int m = 1; m <= 8; m <<= 1) {
                u64 o = __shfl_xor((unsigned long long)key, m, 64);
                if (o > key) key = o;
            }
            if (fr == 0) {
                int tok = rt * 16 + quad * 4 + reg;
                atomicMax(&best[tok], key);
            }
        }
    }
    __syncthreads();
    if (tid < 128) {
        u32 idx = 0xFFFFFFFFu - (u32)best[tid];
        BKT[((size_t)bh * NHASH + h) * LTOT + t0 + tid] = (int)idx;
    }
}

// ---------------------------------------------------------------------------
// Stable counting sort per (bh, hash): sorted-by-(bucket, t).
// ---------------------------------------------------------------------------
__global__ __launch_bounds__(256) void lsh_sort_kernel(
    const int* __restrict__ BKT, int* __restrict__ STS)
{
    __shared__ unsigned short bkt[2048];
    __shared__ unsigned int hist2[16][512];
    __shared__ unsigned int bstart[512];
    int bid = blockIdx.x;
    int h = bid & 3, bh = bid >> 2;
    int tid = threadIdx.x;
    const int* src = BKT + ((size_t)bh * NHASH + h) * LTOT;
    for (int t = tid; t < 2048; t += 256) bkt[t] = (unsigned short)src[t];
    for (int i = tid; i < 16 * 512; i += 256) (&hist2[0][0])[i] = 0u;
    __syncthreads();
    for (int t = tid; t < 2048; t += 256)
        atomicAdd(&hist2[t >> 7][bkt[t]], 1u);
    __syncthreads();
    for (int bb = tid; bb < 512; bb += 256) {
        unsigned int run = 0;
        #pragma unroll
        for (int g = 0; g < 16; ++g) {
            unsigned int c = hist2[g][bb];
            hist2[g][bb] = run;
            run += c;
        }
        bstart[bb] = run;
    }
    __syncthreads();
    if (tid == 0) {
        unsigned int run = 0;
        for (int bb = 0; bb < 512; ++bb) {
            unsigned int c = bstart[bb];
            bstart[bb] = run;
            run += c;
        }
    }
    __syncthreads();
    int* dst = STS + (size_t)bh * (NHASH * LTOT) + h * LTOT;
    for (int t = tid; t < 2048; t += 256) {
        int bb = bkt[t];
        unsigned int rank = hist2[t >> 7][bb];
        int g0 = t & ~127;
        for (int u = g0; u < t; ++u) rank += (bkt[u] == (unsigned short)bb);
        dst[bstart[bb] + rank] = t;
    }
}

// ---------------------------------------------------------------------------
// Attention pass A (fp32): dots + LSE + cached normalized probs PRB.
// ---------------------------------------------------------------------------
__global__ __launch_bounds__(256) void attn_lse_kernel(
    const float* __restrict__ QK, const int* __restrict__ STS,
    float* __restrict__ LSE, float* __restrict__ PRB)
{
    int wid = (blockIdx.x * 256 + threadIdx.x) >> 6;   // global wave id
    int lane = threadIdx.x & 63;
    int bh = wid >> 11;          // 0..63
    int c  = wid & 2047;
    int cp = (c + NCH - 1) & (NCH - 1);
    const int* sts = STS + (size_t)bh * 8192;
    int tok[8];
    #pragma unroll
    for (int j = 0; j < 4; ++j) tok[j] = sts[4 * c + j];
    #pragma unroll
    for (int j = 0; j < 4; ++j) tok[4 + j] = sts[4 * cp + j];
    int b = bh >> 3, hd = bh & 7;
    const float* base = QK + ((size_t)b * LTOT) * DM + hd * DH + lane;
    float kd[8];
    #pragma unroll
    for (int j = 0; j < 8; ++j) kd[j] = base[(size_t)tok[j] * DM];
    float rnrm[8];
    #pragma unroll
    for (int j = 0; j < 8; ++j) {
        float v = kd[j] * kd[j];
        #pragma unroll
        for (int m = 32; m; m >>= 1) v += __shfl_xor(v, m, 64);
        rnrm[j] = 0.125f / fmaxf(sqrtf(v), 1e-12f);
    }
    int hr = c >> 9;
    size_t cbase = ((size_t)bh * NCH + c) * 32;
    float pkeep = 0.f;
    #pragma unroll
    for (int i = 0; i < 4; ++i) {
        float dots[8];
        float myd = -5e4f;
        #pragma unroll
        for (int j = 0; j < 8; ++j) {
            float v = kd[i] * kd[j];
            #pragma unroll
            for (int m = 32; m; m >>= 1) v += __shfl_xor(v, m, 64);
            dots[j] = (tok[j] == tok[i]) ? -5e4f : v * rnrm[j];
            if ((lane & 7) == j) myd = dots[j];
        }
        float mx = dots[0];
        #pragma unroll
        for (int j = 1; j < 8; ++j) mx = fmaxf(mx, dots[j]);
        float s = 0.f;
        #pragma unroll
        for (int j = 0; j < 8; ++j) s += expf(dots[j] - mx);
        float pn = expf(myd - mx) / s;
        if ((lane >> 3) == i) pkeep = pn;
        if (lane == 0)
            LSE[((size_t)bh * NHASH + hr) * LTOT + tok[i]] = mx + logf(s);
    }
    if (lane < 32) PRB[cbase + lane] = pkeep;
}

// ---------------------------------------------------------------------------
// Cross-round softmax weights per token: W4[bh][hr][t] from LSE.
// ---------------------------------------------------------------------------
__global__ __launch_bounds__(256) void wsoft_kernel(
    const float* __restrict__ LSE, float* __restrict__ W4)
{
    int idx = blockIdx.x * 256 + threadIdx.x;   // 131072
    int bh = idx >> 11, t = idx & 2047;
    float L[4];
    #pragma unroll
    for (int hh = 0; hh < 4; ++hh)
        L[hh] = LSE[((size_t)bh * NHASH + hh) * LTOT + t];
    float wm = fmaxf(fmaxf(L[0], L[1]), fmaxf(L[2], L[3]));
    float ws = 0.f;
    #pragma unroll
    for (int hh = 0; hh < 4; ++hh) ws += expf(L[hh] - wm);
    float inv = 1.f / ws;
    #pragma unroll
    for (int hh = 0; hh < 4; ++hh)
        W4[((size_t)bh * NHASH + hh) * LTOT + t] = expf(L[hh] - wm) * inv;
}

// ---------------------------------------------------------------------------
// Attention pass B: cached probs + weights -> weighted V accumulate.
// ---------------------------------------------------------------------------
__global__ __launch_bounds__(256) void attn_out_kernel(
    const float* __restrict__ V, const int* __restrict__ STS,
    const float* __restrict__ PRB, const float* __restrict__ W4,
    float* __restrict__ C)
{
    int wid = (blockIdx.x * 256 + threadIdx.x) >> 6;
    int lane = threadIdx.x & 63;
    int bh = wid >> 11;
    int c  = wid & 2047;
    int cp = (c + NCH - 1) & (NCH - 1);
    const int* sts = STS + (size_t)bh * 8192;
    int tok[8];
    #pragma unroll
    for (int j = 0; j < 4; ++j) tok[j] = sts[4 * c + j];
    #pragma unroll
    for (int j = 0; j < 4; ++j) tok[4 + j] = sts[4 * cp + j];
    int b = bh >> 3, hd = bh & 7;
    const float* vbase = V + ((size_t)b * LTOT) * DM + hd * DH + lane;
    float vd[8];
    #pragma unroll
    for (int j = 0; j < 8; ++j) vd[j] = vbase[(size_t)tok[j] * DM];
    size_t cbase = ((size_t)bh * NCH + c) * 32;
    float pv = PRB[cbase + (lane & 31)];
    int hr = c >> 9;
    const float* w4b = W4 + ((size_t)bh * NHASH + hr) * LTOT;
    float* crow0 = C + ((size_t)b * LTOT) * DM + hd * DH + lane;
    #pragma unroll
    for (int i = 0; i < 4; ++i) {
        float w = w4b[tok[i]];
        float acc = 0.f;
        #pragma unroll
        for (int j = 0; j < 8; ++j)
            acc += __shfl(pv, i * 8 + j, 64) * vd[j];
        atomicAdd(crow0 + (size_t)tok[i] * DM, acc * w);
    }
}

// ---------------------------------------------------------------------------
// LayerNorm over last dim (512). fp64 stats + transform, fp32 out.
// ---------------------------------------------------------------------------
__global__ __launch_bounds__(256) void ln_kernel(
    const float* __restrict__ X, float* __restrict__ Y,
    const float* __restrict__ g, const float* __restrict__ bta)
{
    int row = blockIdx.x;
    int tid = threadIdx.x;
    const float* x = X + (size_t)row * DM;
    double v0 = (double)x[tid], v1 = (double)x[tid + 256];
    double s = v0 + v1;
    double q = v0 * v0 + v1 * v1;
    #pragma unroll
    for (int off = 32; off; off >>= 1) {
        s += __shfl_down(s, off, 64);
        q += __shfl_down(q, off, 64);
    }
    __shared__ double ss[4], qq[4];
    int wid = tid >> 6, lane = tid & 63;
    if (lane == 0) { ss[wid] = s; qq[wid] = q; }
    __syncthreads();
    if (tid == 0) {
        double S = ss[0] + ss[1] + ss[2] + ss[3];
        double Q = qq[0] + qq[1] + qq[2] + qq[3];
        double mu = S * (1.0 / 512.0);
        double var = Q * (1.0 / 512.0) - mu * mu;
        ss[0] = mu;
        qq[0] = 1.0 / sqrt(var + 1e-5);
    }
    __syncthreads();
    double mu = ss[0], rs = qq[0];
    Y[(size_t)row * DM + tid] =
        (float)((v0 - mu) * rs * (double)g[tid] + (double)bta[tid]);
    Y[(size_t)row * DM + tid + 256] =
        (float)((v1 - mu) * rs * (double)g[tid + 256] + (double)bta[tid + 256]);
}

// ---------------------------------------------------------------------------
// Final projection + slice (fp64 acc, fp32 out).
// ---------------------------------------------------------------------------
__global__ __launch_bounds__(64) void proj_kernel(
    const float* __restrict__ Hf, const float* __restrict__ pw,
    const float* __restrict__ pb, float* __restrict__ out)
{
    int idx = blockIdx.x;               // 0..4095
    int b = idx >> 9, i = idx & 511;
    const float* row = Hf + ((size_t)(b * LTOT + SEQ + i)) * DM;
    int lane = threadIdx.x;
    double s = 0.0;
    #pragma unroll
    for (int k = 0; k < 8; ++k)
        s += (double)row[lane + 64 * k] * (double)pw[lane + 64 * k];
    #pragma unroll
    for (int off = 32; off; off >>= 1) s += __shfl_down(s, off, 64);
    if (lane == 0) out[idx] = (float)(s + (double)pb[0]);
}

// ---------------------------------------------------------------------------
extern "C" void kernel_launch(void* const* d_in, const int* in_sizes, int n_in,
                              void* d_out, int out_size, void* d_ws, size_t ws_size,
                              hipStream_t stream)
{
    const float* x_enc      = (const float*)d_in[0];
    const float* x_mark_enc = (const float*)d_in[1];
    const float* x_dec      = (const float*)d_in[2];
    const float* x_mark_dec = (const float*)d_in[3];
    const float* token_w    = (const float*)d_in[4];
    const float* temp_w     = (const float*)d_in[5];
    const float* qk_w       = (const float*)d_in[6];
    const float* v_w        = (const float*)d_in[7];
    const float* out_w      = (const float*)d_in[8];
    const float* out_b      = (const float*)d_in[9];
    const float* ln1_g      = (const float*)d_in[10];
    const float* ln1_b      = (const float*)d_in[11];
    const float* ff1_w      = (const float*)d_in[12];
    const float* ff1_b      = (const float*)d_in[13];
    const float* ff2_w      = (const float*)d_in[14];
    const float* ff2_b      = (const float*)d_in[15];
    const float* ln2_g      = (const float*)d_in[16];
    const float* ln2_b      = (const float*)d_in[17];
    const float* norm_g     = (const float*)d_in[18];
    const float* norm_b     = (const float*)d_in[19];
    const float* proj_w     = (const float*)d_in[20];
    const float* proj_b     = (const float*)d_in[21];
    const float* rotations  = (const float*)d_in[22];

    float* ws = (float*)d_ws;
    const size_t S = (size_t)BATCH * LTOT * DM;   // 8,388,608 floats
    float* Hb  = ws;
    float* QKb = ws + S;
    float* Vb  = ws + 2 * S;
    float* Cb  = ws + 3 * S;
    float* Yb  = QKb;                    // FFN intermediate: spans QKb+Vb (2S)
    int*   BKTb = (int*)(ws + 4 * S);              // 2 MB
    float* LSEb = ws + 4 * S + 524288;             // 2 MB
    int*   STSb = (int*)(ws + 4 * S + 2 * 524288); // 2 MB
    u16*   RShb = (u16*)(ws + 4 * S + 3 * 524288); // rot planes 128 KB x3
    u16*   RSmb = RShb + 4 * 256 * 64;
    u16*   RSlb = RSmb + 4 * 256 * 64;
    const size_t WTOT = 2883584;                   // u16 per weight plane
    u16*   WPh = (u16*)(ws + 4 * S + 3 * 524288 + 98304);
    u16*   WPm = WPh + WTOT;
    u16*   WPl = WPm + WTOT;
    float* PRBb = ws + 4 * S + 3 * 524288 + 98304 + (3 * WTOT) / 2;  // 16.8 MB
    float* W4b  = PRBb + (size_t)NBH * NCH * 32;                     // 2 MB
    const size_t WO_QK = 0, WO_V = 262144, WO_O = 524288,
                 WO_F1 = 786432, WO_F2 = 1835008;

    build_h_kernel<<<BATCH * LTOT, 512, 0, stream>>>(
        x_enc, x_mark_enc, x_dec, x_mark_dec, token_w, temp_w, Hb);

    const int M = BATCH * LTOT;  // 16384
    const int ATT_BLOCKS = NBH * NCH / 4;  // 32768 waves / 4 per block
    for (int l = 0; l < 2; ++l) {
        const float* qkw = qk_w + (size_t)l * DM * DM;
        const float* vw  = v_w  + (size_t)l * DM * DM;
        const float* ow  = out_w + (size_t)l * DM * DM;
        const float* ob  = out_b + (size_t)l * DM;
        const float* l1g = ln1_g + (size_t)l * DM;
        const float* l1b = ln1_b + (size_t)l * DM;
        const float* f1w = ff1_w + (size_t)l * DFF * DM;
        const float* f1b = ff1_b + (size_t)l * DFF;
        const float* f2w = ff2_w + (size_t)l * DM * DFF;
        const float* f2b = ff2_b + (size_t)l * DM;
        const float* l2g = ln2_g + (size_t)l * DM;
        const float* l2b = ln2_b + (size_t)l * DM;
        const float* rot = rotations + (size_t)l * DH * NHASH * 256;

        wsplit_kernel<<<2816, 256, 0, stream>>>(qkw, vw, ow, f1w, f2w, WPh, WPm, WPl);

        dim3 gQ(DM / 128, M / 128);  // (4, 128)
        gemm_mfma<3><<<gQ, 256, 0, stream>>>(Hb, WPh + WO_QK, WPm + WO_QK, WPl + WO_QK,
                                             nullptr, nullptr, QKb, M, DM, DM, 0);
        if (l == 0)
            gemm_mfma<3><<<gQ, 256, 0, stream>>>(Hb, WPh + WO_V, WPm + WO_V, WPl + WO_V,
                                                 nullptr, nullptr, Vb, M, DM, DM, 0);
        else
            gemm_mfma<2><<<gQ, 256, 0, stream>>>(Hb, WPh + WO_V, WPm + WO_V, WPl + WO_V,
                                                 nullptr, nullptr, Vb, M, DM, DM, 0);

        rot_split_kernel<<<4, 256, 0, stream>>>(rot, RShb, RSmb, RSlb);
        lsh_hash_mfma<<<NBH * NHASH * 16, 256, 0, stream>>>(QKb, RShb, RSmb, RSlb, BKTb);
        lsh_sort_kernel<<<NBH * NHASH, 256, 0, stream>>>(BKTb, STSb);

        hipMemsetAsync(Cb, 0, S * sizeof(float), stream);
        attn_lse_kernel<<<ATT_BLOCKS, 256, 0, stream>>>(QKb, STSb, LSEb, PRBb);
        wsoft_kernel<<<512, 256, 0, stream>>>(LSEb, W4b);
        attn_out_kernel<<<ATT_BLOCKS, 256, 0, stream>>>(Vb, STSb, PRBb, W4b, Cb);

        // h = h + attn @ out_w^T + out_b   (in-place residual)
        if (l == 0)
            gemm_mfma<3><<<gQ, 256, 0, stream>>>(Cb, WPh + WO_O, WPm + WO_O, WPl + WO_O,
                                                 ob, Hb, Hb, M, DM, DM, 0);
        else
            gemm_mfma<2><<<gQ, 256, 0, stream>>>(Cb, WPh + WO_O, WPm + WO_O, WPl + WO_O,
                                                 ob, Hb, Hb, M, DM, DM, 0);
        ln_kernel<<<M, 256, 0, stream>>>(Hb, Hb, l1g, l1b);

        // FFN in 2 row-halves of 8192; Y spans QKb+Vb; ff2 in-place into Hb.
        for (int hb2 = 0; hb2 < 2; ++hb2) {
            float* hpart = Hb + (size_t)hb2 * 8192 * DM;
            dim3 gF1(DFF / 128, 8192 / 128);  // (16, 64) = 1024 blocks
            dim3 gF2(DM / 128, 8192 / 128);   // (4, 64)  = 256 blocks
            if (l == 0) {
                gemm_mfma<3><<<gF1, 256, 0, stream>>>(hpart, WPh + WO_F1, WPm + WO_F1, WPl + WO_F1,
                                                      f1b, nullptr, Yb, 8192, DFF, DM, 1);
                gemm_mfma<3><<<gF2, 256, 0, stream>>>(Yb, WPh + WO_F2, WPm + WO_F2, WPl + WO_F2,
                                                      f2b, hpart, hpart, 8192, DM, DFF, 0);
            } else {
                gemm_mfma<2><<<gF1, 256, 0, stream>>>(hpart, WPh + WO_F1, WPm + WO_F1, WPl + WO_F1,
                                                      f1b, nullptr, Yb, 8192, DFF, DM, 1);
                gemm_mfma<2><<<gF2, 256, 0, stream>>>(Yb, WPh + WO_F2, WPm + WO_F2, WPl + WO_F2,
                                                      f2b, hpart, hpart, 8192, DM, DFF, 0);
            }
        }
        ln_kernel<<<M, 256, 0, stream>>>(Hb, Hb, l2g, l2b);
    }

    ln_kernel<<<M, 256, 0, stream>>>(Hb, Cb, norm_g, norm_b);
    proj_kernel<<<4096, 64, 0, stream>>>(Cb, proj_w, proj_b, (float*)d_out);
}

// Round 12
// 2739.767 us; speedup vs baseline: 4.0051x; 1.2173x over previous
//
#include <hip/hip_runtime.h>
#include <math.h>

#define BATCH 8
#define LTOT 2048
#define DM 512
#define NHEADS 8
#define DH 64
#define NBH 64
#define NHASH 4
#define SEQ 1536
#define DECL 768
#define DFF 2048
#define NCH 2048   // total chunks (4 rounds * 512)

typedef unsigned short u16;
typedef unsigned int u32;
typedef unsigned long long u64;
typedef __attribute__((ext_vector_type(8))) short short8;   // 8 bf16 = 4 VGPR
typedef __attribute__((ext_vector_type(4))) float floatx4;  // MFMA C/D

static __device__ __forceinline__ double gelu_d(double x) {
    return 0.5 * x * (1.0 + erf(x * 0.70710678118654752440));
}

static __device__ __forceinline__ u16 f2bf(float x) {   // RNE float->bf16 bits
    u32 u = __float_as_uint(x);
    return (u16)((u + 0x7fffu + ((u >> 16) & 1u)) >> 16);
}
static __device__ __forceinline__ float bf2f(u16 h) {
    return __uint_as_float(((u32)h) << 16);
}
static __device__ __forceinline__ void split3(float x, u16& h, u16& m, u16& l) {
    h = f2bf(x);
    float r1 = x - bf2f(h);
    m = f2bf(r1);
    l = f2bf(r1 - bf2f(m));
}
static __device__ __forceinline__ u32 ordf(float x) {   // monotone float->u32
    u32 b = __float_as_uint(x);
    return (b & 0x80000000u) ? ~b : (b | 0x80000000u);
}
// pack top-16 bits of two fp32 (1 v_perm)
static __device__ __forceinline__ u32 pack_hi16(u32 a, u32 b) {
    return __builtin_amdgcn_perm(b, a, 0x07060302u);
}
// truncation split-3: h,m,l = successive top-16 truncations (exact subs).
static __device__ __forceinline__ void tsplit3_pack(
    float x0, float x1, u32& ph, u32& pm, u32& pl)
{
    u32 b0 = __float_as_uint(x0), b1 = __float_as_uint(x1);
    ph = pack_hi16(b0, b1);
    float r0 = x0 - __uint_as_float(b0 & 0xFFFF0000u);
    float r1 = x1 - __uint_as_float(b1 & 0xFFFF0000u);
    u32 c0 = __float_as_uint(r0), c1 = __float_as_uint(r1);
    pm = pack_hi16(c0, c1);
    float s0 = r0 - __uint_as_float(c0 & 0xFFFF0000u);
    float s1 = r1 - __uint_as_float(c1 & 0xFFFF0000u);
    pl = pack_hi16(__float_as_uint(s0), __float_as_uint(s1));
}
static __device__ __forceinline__ void tsplit2_pack(
    float x0, float x1, u32& ph, u32& pm)
{
    u32 b0 = __float_as_uint(x0), b1 = __float_as_uint(x1);
    ph = pack_hi16(b0, b1);
    float r0 = x0 - __uint_as_float(b0 & 0xFFFF0000u);
    float r1 = x1 - __uint_as_float(b1 & 0xFFFF0000u);
    pm = pack_hi16(__float_as_uint(r0), __float_as_uint(r1));
}

// ---------------------------------------------------------------------------
// h = TokenConv(x) + TimeLinear(xm) + PE   -> H [B, L, 512]
// ---------------------------------------------------------------------------
__global__ __launch_bounds__(512) void build_h_kernel(
    const float* __restrict__ x_enc, const float* __restrict__ x_mark_enc,
    const float* __restrict__ x_dec, const float* __restrict__ x_mark_dec,
    const float* __restrict__ token_w, const float* __restrict__ temp_w,
    float* __restrict__ H)
{
    int bl = blockIdx.x;
    int b = bl >> 11, l = bl & 2047;
    __shared__ float xr[3][7];
    __shared__ float xmr[4];
    int tid = threadIdx.x;
    if (tid < 21) {
        int k = tid / 7, c = tid % 7;
        int t = (l + k - 1 + LTOT) & 2047;
        float v;
        if (t < SEQ) v = x_enc[(b * SEQ + t) * 7 + c];
        else         v = x_dec[(b * DECL + (t - 1280)) * 7 + c];
        xr[k][c] = v;
    } else if (tid < 25) {
        int m = tid - 21;
        float v;
        if (l < SEQ) v = x_mark_enc[(b * SEQ + l) * 4 + m];
        else         v = x_mark_dec[(b * DECL + (l - 1280)) * 4 + m];
        xmr[m] = v;
    }
    __syncthreads();
    int d = tid;  // 0..511
    double val = 0.0;
    #pragma unroll
    for (int k = 0; k < 3; ++k)
        #pragma unroll
        for (int c = 0; c < 7; ++c)
            val += (double)xr[k][c] * (double)token_w[(d * 7 + c) * 3 + k];
    double tmp = 0.0;
    #pragma unroll
    for (int m = 0; m < 4; ++m) tmp += (double)xmr[m] * (double)temp_w[d * 4 + m];
    const float cf = (float)(-9.210340371976184 / 512.0);
    float ef  = (float)(2 * (d >> 1)) * cf;
    float dvf = (float)exp((double)ef);
    float angf = (float)l * dvf;
    double pe = (d & 1) ? cos((double)angf) : sin((double)angf);
    H[((size_t)b * LTOT + l) * DM + d] = (float)(val + tmp + pe);
}

// ---------------------------------------------------------------------------
// Pre-split the layer's 5 weight matrices into trunc-bf16 h/m/l planes,
// TILED layout: per matrix, [nt][kt][128][32] (exact GEMM LDS image).
// ---------------------------------------------------------------------------
__global__ __launch_bounds__(256) void wsplit_kernel(
    const float* __restrict__ qkw, const float* __restrict__ vw,
    const float* __restrict__ ow, const float* __restrict__ f1w,
    const float* __restrict__ f2w,
    u16* __restrict__ Ph, u16* __restrict__ Pm, u16* __restrict__ Pl)
{
    size_t i = ((size_t)blockIdx.x * 256 + threadIdx.x) * 4;
    const float* src; size_t off, base; int kshift;
    if (i < 262144)       { src = qkw; off = i;           base = 0;       kshift = 9; }
    else if (i < 524288)  { src = vw;  off = i - 262144;  base = 262144;  kshift = 9; }
    else if (i < 786432)  { src = ow;  off = i - 524288;  base = 524288;  kshift = 9; }
    else if (i < 1835008) { src = f1w; off = i - 786432;  base = 786432;  kshift = 9; }
    else                  { src = f2w; off = i - 1835008; base = 1835008; kshift = 11; }
    int K = 1 << kshift;
    int n  = (int)(off >> kshift);
    int kg = (int)(off & (size_t)(K - 1));
    int nt = n >> 7, r = n & 127, kt = kg >> 5, kk = kg & 31;
    size_t o = base + ((((size_t)nt * (K >> 5) + kt) << 12) | ((size_t)r << 5) | kk);
    float4 x = *(const float4*)(src + off);
    u32 h01, m01, l01, h23, m23, l23;
    tsplit3_pack(x.x, x.y, h01, m01, l01);
    tsplit3_pack(x.z, x.w, h23, m23, l23);
    *(uint2*)(Ph + o) = make_uint2(h01, h23);
    *(uint2*)(Pm + o) = make_uint2(m01, m23);
    *(uint2*)(Pl + o) = make_uint2(l01, l23);
}

// ---------------------------------------------------------------------------
// MFMA split-bf16 GEMM: C[M,N] = act( A[M,K] @ W[N,K]^T + bias + res )
// W from tiled u16 planes (fully coalesced staging); A split in-kernel.
// ---------------------------------------------------------------------------
template<int NSPLIT>
__global__ __launch_bounds__(256) void gemm_mfma(
    const float* __restrict__ A,
    const u16* __restrict__ WTh, const u16* __restrict__ WTm,
    const u16* __restrict__ WTl,
    const float* __restrict__ bias, const float* __restrict__ res,
    float* __restrict__ C, int M, int N, int K, int act)
{
    __shared__ u16 Ah[128][32], Am[128][32], Al[128][32];
    __shared__ u16 Wh[128][32], Wm[128][32], Wl[128][32];
    const int tid = threadIdx.x;
    const int n0 = blockIdx.x * 128, m0 = blockIdx.y * 128;
    const int row = tid >> 1;           // 0..127
    const int koff = (tid & 1) * 16;    // 0 or 16
    const float* Ag = A + (size_t)(m0 + row) * K + koff;

    const int wv = tid >> 6, lane = tid & 63;
    const int m0w = (wv >> 1) * 64, n0w = (wv & 1) * 64;
    const int fr = lane & 15, quad = lane >> 4;
    u16* WhF = &Wh[0][0]; u16* WmF = &Wm[0][0]; u16* WlF = &Wl[0][0];

    floatx4 acc[4][4];
    #pragma unroll
    for (int i = 0; i < 4; ++i)
        #pragma unroll
        for (int j = 0; j < 4; ++j) acc[i][j] = (floatx4)0.0f;

    for (int kt = 0; kt < K; kt += 32) {
        const size_t tb = ((size_t)blockIdx.x * (K >> 5) + (kt >> 5)) * 4096;
        // W planes: tiled -> fully coalesced 16B/lane loads.
        uint4 wh0 = *(const uint4*)(WTh + tb + tid * 8);
        uint4 wh1 = *(const uint4*)(WTh + tb + 2048 + tid * 8);
        uint4 wm0 = *(const uint4*)(WTm + tb + tid * 8);
        uint4 wm1 = *(const uint4*)(WTm + tb + 2048 + tid * 8);
        uint4 wl0, wl1;
        if (NSPLIT == 3) {
            wl0 = *(const uint4*)(WTl + tb + tid * 8);
            wl1 = *(const uint4*)(WTl + tb + 2048 + tid * 8);
        }
        // A: load fp32, trunc-split.
        u32 pah[8], pam[8], pal[8];
        #pragma unroll
        for (int g = 0; g < 4; ++g) {
            float4 a4 = *(const float4*)(Ag + kt + g * 4);
            if (NSPLIT == 3) {
                tsplit3_pack(a4.x, a4.y, pah[g*2], pam[g*2], pal[g*2]);
                tsplit3_pack(a4.z, a4.w, pah[g*2+1], pam[g*2+1], pal[g*2+1]);
            } else {
                tsplit2_pack(a4.x, a4.y, pah[g*2], pam[g*2]);
                tsplit2_pack(a4.z, a4.w, pah[g*2+1], pam[g*2+1]);
            }
        }
        __syncthreads();
        ((uint4*)&Ah[row][koff])[0] = make_uint4(pah[0], pah[1], pah[2], pah[3]);
        ((uint4*)&Ah[row][koff])[1] = make_uint4(pah[4], pah[5], pah[6], pah[7]);
        ((uint4*)&Am[row][koff])[0] = make_uint4(pam[0], pam[1], pam[2], pam[3]);
        ((uint4*)&Am[row][koff])[1] = make_uint4(pam[4], pam[5], pam[6], pam[7]);
        *(uint4*)(WhF + tid * 8) = wh0;
        *(uint4*)(WhF + 2048 + tid * 8) = wh1;
        *(uint4*)(WmF + tid * 8) = wm0;
        *(uint4*)(WmF + 2048 + tid * 8) = wm1;
        if (NSPLIT == 3) {
            ((uint4*)&Al[row][koff])[0] = make_uint4(pal[0], pal[1], pal[2], pal[3]);
            ((uint4*)&Al[row][koff])[1] = make_uint4(pal[4], pal[5], pal[6], pal[7]);
            *(uint4*)(WlF + tid * 8) = wl0;
            *(uint4*)(WlF + 2048 + tid * 8) = wl1;
        }
        __syncthreads();
        short8 ah4[4], am4[4], al4[4];
        #pragma unroll
        for (int rt = 0; rt < 4; ++rt) {
            int r = m0w + rt * 16 + fr;
            ah4[rt] = *(const short8*)&Ah[r][quad * 8];
            am4[rt] = *(const short8*)&Am[r][quad * 8];
            if (NSPLIT == 3) al4[rt] = *(const short8*)&Al[r][quad * 8];
        }
        #pragma unroll
        for (int ct = 0; ct < 4; ++ct) {
            int nrw = n0w + ct * 16 + fr;
            short8 bh4 = *(const short8*)&Wh[nrw][quad * 8];
            short8 bm4 = *(const short8*)&Wm[nrw][quad * 8];
            short8 bl4;
            if (NSPLIT == 3) bl4 = *(const short8*)&Wl[nrw][quad * 8];
            #pragma unroll
            for (int rt = 0; rt < 4; ++rt) {
                floatx4 c = acc[rt][ct];
                c = __builtin_amdgcn_mfma_f32_16x16x32_bf16(ah4[rt], bh4, c, 0, 0, 0);
                c = __builtin_amdgcn_mfma_f32_16x16x32_bf16(ah4[rt], bm4, c, 0, 0, 0);
                c = __builtin_amdgcn_mfma_f32_16x16x32_bf16(am4[rt], bh4, c, 0, 0, 0);
                if (NSPLIT == 3) {
                    c = __builtin_amdgcn_mfma_f32_16x16x32_bf16(ah4[rt], bl4, c, 0, 0, 0);
                    c = __builtin_amdgcn_mfma_f32_16x16x32_bf16(am4[rt], bm4, c, 0, 0, 0);
                    c = __builtin_amdgcn_mfma_f32_16x16x32_bf16(al4[rt], bh4, c, 0, 0, 0);
                }
                acc[rt][ct] = c;
            }
        }
    }
    // Epilogue: C/D layout col=lane&15, row=quad*4+reg (m89-verified).
    #pragma unroll
    for (int rt = 0; rt < 4; ++rt) {
        #pragma unroll
        for (int ct = 0; ct < 4; ++ct) {
            int n = n0 + n0w + ct * 16 + fr;
            #pragma unroll
            for (int reg = 0; reg < 4; ++reg) {
                int m = m0 + m0w + rt * 16 + quad * 4 + reg;
                double v = (double)acc[rt][ct][reg];
                if (bias) v += (double)bias[n];
                if (res)  v += (double)res[(size_t)m * N + n];
                if (act == 1) v = gelu_d(v);
                C[(size_t)m * N + n] = (float)v;
            }
        }
    }
}

// ---------------------------------------------------------------------------
// Precompute split-3 bf16 planes of rot, transposed to [h][r][d].
// ---------------------------------------------------------------------------
__global__ __launch_bounds__(256) void rot_split_kernel(
    const float* __restrict__ rot, u16* __restrict__ RSh,
    u16* __restrict__ RSm, u16* __restrict__ RSl)
{
    int h = blockIdx.x;      // 0..3
    int r = threadIdx.x;     // 0..255
    #pragma unroll 4
    for (int d = 0; d < 64; ++d) {
        float v = rot[(d * 4 + h) * 256 + r];
        u16 hh, mm, ll;
        split3(v, hh, mm, ll);
        size_t o = ((size_t)h * 256 + r) * 64 + d;
        RSh[o] = hh; RSm[o] = mm; RSl[o] = ll;
    }
}

// ---------------------------------------------------------------------------
// LSH hash via split-3 bf16 MFMA + fused argmax.
// Two half-passes over token rows (acc halved -> occupancy up); LDS pad 68
// (2-way bank aliasing = free); single-key fabs argmax (order-equivalent).
// ---------------------------------------------------------------------------
__global__ __launch_bounds__(256) void lsh_hash_mfma(
    const float* __restrict__ QK, const u16* __restrict__ RSh,
    const u16* __restrict__ RSm, const u16* __restrict__ RSl,
    int* __restrict__ BKT)
{
    __shared__ u16 Ah[128][68], Am[128][68], Al[128][68];  // padded rows
    __shared__ u64 best[128];
    int bid = blockIdx.x;
    int tt = bid & 15;
    int h  = (bid >> 4) & 3;
    int bh = bid >> 6;
    int tid = threadIdx.x;
    int b = bh >> 3, hd = bh & 7;
    const int t0 = tt * 128;

    if (tid < 128) best[tid] = 0ull;

    {
        int row = tid >> 1;
        int kbase = (tid & 1) * 32;
        const float* src = QK + ((size_t)(b * LTOT + t0 + row)) * DM + hd * DH + kbase;
        u32 ph[16], pm[16], pl[16];
        #pragma unroll
        for (int g = 0; g < 8; ++g) {
            float4 a4 = *(const float4*)(src + g * 4);
            u16 h0, m0_, l0, h1, m1_, l1;
            split3(a4.x, h0, m0_, l0); split3(a4.y, h1, m1_, l1);
            ph[g*2]   = (u32)h0 | ((u32)h1 << 16);
            pm[g*2]   = (u32)m0_ | ((u32)m1_ << 16);
            pl[g*2]   = (u32)l0 | ((u32)l1 << 16);
            split3(a4.z, h0, m0_, l0); split3(a4.w, h1, m1_, l1);
            ph[g*2+1] = (u32)h0 | ((u32)h1 << 16);
            pm[g*2+1] = (u32)m0_ | ((u32)m1_ << 16);
            pl[g*2+1] = (u32)l0 | ((u32)l1 << 16);
        }
        #pragma unroll
        for (int g = 0; g < 4; ++g) {
            ((uint4*)&Ah[row][kbase])[g] = make_uint4(ph[g*4], ph[g*4+1], ph[g*4+2], ph[g*4+3]);
            ((uint4*)&Am[row][kbase])[g] = make_uint4(pm[g*4], pm[g*4+1], pm[g*4+2], pm[g*4+3]);
            ((uint4*)&Al[row][kbase])[g] = make_uint4(pl[g*4], pl[g*4+1], pl[g*4+2], pl[g*4+3]);
        }
    }
    __syncthreads();

    const int wv = tid >> 6, lane = tid & 63;
    const int fr = lane & 15, quad = lane >> 4;
    const int nbase = wv * 64;

    #pragma unroll
    for (int half = 0; half < 2; ++half) {
        floatx4 acc[4][4];
        #pragma unroll
        for (int i = 0; i < 4; ++i)
            #pragma unroll
            for (int j = 0; j < 4; ++j) acc[i][j] = (floatx4)0.0f;

        #pragma unroll
        for (int kt = 0; kt < 2; ++kt) {
            #pragma unroll
            for (int ct = 0; ct < 4; ++ct) {
                size_t bo = ((size_t)h * 256 + nbase + ct * 16 + fr) * 64 + kt * 32 + quad * 8;
                short8 bh4 = *(const short8*)(RSh + bo);
                short8 bm4 = *(const short8*)(RSm + bo);
                short8 bl4 = *(const short8*)(RSl + bo);
                #pragma unroll
                for (int rt = 0; rt < 4; ++rt) {
                    const int ar = (half * 4 + rt) * 16 + fr, ak = kt * 32 + quad * 8;
                    short8 ah4 = *(const short8*)&Ah[ar][ak];
                    short8 am4 = *(const short8*)&Am[ar][ak];
                    short8 al4 = *(const short8*)&Al[ar][ak];
                    floatx4 c = acc[rt][ct];
                    c = __builtin_amdgcn_mfma_f32_16x16x32_bf16(ah4, bh4, c, 0, 0, 0);
                    c = __builtin_amdgcn_mfma_f32_16x16x32_bf16(ah4, bm4, c, 0, 0, 0);
                    c = __builtin_amdgcn_mfma_f32_16x16x32_bf16(am4, bh4, c, 0, 0, 0);
                    c = __builtin_amdgcn_mfma_f32_16x16x32_bf16(ah4, bl4, c, 0, 0, 0);
                    c = __builtin_amdgcn_mfma_f32_16x16x32_bf16(am4, bm4, c, 0, 0, 0);
                    c = __builtin_amdgcn_mfma_f32_16x16x32_bf16(al4, bh4, c, 0, 0, 0);
                    acc[rt][ct] = c;
                }
            }
        }

        #pragma unroll
        for (int rt = 0; rt < 4; ++rt) {
            #pragma unroll
            for (int reg = 0; reg < 4; ++reg) {
                u64 key = 0ull;
                #pragma unroll
                for (int ct = 0; ct < 4; ++ct) {
                    float v = acc[rt][ct][reg];
                    float mag = fabsf(v);
                    u32 idx = nbase + ct * 16 + fr + ((v >= 0.f) ? 0u : 256u);
                    u64 k = ((u64)(__float_as_uint(mag) | 0x80000000u) << 32)
                            | (u32)(0xFFFFFFFFu - idx);
                    if (k > key) key = k;
                }
                #pragma unroll
                for (int m = 1; m <= 8; m <<= 1) {
                    u64 o = __shfl_xor((unsigned long long)key, m, 64);
                    if (o > key) key = o;
                }
                if (fr == 0) {
                    int tok = (half * 4 + rt) * 16 + quad * 4 + reg;
                    atomicMax(&best[tok], key);
                }
            }
        }
    }
    __syncthreads();
    if (tid < 128) {
        u32 idx = 0xFFFFFFFFu - (u32)best[tid];
        BKT[((size_t)bh * NHASH + h) * LTOT + t0 + tid] = (int)idx;
    }
}

// ---------------------------------------------------------------------------
// Stable counting sort per (bh, hash): sorted-by-(bucket, t).
// ---------------------------------------------------------------------------
__global__ __launch_bounds__(256) void lsh_sort_kernel(
    const int* __restrict__ BKT, int* __restrict__ STS)
{
    __shared__ unsigned short bkt[2048];
    __shared__ unsigned int hist2[16][512];
    __shared__ unsigned int bstart[512];
    int bid = blockIdx.x;
    int h = bid & 3, bh = bid >> 2;
    int tid = threadIdx.x;
    const int* src = BKT + ((size_t)bh * NHASH + h) * LTOT;
    for (int t = tid; t < 2048; t += 256) bkt[t] = (unsigned short)src[t];
    for (int i = tid; i < 16 * 512; i += 256) (&hist2[0][0])[i] = 0u;
    __syncthreads();
    for (int t = tid; t < 2048; t += 256)
        atomicAdd(&hist2[t >> 7][bkt[t]], 1u);
    __syncthreads();
    for (int bb = tid; bb < 512; bb += 256) {
        unsigned int run = 0;
        #pragma unroll
        for (int g = 0; g < 16; ++g) {
            unsigned int c = hist2[g][bb];
            hist2[g][bb] = run;
            run += c;
        }
        bstart[bb] = run;
    }
    __syncthreads();
    if (tid == 0) {
        unsigned int run = 0;
        for (int bb = 0; bb < 512; ++bb) {
            unsigned int c = bstart[bb];
            bstart[bb] = run;
            run += c;
        }
    }
    __syncthreads();
    int* dst = STS + (size_t)bh * (NHASH * LTOT) + h * LTOT;
    for (int t = tid; t < 2048; t += 256) {
        int bb = bkt[t];
        unsigned int rank = hist2[t >> 7][bb];
        int g0 = t & ~127;
        for (int u = g0; u < t; ++u) rank += (bkt[u] == (unsigned short)bb);
        dst[bstart[bb] + rank] = t;
    }
}

// ---------------------------------------------------------------------------
// Per-token k reciprocal norms (same butterfly order as before -> bit-equal).
// RN[bh][t] = 0.125 / max(||k||, 1e-12)
// ---------------------------------------------------------------------------
__global__ __launch_bounds__(256) void knorm_kernel(
    const float* __restrict__ QK, float* __restrict__ RN)
{
    int wid = (blockIdx.x * 256 + threadIdx.x) >> 6;   // 0..131071
    int lane = threadIdx.x & 63;
    int bh = wid >> 11, t = wid & 2047;
    int b = bh >> 3, hd = bh & 7;
    float kv = QK[((size_t)(b * LTOT + t)) * DM + hd * DH + lane];
    float v = kv * kv;
    #pragma unroll
    for (int m = 32; m; m >>= 1) v += __shfl_xor(v, m, 64);
    if (lane == 0)
        RN[(size_t)bh * LTOT + t] = 0.125f / fmaxf(sqrtf(v), 1e-12f);
}

// ---------------------------------------------------------------------------
// Attention pass A (fp32): dots + LSE + cached normalized probs PRB.
// rnrm loaded from precomputed RN (bit-identical values).
// ---------------------------------------------------------------------------
__global__ __launch_bounds__(256) void attn_lse_kernel(
    const float* __restrict__ QK, const int* __restrict__ STS,
    const float* __restrict__ RN,
    float* __restrict__ LSE, float* __restrict__ PRB)
{
    int wid = (blockIdx.x * 256 + threadIdx.x) >> 6;   // global wave id
    int lane = threadIdx.x & 63;
    int bh = wid >> 11;          // 0..63
    int c  = wid & 2047;
    int cp = (c + NCH - 1) & (NCH - 1);
    const int* sts = STS + (size_t)bh * 8192;
    int tok[8];
    #pragma unroll
    for (int j = 0; j < 4; ++j) tok[j] = sts[4 * c + j];
    #pragma unroll
    for (int j = 0; j < 4; ++j) tok[4 + j] = sts[4 * cp + j];
    int b = bh >> 3, hd = bh & 7;
    const float* base = QK + ((size_t)b * LTOT) * DM + hd * DH + lane;
    float kd[8];
    #pragma unroll
    for (int j = 0; j < 8; ++j) kd[j] = base[(size_t)tok[j] * DM];
    const float* rnb = RN + (size_t)bh * LTOT;
    float rnrm[8];
    #pragma unroll
    for (int j = 0; j < 8; ++j) rnrm[j] = rnb[tok[j]];
    int hr = c >> 9;
    size_t cbase = ((size_t)bh * NCH + c) * 32;
    float pkeep = 0.f;
    #pragma unroll
    for (int i = 0; i < 4; ++i) {
        float dots[8];
        float myd = -5e4f;
        #pragma unroll
        for (int j = 0; j < 8; ++j) {
            float v = kd[i] * kd[j];
            #pragma unroll
            for (int m = 32; m; m >>= 1) v += __shfl_xor(v, m, 64);
            dots[j] = (tok[j] == tok[i]) ? -5e4f : v * rnrm[j];
            if ((lane & 7) == j) myd = dots[j];
        }
        float mx = dots[0];
        #pragma unroll
        for (int j = 1; j < 8; ++j) mx = fmaxf(mx, dots[j]);
        float s = 0.f;
        #pragma unroll
        for (int j = 0; j < 8; ++j) s += expf(dots[j] - mx);
        float pn = expf(myd - mx) / s;
        if ((lane >> 3) == i) pkeep = pn;
        if (lane == 0)
            LSE[((size_t)bh * NHASH + hr) * LTOT + tok[i]] = mx + logf(s);
    }
    if (lane < 32) PRB[cbase + lane] = pkeep;
}

// ---------------------------------------------------------------------------
// Cross-round softmax weights per token: W4[bh][hr][t] from LSE.
// ---------------------------------------------------------------------------
__global__ __launch_bounds__(256) void wsoft_kernel(
    const float* __restrict__ LSE, float* __restrict__ W4)
{
    int idx = blockIdx.x * 256 + threadIdx.x;   // 131072
    int bh = idx >> 11, t = idx & 2047;
    float L[4];
    #pragma unroll
    for (int hh = 0; hh < 4; ++hh)
        L[hh] = LSE[((size_t)bh * NHASH + hh) * LTOT + t];
    float wm = fmaxf(fmaxf(L[0], L[1]), fmaxf(L[2], L[3]));
    float ws = 0.f;
    #pragma unroll
    for (int hh = 0; hh < 4; ++hh) ws += expf(L[hh] - wm);
    float inv = 1.f / ws;
    #pragma unroll
    for (int hh = 0; hh < 4; ++hh)
        W4[((size_t)bh * NHASH + hh) * LTOT + t] = expf(L[hh] - wm) * inv;
}

// ---------------------------------------------------------------------------
// Attention pass B: cached probs + weights -> weighted V accumulate.
// ---------------------------------------------------------------------------
__global__ __launch_bounds__(256) void attn_out_kernel(
    const float* __restrict__ V, const int* __restrict__ STS,
    const float* __restrict__ PRB, const float* __restrict__ W4,
    float* __restrict__ C)
{
    int wid = (blockIdx.x * 256 + threadIdx.x) >> 6;
    int lane = threadIdx.x & 63;
    int bh = wid >> 11;
    int c  = wid & 2047;
    int cp = (c + NCH - 1) & (NCH - 1);
    const int* sts = STS + (size_t)bh * 8192;
    int tok[8];
    #pragma unroll
    for (int j = 0; j < 4; ++j) tok[j] = sts[4 * c + j];
    #pragma unroll
    for (int j = 0; j < 4; ++j) tok[4 + j] = sts[4 * cp + j];
    int b = bh >> 3, hd = bh & 7;
    const float* vbase = V + ((size_t)b * LTOT) * DM + hd * DH + lane;
    float vd[8];
    #pragma unroll
    for (int j = 0; j < 8; ++j) vd[j] = vbase[(size_t)tok[j] * DM];
    size_t cbase = ((size_t)bh * NCH + c) * 32;
    float pv = PRB[cbase + (lane & 31)];
    int hr = c >> 9;
    const float* w4b = W4 + ((size_t)bh * NHASH + hr) * LTOT;
    float* crow0 = C + ((size_t)b * LTOT) * DM + hd * DH + lane;
    #pragma unroll
    for (int i = 0; i < 4; ++i) {
        float w = w4b[tok[i]];
        float acc = 0.f;
        #pragma unroll
        for (int j = 0; j < 8; ++j)
            acc += __shfl(pv, i * 8 + j, 64) * vd[j];
        atomicAdd(crow0 + (size_t)tok[i] * DM, acc * w);
    }
}

// ---------------------------------------------------------------------------
// LayerNorm over last dim (512). fp64 stats + transform, fp32 out.
// ---------------------------------------------------------------------------
__global__ __launch_bounds__(256) void ln_kernel(
    const float* __restrict__ X, float* __restrict__ Y,
    const float* __restrict__ g, const float* __restrict__ bta)
{
    int row = blockIdx.x;
    int tid = threadIdx.x;
    const float* x = X + (size_t)row * DM;
    double v0 = (double)x[tid], v1 = (double)x[tid + 256];
    double s = v0 + v1;
    double q = v0 * v0 + v1 * v1;
    #pragma unroll
    for (int off = 32; off; off >>= 1) {
        s += __shfl_down(s, off, 64);
        q += __shfl_down(q, off, 64);
    }
    __shared__ double ss[4], qq[4];
    int wid = tid >> 6, lane = tid & 63;
    if (lane == 0) { ss[wid] = s; qq[wid] = q; }
    __syncthreads();
    if (tid == 0) {
        double S = ss[0] + ss[1] + ss[2] + ss[3];
        double Q = qq[0] + qq[1] + qq[2] + qq[3];
        double mu = S * (1.0 / 512.0);
        double var = Q * (1.0 / 512.0) - mu * mu;
        ss[0] = mu;
        qq[0] = 1.0 / sqrt(var + 1e-5);
    }
    __syncthreads();
    double mu = ss[0], rs = qq[0];
    Y[(size_t)row * DM + tid] =
        (float)((v0 - mu) * rs * (double)g[tid] + (double)bta[tid]);
    Y[(size_t)row * DM + tid + 256] =
        (float)((v1 - mu) * rs * (double)g[tid + 256] + (double)bta[tid + 256]);
}

// ---------------------------------------------------------------------------
// Final projection + slice (fp64 acc, fp32 out).
// ---------------------------------------------------------------------------
__global__ __launch_bounds__(64) void proj_kernel(
    const float* __restrict__ Hf, const float* __restrict__ pw,
    const float* __restrict__ pb, float* __restrict__ out)
{
    int idx = blockIdx.x;               // 0..4095
    int b = idx >> 9, i = idx & 511;
    const float* row = Hf + ((size_t)(b * LTOT + SEQ + i)) * DM;
    int lane = threadIdx.x;
    double s = 0.0;
    #pragma unroll
    for (int k = 0; k < 8; ++k)
        s += (double)row[lane + 64 * k] * (double)pw[lane + 64 * k];
    #pragma unroll
    for (int off = 32; off; off >>= 1) s += __shfl_down(s, off, 64);
    if (lane == 0) out[idx] = (float)(s + (double)pb[0]);
}

// ---------------------------------------------------------------------------
extern "C" void kernel_launch(void* const* d_in, const int* in_sizes, int n_in,
                              void* d_out, int out_size, void* d_ws, size_t ws_size,
                              hipStream_t stream)
{
    const float* x_enc      = (const float*)d_in[0];
    const float* x_mark_enc = (const float*)d_in[1];
    const float* x_dec      = (const float*)d_in[2];
    const float* x_mark_dec = (const float*)d_in[3];
    const float* token_w    = (const float*)d_in[4];
    const float* temp_w     = (const float*)d_in[5];
    const float* qk_w       = (const float*)d_in[6];
    const float* v_w        = (const float*)d_in[7];
    const float* out_w      = (const float*)d_in[8];
    const float* out_b      = (const float*)d_in[9];
    const float* ln1_g      = (const float*)d_in[10];
    const float* ln1_b      = (const float*)d_in[11];
    const float* ff1_w      = (const float*)d_in[12];
    const float* ff1_b      = (const float*)d_in[13];
    const float* ff2_w      = (const float*)d_in[14];
    const float* ff2_b      = (const float*)d_in[15];
    const float* ln2_g      = (const float*)d_in[16];
    const float* ln2_b      = (const float*)d_in[17];
    const float* norm_g     = (const float*)d_in[18];
    const float* norm_b     = (const float*)d_in[19];
    const float* proj_w     = (const float*)d_in[20];
    const float* proj_b     = (const float*)d_in[21];
    const float* rotations  = (const float*)d_in[22];

    float* ws = (float*)d_ws;
    const size_t S = (size_t)BATCH * LTOT * DM;   // 8,388,608 floats
    float* Hb  = ws;
    float* QKb = ws + S;
    float* Vb  = ws + 2 * S;
    float* Cb  = ws + 3 * S;
    float* Yb  = QKb;                    // FFN intermediate: spans QKb+Vb (2S)
    int*   BKTb = (int*)(ws + 4 * S);              // 2 MB
    float* LSEb = ws + 4 * S + 524288;             // 2 MB
    int*   STSb = (int*)(ws + 4 * S + 2 * 524288); // 2 MB
    u16*   RShb = (u16*)(ws + 4 * S + 3 * 524288); // rot planes 128 KB x3
    u16*   RSmb = RShb + 4 * 256 * 64;
    u16*   RSlb = RSmb + 4 * 256 * 64;
    const size_t WTOT = 2883584;                   // u16 per weight plane
    u16*   WPh = (u16*)(ws + 4 * S + 3 * 524288 + 98304);
    u16*   WPm = WPh + WTOT;
    u16*   WPl = WPm + WTOT;
    float* PRBb = ws + 4 * S + 3 * 524288 + 98304 + (3 * WTOT) / 2;  // 16.8 MB
    float* W4b  = PRBb + (size_t)NBH * NCH * 32;                     // 2 MB
    float* RNb  = W4b + (size_t)NBH * NHASH * LTOT;                  // 0.5 MB
    const size_t WO_QK = 0, WO_V = 262144, WO_O = 524288,
                 WO_F1 = 786432, WO_F2 = 1835008;

    build_h_kernel<<<BATCH * LTOT, 512, 0, stream>>>(
        x_enc, x_mark_enc, x_dec, x_mark_dec, token_w, temp_w, Hb);

    const int M = BATCH * LTOT;  // 16384
    const int ATT_BLOCKS = NBH * NCH / 4;  // 32768 waves / 4 per block
    for (int l = 0; l < 2; ++l) {
        const float* qkw = qk_w + (size_t)l * DM * DM;
        const float* vw  = v_w  + (size_t)l * DM * DM;
        const float* ow  = out_w + (size_t)l * DM * DM;
        const float* ob  = out_b + (size_t)l * DM;
        const float* l1g = ln1_g + (size_t)l * DM;
        const float* l1b = ln1_b + (size_t)l * DM;
        const float* f1w = ff1_w + (size_t)l * DFF * DM;
        const float* f1b = ff1_b + (size_t)l * DFF;
        const float* f2w = ff2_w + (size_t)l * DM * DFF;
        const float* f2b = ff2_b + (size_t)l * DM;
        const float* l2g = ln2_g + (size_t)l * DM;
        const float* l2b = ln2_b + (size_t)l * DM;
        const float* rot = rotations + (size_t)l * DH * NHASH * 256;

        wsplit_kernel<<<2816, 256, 0, stream>>>(qkw, vw, ow, f1w, f2w, WPh, WPm, WPl);

        dim3 gQ(DM / 128, M / 128);  // (4, 128)
        gemm_mfma<3><<<gQ, 256, 0, stream>>>(Hb, WPh + WO_QK, WPm + WO_QK, WPl + WO_QK,
                                             nullptr, nullptr, QKb, M, DM, DM, 0);
        if (l == 0)
            gemm_mfma<3><<<gQ, 256, 0, stream>>>(Hb, WPh + WO_V, WPm + WO_V, WPl + WO_V,
                                                 nullptr, nullptr, Vb, M, DM, DM, 0);
        else
            gemm_mfma<2><<<gQ, 256, 0, stream>>>(Hb, WPh + WO_V, WPm + WO_V, WPl + WO_V,
                                                 nullptr, nullptr, Vb, M, DM, DM, 0);

        rot_split_kernel<<<4, 256, 0, stream>>>(rot, RShb, RSmb, RSlb);
        lsh_hash_mfma<<<NBH * NHASH * 16, 256, 0, stream>>>(QKb, RShb, RSmb, RSlb, BKTb);
        lsh_sort_kernel<<<NBH * NHASH, 256, 0, stream>>>(BKTb, STSb);
        knorm_kernel<<<32768, 256, 0, stream>>>(QKb, RNb);

        hipMemsetAsync(Cb, 0, S * sizeof(float), stream);
        attn_lse_kernel<<<ATT_BLOCKS, 256, 0, stream>>>(QKb, STSb, RNb, LSEb, PRBb);
        wsoft_kernel<<<512, 256, 0, stream>>>(LSEb, W4b);
        attn_out_kernel<<<ATT_BLOCKS, 256, 0, stream>>>(Vb, STSb, PRBb, W4b, Cb);

        // h = h + attn @ out_w^T + out_b   (in-place residual)
        if (l == 0)
            gemm_mfma<3><<<gQ, 256, 0, stream>>>(Cb, WPh + WO_O, WPm + WO_O, WPl + WO_O,
                                                 ob, Hb, Hb, M, DM, DM, 0);
        else
            gemm_mfma<2><<<gQ, 256, 0, stream>>>(Cb, WPh + WO_O, WPm + WO_O, WPl + WO_O,
                                                 ob, Hb, Hb, M, DM, DM, 0);
        ln_kernel<<<M, 256, 0, stream>>>(Hb, Hb, l1g, l1b);

        // FFN in 2 row-halves of 8192; Y spans QKb+Vb; ff2 in-place into Hb.
        for (int hb2 = 0; hb2 < 2; ++hb2) {
            float* hpart = Hb + (size_t)hb2 * 8192 * DM;
            dim3 gF1(DFF / 128, 8192 / 128);  // (16, 64) = 1024 blocks
            dim3 gF2(DM / 128, 8192 / 128);   // (4, 64)  = 256 blocks
            if (l == 0) {
                gemm_mfma<3><<<gF1, 256, 0, stream>>>(hpart, WPh + WO_F1, WPm + WO_F1, WPl + WO_F1,
                                                      f1b, nullptr, Yb, 8192, DFF, DM, 1);
                gemm_mfma<3><<<gF2, 256, 0, stream>>>(Yb, WPh + WO_F2, WPm + WO_F2, WPl + WO_F2,
                                                      f2b, hpart, hpart, 8192, DM, DFF, 0);
            } else {
                gemm_mfma<2><<<gF1, 256, 0, stream>>>(hpart, WPh + WO_F1, WPm + WO_F1, WPl + WO_F1,
                                                      f1b, nullptr, Yb, 8192, DFF, DM, 1);
                gemm_mfma<2><<<gF2, 256, 0, stream>>>(Yb, WPh + WO_F2, WPm + WO_F2, WPl + WO_F2,
                                                      f2b, hpart, hpart, 8192, DM, DFF, 0);
            }
        }
        ln_kernel<<<M, 256, 0, stream>>>(Hb, Hb, l2g, l2b);
    }

    ln_kernel<<<M, 256, 0, stream>>>(Hb, Cb, norm_g, norm_b);
    proj_kernel<<<4096, 64, 0, stream>>>(Cb, proj_w, proj_b, (float*)d_out);
}